// Round 1
// baseline (3698.660 us; speedup 1.0000x reference)
//
#include <hip/hip_runtime.h>
#include <math.h>

#define NPTS 100000
#define CCH 128
#define NWIN 200
#define NBLK_STATS 512

// ---------------- BN statistics ----------------
__global__ void bn_partial(const float* __restrict__ F, float* __restrict__ part) {
    int c = threadIdx.x;            // 128 threads: one per channel
    int b = blockIdx.x;
    float s = 0.f, q = 0.f;
    for (int n = b; n < NPTS; n += NBLK_STATS) {
        float v = F[n * CCH + c];
        s += v; q += v * v;
    }
    part[b * 256 + c] = s;
    part[b * 256 + 128 + c] = q;
}

__global__ void bn_finalize(const float* __restrict__ part,
                            const float* __restrict__ g, const float* __restrict__ bb,
                            float* __restrict__ scale, float* __restrict__ shift) {
    int c = threadIdx.x;            // 128 threads
    double s = 0.0, q = 0.0;
    for (int b = 0; b < NBLK_STATS; b++) {
        s += (double)part[b * 256 + c];
        q += (double)part[b * 256 + 128 + c];
    }
    double m = s / (double)NPTS;
    double var = q / (double)NPTS - m * m;
    double rstd = 1.0 / sqrt(var + 1e-3);
    float sc = (float)rstd * g[c];
    scale[c] = sc;
    shift[c] = bb[c] - (float)m * sc;
}

// ---------------- tiled f32 GEMM with BN-fold / bias / relu / residual ----------------
// Out[r, col] (= or +=) sum_k A'[r,k] * W[k, col] + bias[col]; A' = A*scale+shift (per k)
__global__ __launch_bounds__(256) void gemm_f32(
    const float* __restrict__ A, int lda,
    const float* __restrict__ scale, const float* __restrict__ shift,
    const float* __restrict__ W, int ldw, int K,
    const float* __restrict__ bias,
    float* __restrict__ Out, int ldo,
    int reluLim, int addFlag)
{
    __shared__ float As[64][68];
    __shared__ float Ws[64][64];
    const int bm = blockIdx.x * 64;
    const int bn = blockIdx.y * 64;
    const int tid = threadIdx.x;
    const int tx = tid & 15, ty = tid >> 4;
    const int r = tid >> 2;
    const int q4 = (tid & 3) * 16;
    float acc[4][4] = {{0.f}};

    for (int kk = 0; kk < K; kk += 64) {
        // stage A tile (64 rows x 64 k) with optional bn fold
        int grow = bm + r;
#pragma unroll
        for (int u = 0; u < 4; u++) {
            int cc = q4 + u * 4;
            float4 v = make_float4(0.f, 0.f, 0.f, 0.f);
            if (grow < NPTS)
                v = *reinterpret_cast<const float4*>(&A[grow * lda + kk + cc]);
            if (scale) {
                v.x = v.x * scale[kk + cc + 0] + shift[kk + cc + 0];
                v.y = v.y * scale[kk + cc + 1] + shift[kk + cc + 1];
                v.z = v.z * scale[kk + cc + 2] + shift[kk + cc + 2];
                v.w = v.w * scale[kk + cc + 3] + shift[kk + cc + 3];
            }
            *reinterpret_cast<float4*>(&As[r][cc]) = v;
        }
        // stage W tile (64 k x 64 cols)
#pragma unroll
        for (int u = 0; u < 4; u++) {
            int cc = q4 + u * 4;
            *reinterpret_cast<float4*>(&Ws[r][cc]) =
                *reinterpret_cast<const float4*>(&W[(kk + r) * ldw + bn + cc]);
        }
        __syncthreads();

#pragma unroll
        for (int kc = 0; kc < 64; kc += 4) {
            float a_[4][4], b_[4][4];
#pragma unroll
            for (int i = 0; i < 4; i++) {
                float4 t = *reinterpret_cast<const float4*>(&As[ty * 4 + i][kc]);
                a_[i][0] = t.x; a_[i][1] = t.y; a_[i][2] = t.z; a_[i][3] = t.w;
            }
#pragma unroll
            for (int kj = 0; kj < 4; kj++) {
                float4 t = *reinterpret_cast<const float4*>(&Ws[kc + kj][tx * 4]);
                b_[kj][0] = t.x; b_[kj][1] = t.y; b_[kj][2] = t.z; b_[kj][3] = t.w;
            }
#pragma unroll
            for (int kj = 0; kj < 4; kj++)
#pragma unroll
                for (int i = 0; i < 4; i++)
#pragma unroll
                    for (int j = 0; j < 4; j++)
                        acc[i][j] += a_[i][kj] * b_[kj][j];
        }
        __syncthreads();
    }

    // epilogue
#pragma unroll
    for (int i = 0; i < 4; i++) {
        int rr = bm + ty * 4 + i;
        if (rr >= NPTS) continue;
#pragma unroll
        for (int j = 0; j < 4; j++) {
            int col = bn + tx * 4 + j;
            float v = acc[i][j];
            if (bias) v += bias[col];
            if (col < reluLim) v = fmaxf(v, 0.f);
            float* o = &Out[rr * ldo + col];
            if (addFlag) *o += v; else *o = v;
        }
    }
}

// ---------------- window list build ----------------
__global__ void hist_k(const int* __restrict__ wi, int* __restrict__ hist) {
    int n = blockIdx.x * 256 + threadIdx.x;
    if (n < NPTS) atomicAdd(&hist[wi[n]], 1);
}
__global__ void scan_k(const int* __restrict__ hist, int* __restrict__ offs) {
    if (threadIdx.x == 0 && blockIdx.x == 0) {
        int a = 0;
        for (int w = 0; w < NWIN; w++) { offs[w] = a; a += hist[w]; }
        offs[NWIN] = a;
    }
}
__global__ void scatter_k(const int* __restrict__ wi, const int* __restrict__ offs,
                          int* __restrict__ cursor, int* __restrict__ list) {
    int n = blockIdx.x * 256 + threadIdx.x;
    if (n < NPTS) {
        int w = wi[n];
        int p = atomicAdd(&cursor[w], 1);
        list[offs[w] + p] = n;
    }
}

// ---------------- per-window K^T V and sum(K) ----------------
// R0 rows: [k(128) | v(128)], ld 256. One block per window.
__global__ __launch_bounds__(256) void window_kv(
    const float* __restrict__ R0,
    const int* __restrict__ offs, const int* __restrict__ list,
    float* __restrict__ KV, float* __restrict__ SB)
{
    int w = blockIdx.x;
    int t = threadIdx.x;
    __shared__ float kb[128], vb[128];
    int p0 = offs[w], p1 = offs[w + 1];
    float acc[8] = {0.f,0.f,0.f,0.f,0.f,0.f,0.f,0.f};
    float sa = 0.f;
    int f0 = t * 8;
    int h = f0 >> 8;
    int c = (f0 >> 4) & 15;
    int d0 = f0 & 15;
    for (int p = p0; p < p1; p++) {
        int n = list[p];
        if (t < 128) kb[t] = R0[n * 256 + t];
        else         vb[t - 128] = R0[n * 256 + 128 + (t - 128)];
        __syncthreads();
        float kc = kb[h * 16 + c];
#pragma unroll
        for (int i = 0; i < 8; i++) acc[i] += kc * vb[h * 16 + d0 + i];
        if (t < 128) sa += kb[t];
        __syncthreads();
    }
#pragma unroll
    for (int i = 0; i < 8; i++) KV[w * 2048 + f0 + i] = acc[i];
    if (t < 128) SB[w * 128 + t] = sa;
}

// ---------------- y = (q . kv[w]) / (q . s[w] + eps) ----------------
// Q at R0 col 0 (ld256), Y written to R0 col 128 (same buffer, disjoint cols)
__global__ __launch_bounds__(256) void attn_y(
    const float* Q, const int* __restrict__ wi,
    const float* __restrict__ KV, const float* __restrict__ SB,
    float* Y)
{
    __shared__ float qs[2][128];
    int half = threadIdx.x >> 7;
    int c = threadIdx.x & 127;
    int pt = blockIdx.x * 2 + half;
    if (pt < NPTS) qs[half][c] = Q[pt * 256 + c];
    __syncthreads();
    if (pt >= NPTS) return;
    int w = wi[pt];
    int h = c >> 4, dd = c & 15;
    const float* qh = &qs[half][h * 16];
    const float* kvw = &KV[w * 2048 + h * 256];
    const float* sw = &SB[w * 128 + h * 16];
    float z = 0.f, y = 0.f;
#pragma unroll
    for (int cc = 0; cc < 16; cc++) {
        z += sw[cc] * qh[cc];
        y += qh[cc] * kvw[cc * 16 + dd];
    }
    Y[pt * 256 + 128 + c] = y / (z + 1e-3f);
}

// ---------------- bn apply: FB = bn1(F); F[:,96:128] = 2*FB ----------------
__global__ void bn_apply(float* F, float* FB,
                         const float* __restrict__ scale, const float* __restrict__ shift)
{
    int i = blockIdx.x * 256 + threadIdx.x;   // over NPTS*32 float4 groups
    int n = i >> 5;
    int c4 = (i & 31) * 4;
    float4 v = *reinterpret_cast<const float4*>(&F[n * CCH + c4]);
    float4 o;
    o.x = v.x * scale[c4 + 0] + shift[c4 + 0];
    o.y = v.y * scale[c4 + 1] + shift[c4 + 1];
    o.z = v.z * scale[c4 + 2] + shift[c4 + 2];
    o.w = v.w * scale[c4 + 3] + shift[c4 + 3];
    *reinterpret_cast<float4*>(&FB[n * 256 + c4]) = o;
    if (c4 >= 96) {
        float4 t = make_float4(2.f * o.x, 2.f * o.y, 2.f * o.z, 2.f * o.w);
        *reinterpret_cast<float4*>(&F[n * CCH + c4]) = t;
    }
}

// ---------------- submanifold conv: F[:,out..out+32) = FB[:,g..g+32) + gather conv ----------------
// thread = (point, 4 output channels); W and rows read via global (L2/L3 resident)
template<int KN>
__global__ __launch_bounds__(256) void conv_g(
    const int* __restrict__ nbr, const float* __restrict__ Wc,
    const float* __restrict__ FB, int goff,
    float* __restrict__ Fout, int outoff)
{
    int t = blockIdx.x * 256 + threadIdx.x;
    int pt = t >> 3;
    int so = (t & 7) * 4;
    if (pt >= NPTS) return;
    float acc0 = 0.f, acc1 = 0.f, acc2 = 0.f, acc3 = 0.f;
    const int* nb = &nbr[pt * KN];
#pragma unroll 1
    for (int k = 0; k < KN; k++) {
        int idx = nb[k];
        if (idx >= NPTS) continue;   // sentinel row = zeros
        const float* rr = &FB[idx * 256 + goff];
        const float* wk = &Wc[k * 1024 + so];
#pragma unroll
        for (int c = 0; c < 32; c += 4) {
            float4 rv = *reinterpret_cast<const float4*>(&rr[c]);
            float4 w0 = *reinterpret_cast<const float4*>(&wk[(c + 0) * 32]);
            float4 w1 = *reinterpret_cast<const float4*>(&wk[(c + 1) * 32]);
            float4 w2 = *reinterpret_cast<const float4*>(&wk[(c + 2) * 32]);
            float4 w3 = *reinterpret_cast<const float4*>(&wk[(c + 3) * 32]);
            acc0 += rv.x * w0.x + rv.y * w1.x + rv.z * w2.x + rv.w * w3.x;
            acc1 += rv.x * w0.y + rv.y * w1.y + rv.z * w2.y + rv.w * w3.y;
            acc2 += rv.x * w0.z + rv.y * w1.z + rv.z * w2.z + rv.w * w3.z;
            acc3 += rv.x * w0.w + rv.y * w1.w + rv.z * w2.w + rv.w * w3.w;
        }
    }
    float4 fb = *reinterpret_cast<const float4*>(&FB[pt * 256 + goff + so]);
    float4 o = make_float4(fb.x + acc0, fb.y + acc1, fb.z + acc2, fb.w + acc3);
    *reinterpret_cast<float4*>(&Fout[pt * CCH + outoff + so]) = o;
}

// ---------------- launch ----------------
extern "C" void kernel_launch(void* const* d_in, const int* in_sizes, int n_in,
                              void* d_out, int out_size, void* d_ws, size_t ws_size,
                              hipStream_t stream)
{
    const float* feats   = (const float*)d_in[0];
    const int*   win_inds= (const int*)d_in[1];
    const int*   nbr_k   = (const int*)d_in[2];
    const int*   nbr_h   = (const int*)d_in[3];
    const int*   nbr_w   = (const int*)d_in[4];
    const float* bn_g    = (const float*)d_in[5];
    const float* bn_b    = (const float*)d_in[6];
    const float* Wqkv    = (const float*)d_in[7];
    const float* Wproj   = (const float*)d_in[8];
    const float* bproj   = (const float*)d_in[9];
    const float* bn1_g   = (const float*)d_in[10];
    const float* bn1_b   = (const float*)d_in[11];
    const float* Wk      = (const float*)d_in[12];
    const float* Wh      = (const float*)d_in[13];
    const float* Ww      = (const float*)d_in[14];
    const float* bn2_g   = (const float*)d_in[15];
    const float* bn2_b   = (const float*)d_in[16];
    const float* fc1_W   = (const float*)d_in[17];
    const float* fc1_b   = (const float*)d_in[18];
    const float* fc2_W   = (const float*)d_in[19];
    const float* fc2_b   = (const float*)d_in[20];

    float* F  = (float*)d_out;
    float* R0 = (float*)d_ws;                       // NPTS*256
    float* KV = R0 + (size_t)NPTS * 256;            // NWIN*2048
    float* SB = KV + NWIN * 2048;                   // NWIN*128
    float* ST = SB + NWIN * 128;                    // 6*128
    float* PART = ST + 768;                         // NBLK_STATS*256
    int* HIST = (int*)(PART + NBLK_STATS * 256);    // 256
    int* OFFS = HIST + 256;                         // 256 (201 used)
    int* CURS = OFFS + 256;                         // 256
    int* LIST = CURS + 256;                         // NPTS

    hipMemcpyAsync(F, feats, (size_t)NPTS * CCH * sizeof(float),
                   hipMemcpyDeviceToDevice, stream);

    dim3 g4(1563, 4), g2(1563, 2);

    for (int d = 0; d < 2; d++) {
        const int* wi = win_inds + (size_t)d * NPTS;
        float* SC0 = ST, *SH0 = ST + 128, *SC1 = ST + 256, *SH1 = ST + 384,
             * SC2 = ST + 512, *SH2 = ST + 640;

        // ---- BN0 ----
        bn_partial<<<NBLK_STATS, 128, 0, stream>>>(F, PART);
        bn_finalize<<<1, 128, 0, stream>>>(PART, bn_g + d * CCH, bn_b + d * CCH, SC0, SH0);

        // ---- k,v = relu/id( bn0(F) @ Wqkv[:,128:384] ) -> R0 ----
        gemm_f32<<<g4, 256, 0, stream>>>(F, CCH, SC0, SH0,
                                         Wqkv + (size_t)d * CCH * 384 + 128, 384, CCH,
                                         nullptr, R0, 256, 128, 0);

        // ---- window lists ----
        hipMemsetAsync(HIST, 0, 768 * sizeof(int), stream);
        hist_k<<<391, 256, 0, stream>>>(wi, HIST);
        scan_k<<<1, 64, 0, stream>>>(HIST, OFFS);
        scatter_k<<<391, 256, 0, stream>>>(wi, OFFS, CURS, LIST);

        // ---- per-window KV, S ----
        hipMemsetAsync(KV, 0, (size_t)(NWIN * 2048 + NWIN * 128) * sizeof(float), stream);
        window_kv<<<NWIN, 256, 0, stream>>>(R0, OFFS, LIST, KV, SB);

        // ---- q = relu( bn0(F) @ Wqkv[:,0:128] ) -> R0 col 0 (over dead k) ----
        gemm_f32<<<g2, 256, 0, stream>>>(F, CCH, SC0, SH0,
                                         Wqkv + (size_t)d * CCH * 384, 384, CCH,
                                         nullptr, R0, 256, 128, 0);

        // ---- y -> R0 col 128 (over dead v) ----
        attn_y<<<50000, 256, 0, stream>>>(R0, wi, KV, SB, R0);

        // ---- F += y @ Wproj + bproj ----
        gemm_f32<<<g2, 256, 0, stream>>>(R0 + 128, 256, nullptr, nullptr,
                                         Wproj + (size_t)d * CCH * CCH, CCH, CCH,
                                         bproj + d * CCH, F, CCH, 0, 1);

        // ---- BN1 -> FB (R0 col 0..127), F[:,96:] = 2*FB ----
        bn_partial<<<NBLK_STATS, 128, 0, stream>>>(F, PART);
        bn_finalize<<<1, 128, 0, stream>>>(PART, bn1_g + d * CCH, bn1_b + d * CCH, SC1, SH1);
        bn_apply<<<12500, 256, 0, stream>>>(F, R0, SC1, SH1);

        // ---- submanifold convs (residual fused) ----
        conv_g<27><<<3125, 256, 0, stream>>>(nbr_k, Wk + (size_t)d * 27 * 1024, R0, 0,  F, 0);
        conv_g<13><<<3125, 256, 0, stream>>>(nbr_h, Wh + (size_t)d * 13 * 1024, R0, 32, F, 32);
        conv_g<13><<<3125, 256, 0, stream>>>(nbr_w, Ww + (size_t)d * 13 * 1024, R0, 64, F, 64);

        // ---- BN2 + MLP ----
        bn_partial<<<NBLK_STATS, 128, 0, stream>>>(F, PART);
        bn_finalize<<<1, 128, 0, stream>>>(PART, bn2_g + d * CCH, bn2_b + d * CCH, SC2, SH2);

        gemm_f32<<<g4, 256, 0, stream>>>(F, CCH, SC2, SH2,
                                         fc1_W + (size_t)d * CCH * 256, 256, CCH,
                                         fc1_b + d * 256, R0, 256, 256, 0);
        gemm_f32<<<g2, 256, 0, stream>>>(R0, 256, nullptr, nullptr,
                                         fc2_W + (size_t)d * 256 * CCH, CCH, 256,
                                         fc2_b + d * CCH, F, CCH, 0, 1);
    }
}

// Round 2
// 2967.287 us; speedup vs baseline: 1.2465x; 1.2465x over previous
//
#include <hip/hip_runtime.h>
#include <math.h>

#define NPTS 100000
#define CCH 128
#define NWIN 200
#define NBLK_STATS 512
#define KVCHUNK 64

// ---------------- BN statistics ----------------
__global__ void bn_partial(const float* __restrict__ F, float* __restrict__ part) {
    int c = threadIdx.x;            // 128 threads: one per channel
    int b = blockIdx.x;
    float s = 0.f, q = 0.f;
    for (int n = b; n < NPTS; n += NBLK_STATS) {
        float v = F[n * CCH + c];
        s += v; q += v * v;
    }
    part[b * 256 + c] = s;
    part[b * 256 + 128 + c] = q;
}

__global__ void bn_finalize(const float* __restrict__ part,
                            const float* __restrict__ g, const float* __restrict__ bb,
                            float* __restrict__ scale, float* __restrict__ shift) {
    int c = threadIdx.x;            // 128 threads
    double s = 0.0, q = 0.0;
    for (int b = 0; b < NBLK_STATS; b++) {
        s += (double)part[b * 256 + c];
        q += (double)part[b * 256 + 128 + c];
    }
    double m = s / (double)NPTS;
    double var = q / (double)NPTS - m * m;
    double rstd = 1.0 / sqrt(var + 1e-3);
    float sc = (float)rstd * g[c];
    scale[c] = sc;
    shift[c] = bb[c] - (float)m * sc;
}

// ---------------- tiled f32 GEMM with BN-fold / bias / relu / residual ----------------
// Out[r, col] (= or +=) sum_k A'[r,k] * W[k, col] + bias[col]; A' = A*scale+shift (per k)
__global__ __launch_bounds__(256) void gemm_f32(
    const float* __restrict__ A, int lda,
    const float* __restrict__ scale, const float* __restrict__ shift,
    const float* __restrict__ W, int ldw, int K,
    const float* __restrict__ bias,
    float* __restrict__ Out, int ldo,
    int reluLim, int addFlag)
{
    __shared__ float As[64][68];
    __shared__ float Ws[64][64];
    const int bm = blockIdx.x * 64;
    const int bn = blockIdx.y * 64;
    const int tid = threadIdx.x;
    const int tx = tid & 15, ty = tid >> 4;
    const int r = tid >> 2;
    const int q4 = (tid & 3) * 16;
    float acc[4][4] = {{0.f}};

    for (int kk = 0; kk < K; kk += 64) {
        // stage A tile (64 rows x 64 k) with optional bn fold
        int grow = bm + r;
#pragma unroll
        for (int u = 0; u < 4; u++) {
            int cc = q4 + u * 4;
            float4 v = make_float4(0.f, 0.f, 0.f, 0.f);
            if (grow < NPTS)
                v = *reinterpret_cast<const float4*>(&A[grow * lda + kk + cc]);
            if (scale) {
                v.x = v.x * scale[kk + cc + 0] + shift[kk + cc + 0];
                v.y = v.y * scale[kk + cc + 1] + shift[kk + cc + 1];
                v.z = v.z * scale[kk + cc + 2] + shift[kk + cc + 2];
                v.w = v.w * scale[kk + cc + 3] + shift[kk + cc + 3];
            }
            *reinterpret_cast<float4*>(&As[r][cc]) = v;
        }
        // stage W tile (64 k x 64 cols)
#pragma unroll
        for (int u = 0; u < 4; u++) {
            int cc = q4 + u * 4;
            *reinterpret_cast<float4*>(&Ws[r][cc]) =
                *reinterpret_cast<const float4*>(&W[(kk + r) * ldw + bn + cc]);
        }
        __syncthreads();

#pragma unroll
        for (int kc = 0; kc < 64; kc += 4) {
            float a_[4][4], b_[4][4];
#pragma unroll
            for (int i = 0; i < 4; i++) {
                float4 t = *reinterpret_cast<const float4*>(&As[ty * 4 + i][kc]);
                a_[i][0] = t.x; a_[i][1] = t.y; a_[i][2] = t.z; a_[i][3] = t.w;
            }
#pragma unroll
            for (int kj = 0; kj < 4; kj++) {
                float4 t = *reinterpret_cast<const float4*>(&Ws[kc + kj][tx * 4]);
                b_[kj][0] = t.x; b_[kj][1] = t.y; b_[kj][2] = t.z; b_[kj][3] = t.w;
            }
#pragma unroll
            for (int kj = 0; kj < 4; kj++)
#pragma unroll
                for (int i = 0; i < 4; i++)
#pragma unroll
                    for (int j = 0; j < 4; j++)
                        acc[i][j] += a_[i][kj] * b_[kj][j];
        }
        __syncthreads();
    }

    // epilogue
#pragma unroll
    for (int i = 0; i < 4; i++) {
        int rr = bm + ty * 4 + i;
        if (rr >= NPTS) continue;
#pragma unroll
        for (int j = 0; j < 4; j++) {
            int col = bn + tx * 4 + j;
            float v = acc[i][j];
            if (bias) v += bias[col];
            if (col < reluLim) v = fmaxf(v, 0.f);
            float* o = &Out[rr * ldo + col];
            if (addFlag) *o += v; else *o = v;
        }
    }
}

// ---------------- window list build ----------------
__global__ void hist_k(const int* __restrict__ wi, int* __restrict__ hist) {
    int n = blockIdx.x * 256 + threadIdx.x;
    if (n < NPTS) atomicAdd(&hist[wi[n]], 1);
}
__global__ void scan_k(const int* __restrict__ hist, int* __restrict__ offs) {
    if (threadIdx.x == 0 && blockIdx.x == 0) {
        int a = 0;
        for (int w = 0; w < NWIN; w++) { offs[w] = a; a += hist[w]; }
        offs[NWIN] = a;
    }
}
__global__ void scatter_k(const int* __restrict__ wi, const int* __restrict__ offs,
                          int* __restrict__ cursor, int* __restrict__ list) {
    int n = blockIdx.x * 256 + threadIdx.x;
    if (n < NPTS) {
        int w = wi[n];
        int p = atomicAdd(&cursor[w], 1);
        list[offs[w] + p] = n;
    }
}

// ---------------- chunk-parallel per-window K^T V and sum(K) ----------------
// R0 rows: [k(128) | v(128)], ld 256. Each block handles KVCHUNK points of the
// window-sorted list, accumulates KV slice in registers, flushes per-window
// via atomicAdd (list is sorted by window, so <=2 windows per chunk typically).
__global__ __launch_bounds__(256) void window_kv_chunk(
    const float* __restrict__ R0,
    const int* __restrict__ wi,
    const int* __restrict__ list,
    float* __restrict__ KV, float* __restrict__ SB)
{
    int t = threadIdx.x;
    int p0 = blockIdx.x * KVCHUNK;
    int p1 = min(p0 + KVCHUNK, NPTS);
    __shared__ float kb[128], vb[128];
    float acc[8] = {0.f,0.f,0.f,0.f,0.f,0.f,0.f,0.f};
    float sa = 0.f;
    int f0 = t * 8;
    int h = f0 >> 8;
    int c = (f0 >> 4) & 15;
    int d0 = f0 & 15;
    int curw = -1;
    for (int p = p0; p < p1; p++) {
        int n = list[p];
        int w = wi[n];                       // block-uniform (list sorted by w)
        if (w != curw) {
            if (curw >= 0) {
#pragma unroll
                for (int i = 0; i < 8; i++) {
                    atomicAdd(&KV[curw * 2048 + f0 + i], acc[i]);
                    acc[i] = 0.f;
                }
                if (t < 128) { atomicAdd(&SB[curw * 128 + t], sa); sa = 0.f; }
            }
            curw = w;
        }
        if (t < 128) kb[t] = R0[n * 256 + t];
        else         vb[t - 128] = R0[n * 256 + 128 + (t - 128)];
        __syncthreads();
        float kc = kb[h * 16 + c];
#pragma unroll
        for (int i = 0; i < 8; i++) acc[i] += kc * vb[h * 16 + d0 + i];
        if (t < 128) sa += kb[t];
        __syncthreads();
    }
    if (curw >= 0) {
#pragma unroll
        for (int i = 0; i < 8; i++) atomicAdd(&KV[curw * 2048 + f0 + i], acc[i]);
        if (t < 128) atomicAdd(&SB[curw * 128 + t], sa);
    }
}

// ---------------- y = (q . kv[w]) / (q . s[w] + eps) ----------------
// Q at R0 col 0 (ld256), Y written to R0 col 128 (same buffer, disjoint cols)
__global__ __launch_bounds__(256) void attn_y(
    const float* Q, const int* __restrict__ wi,
    const float* __restrict__ KV, const float* __restrict__ SB,
    float* Y)
{
    __shared__ float qs[2][128];
    int half = threadIdx.x >> 7;
    int c = threadIdx.x & 127;
    int pt = blockIdx.x * 2 + half;
    if (pt < NPTS) qs[half][c] = Q[pt * 256 + c];
    __syncthreads();
    if (pt >= NPTS) return;
    int w = wi[pt];
    int h = c >> 4, dd = c & 15;
    const float* qh = &qs[half][h * 16];
    const float* kvw = &KV[w * 2048 + h * 256];
    const float* sw = &SB[w * 128 + h * 16];
    float z = 0.f, y = 0.f;
#pragma unroll
    for (int cc = 0; cc < 16; cc++) {
        z += sw[cc] * qh[cc];
        y += qh[cc] * kvw[cc * 16 + dd];
    }
    Y[pt * 256 + 128 + c] = y / (z + 1e-3f);
}

// ---------------- bn apply: FB = bn1(F); F[:,96:128] = 2*FB ----------------
__global__ void bn_apply(float* F, float* FB,
                         const float* __restrict__ scale, const float* __restrict__ shift)
{
    int i = blockIdx.x * 256 + threadIdx.x;   // over NPTS*32 float4 groups
    int n = i >> 5;
    int c4 = (i & 31) * 4;
    float4 v = *reinterpret_cast<const float4*>(&F[n * CCH + c4]);
    float4 o;
    o.x = v.x * scale[c4 + 0] + shift[c4 + 0];
    o.y = v.y * scale[c4 + 1] + shift[c4 + 1];
    o.z = v.z * scale[c4 + 2] + shift[c4 + 2];
    o.w = v.w * scale[c4 + 3] + shift[c4 + 3];
    *reinterpret_cast<float4*>(&FB[n * 256 + c4]) = o;
    if (c4 >= 96) {
        float4 t = make_float4(2.f * o.x, 2.f * o.y, 2.f * o.z, 2.f * o.w);
        *reinterpret_cast<float4*>(&F[n * CCH + c4]) = t;
    }
}

// ---------------- submanifold conv: F[:,out..out+32) = FB[:,g..g+32) + gather conv ----------------
// thread = (point, 4 output channels); W and rows read via global (L2/L3 resident)
template<int KN>
__global__ __launch_bounds__(256) void conv_g(
    const int* __restrict__ nbr, const float* __restrict__ Wc,
    const float* __restrict__ FB, int goff,
    float* __restrict__ Fout, int outoff)
{
    int t = blockIdx.x * 256 + threadIdx.x;
    int pt = t >> 3;
    int so = (t & 7) * 4;
    if (pt >= NPTS) return;
    float acc0 = 0.f, acc1 = 0.f, acc2 = 0.f, acc3 = 0.f;
    const int* nb = &nbr[pt * KN];
#pragma unroll 1
    for (int k = 0; k < KN; k++) {
        int idx = nb[k];
        if (idx >= NPTS) continue;   // sentinel row = zeros
        const float* rr = &FB[idx * 256 + goff];
        const float* wk = &Wc[k * 1024 + so];
#pragma unroll
        for (int c = 0; c < 32; c += 4) {
            float4 rv = *reinterpret_cast<const float4*>(&rr[c]);
            float4 w0 = *reinterpret_cast<const float4*>(&wk[(c + 0) * 32]);
            float4 w1 = *reinterpret_cast<const float4*>(&wk[(c + 1) * 32]);
            float4 w2 = *reinterpret_cast<const float4*>(&wk[(c + 2) * 32]);
            float4 w3 = *reinterpret_cast<const float4*>(&wk[(c + 3) * 32]);
            acc0 += rv.x * w0.x + rv.y * w1.x + rv.z * w2.x + rv.w * w3.x;
            acc1 += rv.x * w0.y + rv.y * w1.y + rv.z * w2.y + rv.w * w3.y;
            acc2 += rv.x * w0.z + rv.y * w1.z + rv.z * w2.z + rv.w * w3.z;
            acc3 += rv.x * w0.w + rv.y * w1.w + rv.z * w2.w + rv.w * w3.w;
        }
    }
    float4 fb = *reinterpret_cast<const float4*>(&FB[pt * 256 + goff + so]);
    float4 o = make_float4(fb.x + acc0, fb.y + acc1, fb.z + acc2, fb.w + acc3);
    *reinterpret_cast<float4*>(&Fout[pt * CCH + outoff + so]) = o;
}

// ---------------- launch ----------------
extern "C" void kernel_launch(void* const* d_in, const int* in_sizes, int n_in,
                              void* d_out, int out_size, void* d_ws, size_t ws_size,
                              hipStream_t stream)
{
    const float* feats   = (const float*)d_in[0];
    const int*   win_inds= (const int*)d_in[1];
    const int*   nbr_k   = (const int*)d_in[2];
    const int*   nbr_h   = (const int*)d_in[3];
    const int*   nbr_w   = (const int*)d_in[4];
    const float* bn_g    = (const float*)d_in[5];
    const float* bn_b    = (const float*)d_in[6];
    const float* Wqkv    = (const float*)d_in[7];
    const float* Wproj   = (const float*)d_in[8];
    const float* bproj   = (const float*)d_in[9];
    const float* bn1_g   = (const float*)d_in[10];
    const float* bn1_b   = (const float*)d_in[11];
    const float* Wk      = (const float*)d_in[12];
    const float* Wh      = (const float*)d_in[13];
    const float* Ww      = (const float*)d_in[14];
    const float* bn2_g   = (const float*)d_in[15];
    const float* bn2_b   = (const float*)d_in[16];
    const float* fc1_W   = (const float*)d_in[17];
    const float* fc1_b   = (const float*)d_in[18];
    const float* fc2_W   = (const float*)d_in[19];
    const float* fc2_b   = (const float*)d_in[20];

    float* F  = (float*)d_out;
    float* R0 = (float*)d_ws;                       // NPTS*256
    float* KV = R0 + (size_t)NPTS * 256;            // NWIN*2048
    float* SB = KV + NWIN * 2048;                   // NWIN*128
    float* ST = SB + NWIN * 128;                    // 6*128
    float* PART = ST + 768;                         // NBLK_STATS*256
    int* HIST = (int*)(PART + NBLK_STATS * 256);    // 256
    int* OFFS = HIST + 256;                         // 256 (201 used)
    int* CURS = OFFS + 256;                         // 256
    int* LIST = CURS + 256;                         // NPTS

    hipMemcpyAsync(F, feats, (size_t)NPTS * CCH * sizeof(float),
                   hipMemcpyDeviceToDevice, stream);

    dim3 g4(1563, 4), g2(1563, 2);

    for (int d = 0; d < 2; d++) {
        const int* wi = win_inds + (size_t)d * NPTS;
        float* SC0 = ST, *SH0 = ST + 128, *SC1 = ST + 256, *SH1 = ST + 384,
             * SC2 = ST + 512, *SH2 = ST + 640;

        // ---- BN0 ----
        bn_partial<<<NBLK_STATS, 128, 0, stream>>>(F, PART);
        bn_finalize<<<1, 128, 0, stream>>>(PART, bn_g + d * CCH, bn_b + d * CCH, SC0, SH0);

        // ---- k,v = relu/id( bn0(F) @ Wqkv[:,128:384] ) -> R0 ----
        gemm_f32<<<g4, 256, 0, stream>>>(F, CCH, SC0, SH0,
                                         Wqkv + (size_t)d * CCH * 384 + 128, 384, CCH,
                                         nullptr, R0, 256, 128, 0);

        // ---- window lists ----
        hipMemsetAsync(HIST, 0, 768 * sizeof(int), stream);
        hist_k<<<391, 256, 0, stream>>>(wi, HIST);
        scan_k<<<1, 64, 0, stream>>>(HIST, OFFS);
        scatter_k<<<391, 256, 0, stream>>>(wi, OFFS, CURS, LIST);

        // ---- per-window KV, S (chunk-parallel, atomic reduce) ----
        hipMemsetAsync(KV, 0, (size_t)(NWIN * 2048 + NWIN * 128) * sizeof(float), stream);
        window_kv_chunk<<<(NPTS + KVCHUNK - 1) / KVCHUNK, 256, 0, stream>>>(
            R0, wi, LIST, KV, SB);

        // ---- q = relu( bn0(F) @ Wqkv[:,0:128] ) -> R0 col 0 (over dead k) ----
        gemm_f32<<<g2, 256, 0, stream>>>(F, CCH, SC0, SH0,
                                         Wqkv + (size_t)d * CCH * 384, 384, CCH,
                                         nullptr, R0, 256, 128, 0);

        // ---- y -> R0 col 128 (over dead v) ----
        attn_y<<<50000, 256, 0, stream>>>(R0, wi, KV, SB, R0);

        // ---- F += y @ Wproj + bproj ----
        gemm_f32<<<g2, 256, 0, stream>>>(R0 + 128, 256, nullptr, nullptr,
                                         Wproj + (size_t)d * CCH * CCH, CCH, CCH,
                                         bproj + d * CCH, F, CCH, 0, 1);

        // ---- BN1 -> FB (R0 col 0..127), F[:,96:] = 2*FB ----
        bn_partial<<<NBLK_STATS, 128, 0, stream>>>(F, PART);
        bn_finalize<<<1, 128, 0, stream>>>(PART, bn1_g + d * CCH, bn1_b + d * CCH, SC1, SH1);
        bn_apply<<<12500, 256, 0, stream>>>(F, R0, SC1, SH1);

        // ---- submanifold convs (residual fused) ----
        conv_g<27><<<3125, 256, 0, stream>>>(nbr_k, Wk + (size_t)d * 27 * 1024, R0, 0,  F, 0);
        conv_g<13><<<3125, 256, 0, stream>>>(nbr_h, Wh + (size_t)d * 13 * 1024, R0, 32, F, 32);
        conv_g<13><<<3125, 256, 0, stream>>>(nbr_w, Ww + (size_t)d * 13 * 1024, R0, 64, F, 64);

        // ---- BN2 + MLP ----
        bn_partial<<<NBLK_STATS, 128, 0, stream>>>(F, PART);
        bn_finalize<<<1, 128, 0, stream>>>(PART, bn2_g + d * CCH, bn2_b + d * CCH, SC2, SH2);

        gemm_f32<<<g4, 256, 0, stream>>>(F, CCH, SC2, SH2,
                                         fc1_W + (size_t)d * CCH * 256, 256, CCH,
                                         fc1_b + d * 256, R0, 256, 256, 0);
        gemm_f32<<<g2, 256, 0, stream>>>(R0, 256, nullptr, nullptr,
                                         fc2_W + (size_t)d * 256 * CCH, CCH, 256,
                                         fc2_b + d * CCH, F, CCH, 0, 1);
    }
}

// Round 3
// 2151.067 us; speedup vs baseline: 1.7195x; 1.3794x over previous
//
#include <hip/hip_runtime.h>
#include <math.h>

#define NPTS 100000
#define CCH 128
#define NWIN 200
#define NBLK_STATS 512
#define KVCHUNK 64
#define NBLK_SORT 391   // ceil(NPTS/256)

// ---------------- BN statistics ----------------
__global__ void bn_partial(const float* __restrict__ F, float* __restrict__ part) {
    int c = threadIdx.x;            // 128 threads: one per channel
    int b = blockIdx.x;
    float s = 0.f, q = 0.f;
    for (int n = b; n < NPTS; n += NBLK_STATS) {
        float v = F[n * CCH + c];
        s += v; q += v * v;
    }
    part[b * 256 + c] = s;
    part[b * 256 + 128 + c] = q;
}

__global__ void bn_finalize(const float* __restrict__ part,
                            const float* __restrict__ g, const float* __restrict__ bb,
                            float* __restrict__ scale, float* __restrict__ shift) {
    int c = threadIdx.x;            // 128 threads
    double s = 0.0, q = 0.0;
    for (int b = 0; b < NBLK_STATS; b++) {
        s += (double)part[b * 256 + c];
        q += (double)part[b * 256 + 128 + c];
    }
    double m = s / (double)NPTS;
    double var = q / (double)NPTS - m * m;
    double rstd = 1.0 / sqrt(var + 1e-3);
    float sc = (float)rstd * g[c];
    scale[c] = sc;
    shift[c] = bb[c] - (float)m * sc;
}

// ---------------- tiled f32 GEMM with BN-fold / bias / relu / residual ----------------
__global__ __launch_bounds__(256) void gemm_f32(
    const float* __restrict__ A, int lda,
    const float* __restrict__ scale, const float* __restrict__ shift,
    const float* __restrict__ W, int ldw, int K,
    const float* __restrict__ bias,
    float* __restrict__ Out, int ldo,
    int reluLim, int addFlag)
{
    __shared__ float As[64][68];
    __shared__ float Ws[64][64];
    const int bm = blockIdx.x * 64;
    const int bn = blockIdx.y * 64;
    const int tid = threadIdx.x;
    const int tx = tid & 15, ty = tid >> 4;
    const int r = tid >> 2;
    const int q4 = (tid & 3) * 16;
    float acc[4][4] = {{0.f}};

    for (int kk = 0; kk < K; kk += 64) {
        int grow = bm + r;
#pragma unroll
        for (int u = 0; u < 4; u++) {
            int cc = q4 + u * 4;
            float4 v = make_float4(0.f, 0.f, 0.f, 0.f);
            if (grow < NPTS)
                v = *reinterpret_cast<const float4*>(&A[grow * lda + kk + cc]);
            if (scale) {
                v.x = v.x * scale[kk + cc + 0] + shift[kk + cc + 0];
                v.y = v.y * scale[kk + cc + 1] + shift[kk + cc + 1];
                v.z = v.z * scale[kk + cc + 2] + shift[kk + cc + 2];
                v.w = v.w * scale[kk + cc + 3] + shift[kk + cc + 3];
            }
            *reinterpret_cast<float4*>(&As[r][cc]) = v;
        }
#pragma unroll
        for (int u = 0; u < 4; u++) {
            int cc = q4 + u * 4;
            *reinterpret_cast<float4*>(&Ws[r][cc]) =
                *reinterpret_cast<const float4*>(&W[(kk + r) * ldw + bn + cc]);
        }
        __syncthreads();

#pragma unroll
        for (int kc = 0; kc < 64; kc += 4) {
            float a_[4][4], b_[4][4];
#pragma unroll
            for (int i = 0; i < 4; i++) {
                float4 t = *reinterpret_cast<const float4*>(&As[ty * 4 + i][kc]);
                a_[i][0] = t.x; a_[i][1] = t.y; a_[i][2] = t.z; a_[i][3] = t.w;
            }
#pragma unroll
            for (int kj = 0; kj < 4; kj++) {
                float4 t = *reinterpret_cast<const float4*>(&Ws[kc + kj][tx * 4]);
                b_[kj][0] = t.x; b_[kj][1] = t.y; b_[kj][2] = t.z; b_[kj][3] = t.w;
            }
#pragma unroll
            for (int kj = 0; kj < 4; kj++)
#pragma unroll
                for (int i = 0; i < 4; i++)
#pragma unroll
                    for (int j = 0; j < 4; j++)
                        acc[i][j] += a_[i][kj] * b_[kj][j];
        }
        __syncthreads();
    }

#pragma unroll
    for (int i = 0; i < 4; i++) {
        int rr = bm + ty * 4 + i;
        if (rr >= NPTS) continue;
#pragma unroll
        for (int j = 0; j < 4; j++) {
            int col = bn + tx * 4 + j;
            float v = acc[i][j];
            if (bias) v += bias[col];
            if (col < reluLim) v = fmaxf(v, 0.f);
            float* o = &Out[rr * ldo + col];
            if (addFlag) *o += v; else *o = v;
        }
    }
}

// ---------------- window list build (block-local counting sort, no global contention) ----------------
__global__ __launch_bounds__(256) void hist2_k(const int* __restrict__ wi,
                                               int* __restrict__ BH, int* __restrict__ HIST) {
    __shared__ int h[NWIN];
    int t = threadIdx.x;
    if (t < NWIN) h[t] = 0;
    __syncthreads();
    int n = blockIdx.x * 256 + t;
    if (n < NPTS) atomicAdd(&h[wi[n]], 1);
    __syncthreads();
    if (t < NWIN) {
        BH[blockIdx.x * 256 + t] = h[t];
        if (h[t]) atomicAdd(&HIST[t], h[t]);
    }
}

__global__ void scan_k(const int* __restrict__ hist, int* __restrict__ offs) {
    if (threadIdx.x == 0 && blockIdx.x == 0) {
        int a = 0;
        for (int w = 0; w < NWIN; w++) { offs[w] = a; a += hist[w]; }
        offs[NWIN] = a;
    }
}

// per-(block,window) running offsets: OFFB[b][w] = OFFS[w] + sum_{b'<b} BH[b'][w]
__global__ void colscan_k(const int* __restrict__ BH, const int* __restrict__ OFFS,
                          int* __restrict__ OFFB) {
    int w = threadIdx.x;
    if (w >= NWIN) return;
    int a = OFFS[w];
    for (int b = 0; b < NBLK_SORT; b++) {
        OFFB[b * 256 + w] = a;
        a += BH[b * 256 + w];
    }
}

__global__ __launch_bounds__(256) void scatter2_k(const int* __restrict__ wi,
                                                  const int* __restrict__ OFFB,
                                                  int* __restrict__ list) {
    __shared__ int h[NWIN];
    int t = threadIdx.x;
    if (t < NWIN) h[t] = 0;
    __syncthreads();
    int n = blockIdx.x * 256 + t;
    if (n < NPTS) {
        int w = wi[n];
        int r = atomicAdd(&h[w], 1);
        list[OFFB[blockIdx.x * 256 + w] + r] = n;
    }
}

// ---------------- chunk-parallel per-window K^T V and sum(K) ----------------
__global__ __launch_bounds__(256) void window_kv_chunk(
    const float* __restrict__ R0,
    const int* __restrict__ wi,
    const int* __restrict__ list,
    float* __restrict__ KV, float* __restrict__ SB)
{
    int t = threadIdx.x;
    int p0 = blockIdx.x * KVCHUNK;
    int p1 = min(p0 + KVCHUNK, NPTS);
    __shared__ float kb[128], vb[128];
    float acc[8] = {0.f,0.f,0.f,0.f,0.f,0.f,0.f,0.f};
    float sa = 0.f;
    int f0 = t * 8;
    int h = f0 >> 8;
    int c = (f0 >> 4) & 15;
    int d0 = f0 & 15;
    int curw = -1;
    for (int p = p0; p < p1; p++) {
        int n = list[p];
        int w = wi[n];                       // block-uniform (list sorted by w)
        if (w != curw) {
            if (curw >= 0) {
#pragma unroll
                for (int i = 0; i < 8; i++) {
                    atomicAdd(&KV[curw * 2048 + f0 + i], acc[i]);
                    acc[i] = 0.f;
                }
                if (t < 128) { atomicAdd(&SB[curw * 128 + t], sa); sa = 0.f; }
            }
            curw = w;
        }
        if (t < 128) kb[t] = R0[n * 256 + t];
        else         vb[t - 128] = R0[n * 256 + 128 + (t - 128)];
        __syncthreads();
        float kc = kb[h * 16 + c];
#pragma unroll
        for (int i = 0; i < 8; i++) acc[i] += kc * vb[h * 16 + d0 + i];
        if (t < 128) sa += kb[t];
        __syncthreads();
    }
    if (curw >= 0) {
#pragma unroll
        for (int i = 0; i < 8; i++) atomicAdd(&KV[curw * 2048 + f0 + i], acc[i]);
        if (t < 128) atomicAdd(&SB[curw * 128 + t], sa);
    }
}

// ---------------- y = (q . kv[w]) / (q . s[w] + eps) ----------------
__global__ __launch_bounds__(256) void attn_y(
    const float* Q, const int* __restrict__ wi,
    const float* __restrict__ KV, const float* __restrict__ SB,
    float* Y)
{
    __shared__ float qs[2][128];
    int half = threadIdx.x >> 7;
    int c = threadIdx.x & 127;
    int pt = blockIdx.x * 2 + half;
    if (pt < NPTS) qs[half][c] = Q[pt * 256 + c];
    __syncthreads();
    if (pt >= NPTS) return;
    int w = wi[pt];
    int h = c >> 4, dd = c & 15;
    const float* qh = &qs[half][h * 16];
    const float* kvw = &KV[w * 2048 + h * 256];
    const float* sw = &SB[w * 128 + h * 16];
    float z = 0.f, y = 0.f;
#pragma unroll
    for (int cc = 0; cc < 16; cc++) {
        z += sw[cc] * qh[cc];
        y += qh[cc] * kvw[cc * 16 + dd];
    }
    Y[pt * 256 + 128 + c] = y / (z + 1e-3f);
}

// ---------------- bn apply: FB = bn1(F); F[:,96:128] = 2*FB ----------------
__global__ void bn_apply(float* F, float* FB,
                         const float* __restrict__ scale, const float* __restrict__ shift)
{
    int i = blockIdx.x * 256 + threadIdx.x;   // over NPTS*32 float4 groups
    int n = i >> 5;
    int c4 = (i & 31) * 4;
    float4 v = *reinterpret_cast<const float4*>(&F[n * CCH + c4]);
    float4 o;
    o.x = v.x * scale[c4 + 0] + shift[c4 + 0];
    o.y = v.y * scale[c4 + 1] + shift[c4 + 1];
    o.z = v.z * scale[c4 + 2] + shift[c4 + 2];
    o.w = v.w * scale[c4 + 3] + shift[c4 + 3];
    *reinterpret_cast<float4*>(&FB[n * 256 + c4]) = o;
    if (c4 >= 96) {
        float4 t = make_float4(2.f * o.x, 2.f * o.y, 2.f * o.z, 2.f * o.w);
        *reinterpret_cast<float4*>(&F[n * CCH + c4]) = t;
    }
}

// ---------------- submanifold conv ----------------
template<int KN>
__global__ __launch_bounds__(256) void conv_g(
    const int* __restrict__ nbr, const float* __restrict__ Wc,
    const float* __restrict__ FB, int goff,
    float* __restrict__ Fout, int outoff)
{
    int t = blockIdx.x * 256 + threadIdx.x;
    int pt = t >> 3;
    int so = (t & 7) * 4;
    if (pt >= NPTS) return;
    float acc0 = 0.f, acc1 = 0.f, acc2 = 0.f, acc3 = 0.f;
    const int* nb = &nbr[pt * KN];
#pragma unroll 1
    for (int k = 0; k < KN; k++) {
        int idx = nb[k];
        if (idx >= NPTS) continue;   // sentinel row = zeros
        const float* rr = &FB[idx * 256 + goff];
        const float* wk = &Wc[k * 1024 + so];
#pragma unroll
        for (int c = 0; c < 32; c += 4) {
            float4 rv = *reinterpret_cast<const float4*>(&rr[c]);
            float4 w0 = *reinterpret_cast<const float4*>(&wk[(c + 0) * 32]);
            float4 w1 = *reinterpret_cast<const float4*>(&wk[(c + 1) * 32]);
            float4 w2 = *reinterpret_cast<const float4*>(&wk[(c + 2) * 32]);
            float4 w3 = *reinterpret_cast<const float4*>(&wk[(c + 3) * 32]);
            acc0 += rv.x * w0.x + rv.y * w1.x + rv.z * w2.x + rv.w * w3.x;
            acc1 += rv.x * w0.y + rv.y * w1.y + rv.z * w2.y + rv.w * w3.y;
            acc2 += rv.x * w0.z + rv.y * w1.z + rv.z * w2.z + rv.w * w3.z;
            acc3 += rv.x * w0.w + rv.y * w1.w + rv.z * w2.w + rv.w * w3.w;
        }
    }
    float4 fb = *reinterpret_cast<const float4*>(&FB[pt * 256 + goff + so]);
    float4 o = make_float4(fb.x + acc0, fb.y + acc1, fb.z + acc2, fb.w + acc3);
    *reinterpret_cast<float4*>(&Fout[pt * CCH + outoff + so]) = o;
}

// ---------------- launch ----------------
extern "C" void kernel_launch(void* const* d_in, const int* in_sizes, int n_in,
                              void* d_out, int out_size, void* d_ws, size_t ws_size,
                              hipStream_t stream)
{
    const float* feats   = (const float*)d_in[0];
    const int*   win_inds= (const int*)d_in[1];
    const int*   nbr_k   = (const int*)d_in[2];
    const int*   nbr_h   = (const int*)d_in[3];
    const int*   nbr_w   = (const int*)d_in[4];
    const float* bn_g    = (const float*)d_in[5];
    const float* bn_b    = (const float*)d_in[6];
    const float* Wqkv    = (const float*)d_in[7];
    const float* Wproj   = (const float*)d_in[8];
    const float* bproj   = (const float*)d_in[9];
    const float* bn1_g   = (const float*)d_in[10];
    const float* bn1_b   = (const float*)d_in[11];
    const float* Wk      = (const float*)d_in[12];
    const float* Wh      = (const float*)d_in[13];
    const float* Ww      = (const float*)d_in[14];
    const float* bn2_g   = (const float*)d_in[15];
    const float* bn2_b   = (const float*)d_in[16];
    const float* fc1_W   = (const float*)d_in[17];
    const float* fc1_b   = (const float*)d_in[18];
    const float* fc2_W   = (const float*)d_in[19];
    const float* fc2_b   = (const float*)d_in[20];

    float* F  = (float*)d_out;
    float* R0 = (float*)d_ws;                       // NPTS*256
    float* KV = R0 + (size_t)NPTS * 256;            // NWIN*2048
    float* SB = KV + NWIN * 2048;                   // NWIN*128
    float* ST = SB + NWIN * 128;                    // 6*128
    float* PART = ST + 768;                         // NBLK_STATS*256
    int* HIST = (int*)(PART + NBLK_STATS * 256);    // 256
    int* OFFS = HIST + 256;                         // 256 (201 used)
    int* LIST = OFFS + 256;                         // NPTS
    int* BH   = LIST + NPTS;                        // NBLK_SORT*256
    int* OFFB = BH + NBLK_SORT * 256;               // NBLK_SORT*256

    hipMemcpyAsync(F, feats, (size_t)NPTS * CCH * sizeof(float),
                   hipMemcpyDeviceToDevice, stream);

    dim3 g4(1563, 4), g2(1563, 2);

    for (int d = 0; d < 2; d++) {
        const int* wi = win_inds + (size_t)d * NPTS;
        float* SC0 = ST, *SH0 = ST + 128, *SC1 = ST + 256, *SH1 = ST + 384,
             * SC2 = ST + 512, *SH2 = ST + 640;

        // ---- BN0 ----
        bn_partial<<<NBLK_STATS, 128, 0, stream>>>(F, PART);
        bn_finalize<<<1, 128, 0, stream>>>(PART, bn_g + d * CCH, bn_b + d * CCH, SC0, SH0);

        // ---- k,v = relu/id( bn0(F) @ Wqkv[:,128:384] ) -> R0 ----
        gemm_f32<<<g4, 256, 0, stream>>>(F, CCH, SC0, SH0,
                                         Wqkv + (size_t)d * CCH * 384 + 128, 384, CCH,
                                         nullptr, R0, 256, 128, 0);

        // ---- window lists (contention-free counting sort) ----
        hipMemsetAsync(HIST, 0, 256 * sizeof(int), stream);
        hist2_k<<<NBLK_SORT, 256, 0, stream>>>(wi, BH, HIST);
        scan_k<<<1, 64, 0, stream>>>(HIST, OFFS);
        colscan_k<<<1, 256, 0, stream>>>(BH, OFFS, OFFB);
        scatter2_k<<<NBLK_SORT, 256, 0, stream>>>(wi, OFFB, LIST);

        // ---- per-window KV, S (chunk-parallel, atomic reduce) ----
        hipMemsetAsync(KV, 0, (size_t)(NWIN * 2048 + NWIN * 128) * sizeof(float), stream);
        window_kv_chunk<<<(NPTS + KVCHUNK - 1) / KVCHUNK, 256, 0, stream>>>(
            R0, wi, LIST, KV, SB);

        // ---- q = relu( bn0(F) @ Wqkv[:,0:128] ) -> R0 col 0 (over dead k) ----
        gemm_f32<<<g2, 256, 0, stream>>>(F, CCH, SC0, SH0,
                                         Wqkv + (size_t)d * CCH * 384, 384, CCH,
                                         nullptr, R0, 256, 128, 0);

        // ---- y -> R0 col 128 (over dead v) ----
        attn_y<<<50000, 256, 0, stream>>>(R0, wi, KV, SB, R0);

        // ---- F += y @ Wproj + bproj ----
        gemm_f32<<<g2, 256, 0, stream>>>(R0 + 128, 256, nullptr, nullptr,
                                         Wproj + (size_t)d * CCH * CCH, CCH, CCH,
                                         bproj + d * CCH, F, CCH, 0, 1);

        // ---- BN1 -> FB (R0 col 0..127), F[:,96:] = 2*FB ----
        bn_partial<<<NBLK_STATS, 128, 0, stream>>>(F, PART);
        bn_finalize<<<1, 128, 0, stream>>>(PART, bn1_g + d * CCH, bn1_b + d * CCH, SC1, SH1);
        bn_apply<<<12500, 256, 0, stream>>>(F, R0, SC1, SH1);

        // ---- submanifold convs (residual fused) ----
        conv_g<27><<<3125, 256, 0, stream>>>(nbr_k, Wk + (size_t)d * 27 * 1024, R0, 0,  F, 0);
        conv_g<13><<<3125, 256, 0, stream>>>(nbr_h, Wh + (size_t)d * 13 * 1024, R0, 32, F, 32);
        conv_g<13><<<3125, 256, 0, stream>>>(nbr_w, Ww + (size_t)d * 13 * 1024, R0, 64, F, 64);

        // ---- BN2 + MLP ----
        bn_partial<<<NBLK_STATS, 128, 0, stream>>>(F, PART);
        bn_finalize<<<1, 128, 0, stream>>>(PART, bn2_g + d * CCH, bn2_b + d * CCH, SC2, SH2);

        gemm_f32<<<g4, 256, 0, stream>>>(F, CCH, SC2, SH2,
                                         fc1_W + (size_t)d * CCH * 256, 256, CCH,
                                         fc1_b + d * 256, R0, 256, 256, 0);
        gemm_f32<<<g2, 256, 0, stream>>>(R0, 256, nullptr, nullptr,
                                         fc2_W + (size_t)d * 256 * CCH, CCH, 256,
                                         fc2_b + d * CCH, F, CCH, 0, 1);
    }
}

// Round 4
// 1735.829 us; speedup vs baseline: 2.1308x; 1.2392x over previous
//
#include <hip/hip_runtime.h>
#include <math.h>

#define NPTS 100000
#define CCH 128
#define NWIN 200
#define NBLK_STATS 512
#define KVCHUNK 64
#define NBLK_SORT 391   // ceil(NPTS/256)

#define BM 128
#define BN 64
#define BK 64

typedef __attribute__((ext_vector_type(8))) short bf16x8;
typedef __attribute__((ext_vector_type(4))) float f32x4;
typedef __attribute__((ext_vector_type(4))) unsigned short u16x4;

__device__ __forceinline__ unsigned short f2bf(float f) {
    union { float f; unsigned u; } x; x.f = f;
    unsigned r = x.u + 0x7fff + ((x.u >> 16) & 1);   // RNE (no NaN inputs here)
    return (unsigned short)(r >> 16);
}

// ---------------- BN statistics ----------------
__global__ void bn_partial(const float* __restrict__ F, float* __restrict__ part) {
    int c = threadIdx.x;            // 128 threads: one per channel
    int b = blockIdx.x;
    float s = 0.f, q = 0.f;
    for (int n = b; n < NPTS; n += NBLK_STATS) {
        float v = F[n * CCH + c];
        s += v; q += v * v;
    }
    part[b * 256 + c] = s;
    part[b * 256 + 128 + c] = q;
}

__global__ void bn_finalize(const float* __restrict__ part,
                            const float* __restrict__ g, const float* __restrict__ bb,
                            float* __restrict__ scale, float* __restrict__ shift) {
    int c = threadIdx.x;            // 128 threads
    double s = 0.0, q = 0.0;
    for (int b = 0; b < NBLK_STATS; b++) {
        s += (double)part[b * 256 + c];
        q += (double)part[b * 256 + 128 + c];
    }
    double m = s / (double)NPTS;
    double var = q / (double)NPTS - m * m;
    double rstd = 1.0 / sqrt(var + 1e-3);
    float sc = (float)rstd * g[c];
    scale[c] = sc;
    shift[c] = bb[c] - (float)m * sc;
}

// ---------------- bf16 MFMA GEMM with BN-fold / bias / relu / residual ----------------
// Out[r, col] (= or +=) sum_k A'[r,k] * W[k, col] (+bias); A' = A*scale+shift (per k)
// A,W f32 in global; converted to bf16 (RNE) during LDS staging; f32 accumulate.
__global__ __launch_bounds__(256) void gemm_bf16(
    const float* __restrict__ A, int lda,
    const float* __restrict__ scale, const float* __restrict__ shift,
    const float* __restrict__ W, int ldw, int K,
    const float* __restrict__ bias,
    float* __restrict__ Out, int ldo,
    int reluLim, int addFlag)
{
    __shared__ unsigned short As[BM * BK];   // [128][64] bf16, slot-XOR-swizzled
    __shared__ unsigned short Bs[BN * BK];   // [64][64] = B^T (col-major W), swizzled

    const int tid  = threadIdx.x;
    const int wave = tid >> 6;
    const int lane = tid & 63;
    const int bm = blockIdx.x * BM;
    const int bn = blockIdx.y * BN;

    f32x4 acc[2][4];
#pragma unroll
    for (int i = 0; i < 2; i++)
#pragma unroll
        for (int j = 0; j < 4; j++)
            acc[i][j] = (f32x4){0.f, 0.f, 0.f, 0.f};

    const int arow_t = tid >> 4;          // 0..15
    const int acol   = (tid & 15) * 4;    // 0..60
    const int kq = (tid >> 4) * 4;        // B micro-tile k0
    const int cq = (tid & 15) * 4;        // B micro-tile col0
    const int lrow = lane & 15;
    const int lhk  = lane >> 4;           // 0..3

    for (int kk = 0; kk < K; kk += BK) {
        // ---- stage A: 8 passes x (16 rows x 64 k), fold BN, cvt bf16 ----
#pragma unroll
        for (int pass = 0; pass < 8; pass++) {
            int row = pass * 16 + arow_t;
            int grow = bm + row;
            float4 v = make_float4(0.f, 0.f, 0.f, 0.f);
            if (grow < NPTS)
                v = *reinterpret_cast<const float4*>(&A[(size_t)grow * lda + kk + acol]);
            if (scale) {
                v.x = v.x * scale[kk + acol + 0] + shift[kk + acol + 0];
                v.y = v.y * scale[kk + acol + 1] + shift[kk + acol + 1];
                v.z = v.z * scale[kk + acol + 2] + shift[kk + acol + 2];
                v.w = v.w * scale[kk + acol + 3] + shift[kk + acol + 3];
            }
            u16x4 h = { f2bf(v.x), f2bf(v.y), f2bf(v.z), f2bf(v.w) };
            int s = acol >> 3;                       // 16B slot (0..7)
            int sw = s ^ (row & 7);
            *reinterpret_cast<u16x4*>(&As[row * 64 + sw * 8 + (acol & 7)]) = h;
        }
        // ---- stage B: 4x4 micro-transpose -> Bs[col][k] ----
        {
            float4 wv[4];
#pragma unroll
            for (int i = 0; i < 4; i++)
                wv[i] = *reinterpret_cast<const float4*>(&W[(size_t)(kk + kq + i) * ldw + bn + cq]);
            const float* wp = reinterpret_cast<const float*>(wv);
#pragma unroll
            for (int j = 0; j < 4; j++) {
                int col = cq + j;
                u16x4 h = { f2bf(wp[0 * 4 + j]), f2bf(wp[1 * 4 + j]),
                            f2bf(wp[2 * 4 + j]), f2bf(wp[3 * 4 + j]) };
                int s = kq >> 3;
                int sw = s ^ (col & 7);
                *reinterpret_cast<u16x4*>(&Bs[col * 64 + sw * 8 + (kq & 7)]) = h;
            }
        }
        __syncthreads();

        // ---- compute: 2 k-steps of 32 ----
#pragma unroll
        for (int ks = 0; ks < 2; ks++) {
            bf16x8 af[2], bfr[4];
#pragma unroll
            for (int fi = 0; fi < 2; fi++) {
                int row = wave * 32 + fi * 16 + lrow;
                int sw = (ks * 4 + lhk) ^ (row & 7);
                af[fi] = *reinterpret_cast<const bf16x8*>(&As[row * 64 + sw * 8]);
            }
#pragma unroll
            for (int fj = 0; fj < 4; fj++) {
                int col = fj * 16 + lrow;
                int sw = (ks * 4 + lhk) ^ (col & 7);
                bfr[fj] = *reinterpret_cast<const bf16x8*>(&Bs[col * 64 + sw * 8]);
            }
#pragma unroll
            for (int fi = 0; fi < 2; fi++)
#pragma unroll
                for (int fj = 0; fj < 4; fj++)
                    acc[fi][fj] = __builtin_amdgcn_mfma_f32_16x16x32_bf16(
                        af[fi], bfr[fj], acc[fi][fj], 0, 0, 0);
        }
        __syncthreads();
    }

    // ---- epilogue: bias / relu / residual, f32 store ----
#pragma unroll
    for (int fi = 0; fi < 2; fi++) {
        int grow0 = bm + wave * 32 + fi * 16 + (lane >> 4) * 4;
#pragma unroll
        for (int fj = 0; fj < 4; fj++) {
            int col = bn + fj * 16 + (lane & 15);
            float bv = bias ? bias[col] : 0.f;
            bool rl = (col < reluLim);
#pragma unroll
            for (int r = 0; r < 4; r++) {
                int rr = grow0 + r;
                if (rr >= NPTS) continue;
                float v = acc[fi][fj][r] + bv;
                if (rl) v = fmaxf(v, 0.f);
                float* o = &Out[(size_t)rr * ldo + col];
                if (addFlag) *o += v; else *o = v;
            }
        }
    }
}

// ---------------- window list build (block-local counting sort) ----------------
__global__ __launch_bounds__(256) void hist2_k(const int* __restrict__ wi,
                                               int* __restrict__ BH, int* __restrict__ HIST) {
    __shared__ int h[NWIN];
    int t = threadIdx.x;
    if (t < NWIN) h[t] = 0;
    __syncthreads();
    int n = blockIdx.x * 256 + t;
    if (n < NPTS) atomicAdd(&h[wi[n]], 1);
    __syncthreads();
    if (t < NWIN) {
        BH[blockIdx.x * 256 + t] = h[t];
        if (h[t]) atomicAdd(&HIST[t], h[t]);
    }
}

__global__ void scan_k(const int* __restrict__ hist, int* __restrict__ offs) {
    if (threadIdx.x == 0 && blockIdx.x == 0) {
        int a = 0;
        for (int w = 0; w < NWIN; w++) { offs[w] = a; a += hist[w]; }
        offs[NWIN] = a;
    }
}

__global__ void colscan_k(const int* __restrict__ BH, const int* __restrict__ OFFS,
                          int* __restrict__ OFFB) {
    int w = threadIdx.x;
    if (w >= NWIN) return;
    int a = OFFS[w];
    for (int b = 0; b < NBLK_SORT; b++) {
        OFFB[b * 256 + w] = a;
        a += BH[b * 256 + w];
    }
}

__global__ __launch_bounds__(256) void scatter2_k(const int* __restrict__ wi,
                                                  const int* __restrict__ OFFB,
                                                  int* __restrict__ list) {
    __shared__ int h[NWIN];
    int t = threadIdx.x;
    if (t < NWIN) h[t] = 0;
    __syncthreads();
    int n = blockIdx.x * 256 + t;
    if (n < NPTS) {
        int w = wi[n];
        int r = atomicAdd(&h[w], 1);
        list[OFFB[blockIdx.x * 256 + w] + r] = n;
    }
}

// ---------------- chunk-parallel per-window K^T V and sum(K) ----------------
__global__ __launch_bounds__(256) void window_kv_chunk(
    const float* __restrict__ R0,
    const int* __restrict__ wi,
    const int* __restrict__ list,
    float* __restrict__ KV, float* __restrict__ SB)
{
    int t = threadIdx.x;
    int p0 = blockIdx.x * KVCHUNK;
    int p1 = min(p0 + KVCHUNK, NPTS);
    __shared__ float kb[128], vb[128];
    float acc[8] = {0.f,0.f,0.f,0.f,0.f,0.f,0.f,0.f};
    float sa = 0.f;
    int f0 = t * 8;
    int h = f0 >> 8;
    int c = (f0 >> 4) & 15;
    int d0 = f0 & 15;
    int curw = -1;
    for (int p = p0; p < p1; p++) {
        int n = list[p];
        int w = wi[n];
        if (w != curw) {
            if (curw >= 0) {
#pragma unroll
                for (int i = 0; i < 8; i++) {
                    atomicAdd(&KV[curw * 2048 + f0 + i], acc[i]);
                    acc[i] = 0.f;
                }
                if (t < 128) { atomicAdd(&SB[curw * 128 + t], sa); sa = 0.f; }
            }
            curw = w;
        }
        if (t < 128) kb[t] = R0[n * 256 + t];
        else         vb[t - 128] = R0[n * 256 + 128 + (t - 128)];
        __syncthreads();
        float kc = kb[h * 16 + c];
#pragma unroll
        for (int i = 0; i < 8; i++) acc[i] += kc * vb[h * 16 + d0 + i];
        if (t < 128) sa += kb[t];
        __syncthreads();
    }
    if (curw >= 0) {
#pragma unroll
        for (int i = 0; i < 8; i++) atomicAdd(&KV[curw * 2048 + f0 + i], acc[i]);
        if (t < 128) atomicAdd(&SB[curw * 128 + t], sa);
    }
}

// ---------------- y = (q . kv[w]) / (q . s[w] + eps) ----------------
__global__ __launch_bounds__(256) void attn_y(
    const float* Q, const int* __restrict__ wi,
    const float* __restrict__ KV, const float* __restrict__ SB,
    float* Y)
{
    __shared__ float qs[2][128];
    int half = threadIdx.x >> 7;
    int c = threadIdx.x & 127;
    int pt = blockIdx.x * 2 + half;
    if (pt < NPTS) qs[half][c] = Q[pt * 256 + c];
    __syncthreads();
    if (pt >= NPTS) return;
    int w = wi[pt];
    int h = c >> 4, dd = c & 15;
    const float* qh = &qs[half][h * 16];
    const float* kvw = &KV[w * 2048 + h * 256];
    const float* sw = &SB[w * 128 + h * 16];
    float z = 0.f, y = 0.f;
#pragma unroll
    for (int cc = 0; cc < 16; cc++) {
        z += sw[cc] * qh[cc];
        y += qh[cc] * kvw[cc * 16 + dd];
    }
    Y[pt * 256 + 128 + c] = y / (z + 1e-3f);
}

// ---------------- bn apply: FB = bn1(F); F[:,96:128] = 2*FB ----------------
__global__ void bn_apply(float* F, float* FB,
                         const float* __restrict__ scale, const float* __restrict__ shift)
{
    int i = blockIdx.x * 256 + threadIdx.x;
    int n = i >> 5;
    int c4 = (i & 31) * 4;
    float4 v = *reinterpret_cast<const float4*>(&F[n * CCH + c4]);
    float4 o;
    o.x = v.x * scale[c4 + 0] + shift[c4 + 0];
    o.y = v.y * scale[c4 + 1] + shift[c4 + 1];
    o.z = v.z * scale[c4 + 2] + shift[c4 + 2];
    o.w = v.w * scale[c4 + 3] + shift[c4 + 3];
    *reinterpret_cast<float4*>(&FB[n * 256 + c4]) = o;
    if (c4 >= 96) {
        float4 t = make_float4(2.f * o.x, 2.f * o.y, 2.f * o.z, 2.f * o.w);
        *reinterpret_cast<float4*>(&F[n * CCH + c4]) = t;
    }
}

// ---------------- submanifold conv ----------------
template<int KN>
__global__ __launch_bounds__(256) void conv_g(
    const int* __restrict__ nbr, const float* __restrict__ Wc,
    const float* __restrict__ FB, int goff,
    float* __restrict__ Fout, int outoff)
{
    int t = blockIdx.x * 256 + threadIdx.x;
    int pt = t >> 3;
    int so = (t & 7) * 4;
    if (pt >= NPTS) return;
    float acc0 = 0.f, acc1 = 0.f, acc2 = 0.f, acc3 = 0.f;
    const int* nb = &nbr[pt * KN];
#pragma unroll 1
    for (int k = 0; k < KN; k++) {
        int idx = nb[k];
        if (idx >= NPTS) continue;   // sentinel row = zeros
        const float* rr = &FB[idx * 256 + goff];
        const float* wk = &Wc[k * 1024 + so];
#pragma unroll
        for (int c = 0; c < 32; c += 4) {
            float4 rv = *reinterpret_cast<const float4*>(&rr[c]);
            float4 w0 = *reinterpret_cast<const float4*>(&wk[(c + 0) * 32]);
            float4 w1 = *reinterpret_cast<const float4*>(&wk[(c + 1) * 32]);
            float4 w2 = *reinterpret_cast<const float4*>(&wk[(c + 2) * 32]);
            float4 w3 = *reinterpret_cast<const float4*>(&wk[(c + 3) * 32]);
            acc0 += rv.x * w0.x + rv.y * w1.x + rv.z * w2.x + rv.w * w3.x;
            acc1 += rv.x * w0.y + rv.y * w1.y + rv.z * w2.y + rv.w * w3.y;
            acc2 += rv.x * w0.z + rv.y * w1.z + rv.z * w2.z + rv.w * w3.z;
            acc3 += rv.x * w0.w + rv.y * w1.w + rv.z * w2.w + rv.w * w3.w;
        }
    }
    float4 fb = *reinterpret_cast<const float4*>(&FB[pt * 256 + goff + so]);
    float4 o = make_float4(fb.x + acc0, fb.y + acc1, fb.z + acc2, fb.w + acc3);
    *reinterpret_cast<float4*>(&Fout[pt * CCH + outoff + so]) = o;
}

// ---------------- launch ----------------
extern "C" void kernel_launch(void* const* d_in, const int* in_sizes, int n_in,
                              void* d_out, int out_size, void* d_ws, size_t ws_size,
                              hipStream_t stream)
{
    const float* feats   = (const float*)d_in[0];
    const int*   win_inds= (const int*)d_in[1];
    const int*   nbr_k   = (const int*)d_in[2];
    const int*   nbr_h   = (const int*)d_in[3];
    const int*   nbr_w   = (const int*)d_in[4];
    const float* bn_g    = (const float*)d_in[5];
    const float* bn_b    = (const float*)d_in[6];
    const float* Wqkv    = (const float*)d_in[7];
    const float* Wproj   = (const float*)d_in[8];
    const float* bproj   = (const float*)d_in[9];
    const float* bn1_g   = (const float*)d_in[10];
    const float* bn1_b   = (const float*)d_in[11];
    const float* Wk      = (const float*)d_in[12];
    const float* Wh      = (const float*)d_in[13];
    const float* Ww      = (const float*)d_in[14];
    const float* bn2_g   = (const float*)d_in[15];
    const float* bn2_b   = (const float*)d_in[16];
    const float* fc1_W   = (const float*)d_in[17];
    const float* fc1_b   = (const float*)d_in[18];
    const float* fc2_W   = (const float*)d_in[19];
    const float* fc2_b   = (const float*)d_in[20];

    float* F  = (float*)d_out;
    float* R0 = (float*)d_ws;                       // NPTS*256
    float* KV = R0 + (size_t)NPTS * 256;            // NWIN*2048
    float* SB = KV + NWIN * 2048;                   // NWIN*128
    float* ST = SB + NWIN * 128;                    // 6*128
    float* PART = ST + 768;                         // NBLK_STATS*256
    int* HIST = (int*)(PART + NBLK_STATS * 256);    // 256
    int* OFFS = HIST + 256;                         // 256 (201 used)
    int* LIST = OFFS + 256;                         // NPTS
    int* BH   = LIST + NPTS;                        // NBLK_SORT*256
    int* OFFB = BH + NBLK_SORT * 256;               // NBLK_SORT*256

    hipMemcpyAsync(F, feats, (size_t)NPTS * CCH * sizeof(float),
                   hipMemcpyDeviceToDevice, stream);

    dim3 gA(782, 4), gB(782, 2);    // 782 = ceil(100000/128)

    for (int d = 0; d < 2; d++) {
        const int* wi = win_inds + (size_t)d * NPTS;
        float* SC0 = ST, *SH0 = ST + 128, *SC1 = ST + 256, *SH1 = ST + 384,
             * SC2 = ST + 512, *SH2 = ST + 640;

        // ---- BN0 ----
        bn_partial<<<NBLK_STATS, 128, 0, stream>>>(F, PART);
        bn_finalize<<<1, 128, 0, stream>>>(PART, bn_g + d * CCH, bn_b + d * CCH, SC0, SH0);

        // ---- k,v = relu/id( bn0(F) @ Wqkv[:,128:384] ) -> R0 ----
        gemm_bf16<<<gA, 256, 0, stream>>>(F, CCH, SC0, SH0,
                                          Wqkv + (size_t)d * CCH * 384 + 128, 384, CCH,
                                          nullptr, R0, 256, 128, 0);

        // ---- window lists (contention-free counting sort) ----
        hipMemsetAsync(HIST, 0, 256 * sizeof(int), stream);
        hist2_k<<<NBLK_SORT, 256, 0, stream>>>(wi, BH, HIST);
        scan_k<<<1, 64, 0, stream>>>(HIST, OFFS);
        colscan_k<<<1, 256, 0, stream>>>(BH, OFFS, OFFB);
        scatter2_k<<<NBLK_SORT, 256, 0, stream>>>(wi, OFFB, LIST);

        // ---- per-window KV, S (chunk-parallel, atomic reduce) ----
        hipMemsetAsync(KV, 0, (size_t)(NWIN * 2048 + NWIN * 128) * sizeof(float), stream);
        window_kv_chunk<<<(NPTS + KVCHUNK - 1) / KVCHUNK, 256, 0, stream>>>(
            R0, wi, LIST, KV, SB);

        // ---- q = relu( bn0(F) @ Wqkv[:,0:128] ) -> R0 col 0 (over dead k) ----
        gemm_bf16<<<gB, 256, 0, stream>>>(F, CCH, SC0, SH0,
                                          Wqkv + (size_t)d * CCH * 384, 384, CCH,
                                          nullptr, R0, 256, 128, 0);

        // ---- y -> R0 col 128 (over dead v) ----
        attn_y<<<50000, 256, 0, stream>>>(R0, wi, KV, SB, R0);

        // ---- F += y @ Wproj + bproj ----
        gemm_bf16<<<gB, 256, 0, stream>>>(R0 + 128, 256, nullptr, nullptr,
                                          Wproj + (size_t)d * CCH * CCH, CCH, CCH,
                                          bproj + d * CCH, F, CCH, 0, 1);

        // ---- BN1 -> FB (R0 col 0..127), F[:,96:] = 2*FB ----
        bn_partial<<<NBLK_STATS, 128, 0, stream>>>(F, PART);
        bn_finalize<<<1, 128, 0, stream>>>(PART, bn1_g + d * CCH, bn1_b + d * CCH, SC1, SH1);
        bn_apply<<<12500, 256, 0, stream>>>(F, R0, SC1, SH1);

        // ---- submanifold convs (residual fused) ----
        conv_g<27><<<3125, 256, 0, stream>>>(nbr_k, Wk + (size_t)d * 27 * 1024, R0, 0,  F, 0);
        conv_g<13><<<3125, 256, 0, stream>>>(nbr_h, Wh + (size_t)d * 13 * 1024, R0, 32, F, 32);
        conv_g<13><<<3125, 256, 0, stream>>>(nbr_w, Ww + (size_t)d * 13 * 1024, R0, 64, F, 64);

        // ---- BN2 + MLP ----
        bn_partial<<<NBLK_STATS, 128, 0, stream>>>(F, PART);
        bn_finalize<<<1, 128, 0, stream>>>(PART, bn2_g + d * CCH, bn2_b + d * CCH, SC2, SH2);

        gemm_bf16<<<gA, 256, 0, stream>>>(F, CCH, SC2, SH2,
                                          fc1_W + (size_t)d * CCH * 256, 256, CCH,
                                          fc1_b + d * 256, R0, 256, 256, 0);
        gemm_bf16<<<gB, 256, 0, stream>>>(R0, 256, nullptr, nullptr,
                                          fc2_W + (size_t)d * 256 * CCH, CCH, 256,
                                          fc2_b + d * CCH, F, CCH, 0, 1);
    }
}

// Round 5
// 1675.829 us; speedup vs baseline: 2.2071x; 1.0358x over previous
//
#include <hip/hip_runtime.h>
#include <math.h>

#define NPTS 100000
#define CCH 128
#define NWIN 200
#define NBLK_STATS 512
#define KVCHUNK 128
#define NBLK_SORT 391   // ceil(NPTS/256)

#define BM 128
#define BN 64
#define BK 64

typedef __attribute__((ext_vector_type(8))) short bf16x8;
typedef __attribute__((ext_vector_type(4))) float f32x4;
typedef __attribute__((ext_vector_type(4))) unsigned short u16x4;

__device__ __forceinline__ unsigned short f2bf(float f) {
    union { float f; unsigned u; } x; x.f = f;
    unsigned r = x.u + 0x7fff + ((x.u >> 16) & 1);   // RNE (no NaN inputs here)
    return (unsigned short)(r >> 16);
}

// ---------------- BN statistics ----------------
__global__ void bn_partial(const float* __restrict__ F, float* __restrict__ part) {
    int c = threadIdx.x;            // 128 threads: one per channel
    int b = blockIdx.x;
    float s = 0.f, q = 0.f;
    for (int n = b; n < NPTS; n += NBLK_STATS) {
        float v = F[n * CCH + c];
        s += v; q += v * v;
    }
    part[b * 256 + c] = s;
    part[b * 256 + 128 + c] = q;
}

__global__ void bn_finalize(const float* __restrict__ part,
                            const float* __restrict__ g, const float* __restrict__ bb,
                            float* __restrict__ scale, float* __restrict__ shift) {
    int c = threadIdx.x;            // 128 threads
    double s = 0.0, q = 0.0;
    for (int b = 0; b < NBLK_STATS; b++) {
        s += (double)part[b * 256 + c];
        q += (double)part[b * 256 + 128 + c];
    }
    double m = s / (double)NPTS;
    double var = q / (double)NPTS - m * m;
    double rstd = 1.0 / sqrt(var + 1e-3);
    float sc = (float)rstd * g[c];
    scale[c] = sc;
    shift[c] = bb[c] - (float)m * sc;
}

// ---------------- bf16 MFMA GEMM with BN-fold / bias / relu / residual ----------------
__global__ __launch_bounds__(256) void gemm_bf16(
    const float* __restrict__ A, int lda,
    const float* __restrict__ scale, const float* __restrict__ shift,
    const float* __restrict__ W, int ldw, int K,
    const float* __restrict__ bias,
    float* __restrict__ Out, int ldo,
    int reluLim, int addFlag)
{
    __shared__ unsigned short As[BM * BK];   // [128][64] bf16, slot-XOR-swizzled
    __shared__ unsigned short Bs[BN * BK];   // [64][64] = B^T (col-major W), swizzled

    const int tid  = threadIdx.x;
    const int wave = tid >> 6;
    const int lane = tid & 63;
    const int bm = blockIdx.x * BM;
    const int bn = blockIdx.y * BN;

    f32x4 acc[2][4];
#pragma unroll
    for (int i = 0; i < 2; i++)
#pragma unroll
        for (int j = 0; j < 4; j++)
            acc[i][j] = (f32x4){0.f, 0.f, 0.f, 0.f};

    const int arow_t = tid >> 4;          // 0..15
    const int acol   = (tid & 15) * 4;    // 0..60
    const int kq = (tid >> 4) * 4;        // B micro-tile k0
    const int cq = (tid & 15) * 4;        // B micro-tile col0
    const int lrow = lane & 15;
    const int lhk  = lane >> 4;           // 0..3

    for (int kk = 0; kk < K; kk += BK) {
#pragma unroll
        for (int pass = 0; pass < 8; pass++) {
            int row = pass * 16 + arow_t;
            int grow = bm + row;
            float4 v = make_float4(0.f, 0.f, 0.f, 0.f);
            if (grow < NPTS)
                v = *reinterpret_cast<const float4*>(&A[(size_t)grow * lda + kk + acol]);
            if (scale) {
                v.x = v.x * scale[kk + acol + 0] + shift[kk + acol + 0];
                v.y = v.y * scale[kk + acol + 1] + shift[kk + acol + 1];
                v.z = v.z * scale[kk + acol + 2] + shift[kk + acol + 2];
                v.w = v.w * scale[kk + acol + 3] + shift[kk + acol + 3];
            }
            u16x4 h = { f2bf(v.x), f2bf(v.y), f2bf(v.z), f2bf(v.w) };
            int s = acol >> 3;                       // 16B slot (0..7)
            int sw = s ^ (row & 7);
            *reinterpret_cast<u16x4*>(&As[row * 64 + sw * 8 + (acol & 7)]) = h;
        }
        {
            float4 wv[4];
#pragma unroll
            for (int i = 0; i < 4; i++)
                wv[i] = *reinterpret_cast<const float4*>(&W[(size_t)(kk + kq + i) * ldw + bn + cq]);
            const float* wp = reinterpret_cast<const float*>(wv);
#pragma unroll
            for (int j = 0; j < 4; j++) {
                int col = cq + j;
                u16x4 h = { f2bf(wp[0 * 4 + j]), f2bf(wp[1 * 4 + j]),
                            f2bf(wp[2 * 4 + j]), f2bf(wp[3 * 4 + j]) };
                int s = kq >> 3;
                int sw = s ^ (col & 7);
                *reinterpret_cast<u16x4*>(&Bs[col * 64 + sw * 8 + (kq & 7)]) = h;
            }
        }
        __syncthreads();

#pragma unroll
        for (int ks = 0; ks < 2; ks++) {
            bf16x8 af[2], bfr[4];
#pragma unroll
            for (int fi = 0; fi < 2; fi++) {
                int row = wave * 32 + fi * 16 + lrow;
                int sw = (ks * 4 + lhk) ^ (row & 7);
                af[fi] = *reinterpret_cast<const bf16x8*>(&As[row * 64 + sw * 8]);
            }
#pragma unroll
            for (int fj = 0; fj < 4; fj++) {
                int col = fj * 16 + lrow;
                int sw = (ks * 4 + lhk) ^ (col & 7);
                bfr[fj] = *reinterpret_cast<const bf16x8*>(&Bs[col * 64 + sw * 8]);
            }
#pragma unroll
            for (int fi = 0; fi < 2; fi++)
#pragma unroll
                for (int fj = 0; fj < 4; fj++)
                    acc[fi][fj] = __builtin_amdgcn_mfma_f32_16x16x32_bf16(
                        af[fi], bfr[fj], acc[fi][fj], 0, 0, 0);
        }
        __syncthreads();
    }

#pragma unroll
    for (int fi = 0; fi < 2; fi++) {
        int grow0 = bm + wave * 32 + fi * 16 + (lane >> 4) * 4;
#pragma unroll
        for (int fj = 0; fj < 4; fj++) {
            int col = bn + fj * 16 + (lane & 15);
            float bv = bias ? bias[col] : 0.f;
            bool rl = (col < reluLim);
#pragma unroll
            for (int r = 0; r < 4; r++) {
                int rr = grow0 + r;
                if (rr >= NPTS) continue;
                float v = acc[fi][fj][r] + bv;
                if (rl) v = fmaxf(v, 0.f);
                float* o = &Out[(size_t)rr * ldo + col];
                if (addFlag) *o += v; else *o = v;
            }
        }
    }
}

// ---------------- window list build (block-local counting sort) ----------------
__global__ __launch_bounds__(256) void hist2_k(const int* __restrict__ wi,
                                               int* __restrict__ BH, int* __restrict__ HIST) {
    __shared__ int h[NWIN];
    int t = threadIdx.x;
    if (t < NWIN) h[t] = 0;
    __syncthreads();
    int n = blockIdx.x * 256 + t;
    if (n < NPTS) atomicAdd(&h[wi[n]], 1);
    __syncthreads();
    if (t < NWIN) {
        BH[blockIdx.x * 256 + t] = h[t];
        if (h[t]) atomicAdd(&HIST[t], h[t]);
    }
}

__global__ void scan_k(const int* __restrict__ hist, int* __restrict__ offs) {
    if (threadIdx.x == 0 && blockIdx.x == 0) {
        int a = 0;
        for (int w = 0; w < NWIN; w++) { offs[w] = a; a += hist[w]; }
        offs[NWIN] = a;
    }
}

__global__ void colscan_k(const int* __restrict__ BH, const int* __restrict__ OFFS,
                          int* __restrict__ OFFB) {
    int w = threadIdx.x;
    if (w >= NWIN) return;
    int a = OFFS[w];
    for (int b = 0; b < NBLK_SORT; b++) {
        OFFB[b * 256 + w] = a;
        a += BH[b * 256 + w];
    }
}

__global__ __launch_bounds__(256) void scatter2_k(const int* __restrict__ wi,
                                                  const int* __restrict__ OFFB,
                                                  int* __restrict__ list,
                                                  int* __restrict__ wsort) {
    __shared__ int h[NWIN];
    int t = threadIdx.x;
    if (t < NWIN) h[t] = 0;
    __syncthreads();
    int n = blockIdx.x * 256 + t;
    if (n < NPTS) {
        int w = wi[n];
        int r = atomicAdd(&h[w], 1);
        int p = OFFB[blockIdx.x * 256 + w] + r;
        list[p] = n;
        wsort[p] = w;
    }
}

// ---------------- chunk-parallel per-window K^T V and sum(K), 8-point pipelined ----------------
// R0 rows: [k(128) | v(128)], ld 256. Each block: KVCHUNK points in groups of 8;
// 8 rows staged per barrier-pair (8 loads in flight), flush per window via atomicAdd.
__global__ __launch_bounds__(256) void window_kv_chunk(
    const float* __restrict__ R0,
    const int* __restrict__ list,
    const int* __restrict__ wsort,
    float* __restrict__ KV, float* __restrict__ SB)
{
    int t = threadIdx.x;
    int p0 = blockIdx.x * KVCHUNK;
    int p1 = min(p0 + KVCHUNK, NPTS);
    __shared__ float buf[8][256];
    float acc[8] = {0.f,0.f,0.f,0.f,0.f,0.f,0.f,0.f};
    float sa = 0.f;
    int f0 = t * 8;
    int h = f0 >> 8;
    int c = (f0 >> 4) & 15;
    int d0 = f0 & 15;
    int curw = -1;

    for (int g = p0; g < p1; g += 8) {
        int m = min(8, p1 - g);
        int nj[8], wj[8];
#pragma unroll
        for (int j = 0; j < 8; j++) {
            int p = (g + j < p1) ? g + j : p1 - 1;
            nj[j] = list[p];
            wj[j] = wsort[p];
        }
        __syncthreads();   // buf free (previous group consumed)
#pragma unroll
        for (int j = 0; j < 8; j++)
            if (j < m) buf[j][t] = R0[(size_t)nj[j] * 256 + t];
        __syncthreads();
#pragma unroll
        for (int j = 0; j < 8; j++) {
            if (j >= m) break;
            int w = wj[j];
            if (w != curw) {
                if (curw >= 0) {
#pragma unroll
                    for (int i = 0; i < 8; i++) {
                        atomicAdd(&KV[curw * 2048 + f0 + i], acc[i]);
                        acc[i] = 0.f;
                    }
                    if (t < 128) { atomicAdd(&SB[curw * 128 + t], sa); sa = 0.f; }
                }
                curw = w;
            }
            float kc = buf[j][h * 16 + c];
#pragma unroll
            for (int i = 0; i < 8; i++) acc[i] += kc * buf[j][128 + h * 16 + d0 + i];
            if (t < 128) sa += buf[j][t];
        }
    }
    if (curw >= 0) {
#pragma unroll
        for (int i = 0; i < 8; i++) atomicAdd(&KV[curw * 2048 + f0 + i], acc[i]);
        if (t < 128) atomicAdd(&SB[curw * 128 + t], sa);
    }
}

// ---------------- y = (q . kv[w]) / (q . s[w] + eps) ----------------
__global__ __launch_bounds__(256) void attn_y(
    const float* Q, const int* __restrict__ wi,
    const float* __restrict__ KV, const float* __restrict__ SB,
    float* Y)
{
    __shared__ float qs[2][128];
    int half = threadIdx.x >> 7;
    int c = threadIdx.x & 127;
    int pt = blockIdx.x * 2 + half;
    if (pt < NPTS) qs[half][c] = Q[pt * 256 + c];
    __syncthreads();
    if (pt >= NPTS) return;
    int w = wi[pt];
    int h = c >> 4, dd = c & 15;
    const float* qh = &qs[half][h * 16];
    const float* kvw = &KV[w * 2048 + h * 256];
    const float* sw = &SB[w * 128 + h * 16];
    float z = 0.f, y = 0.f;
#pragma unroll
    for (int cc = 0; cc < 16; cc++) {
        z += sw[cc] * qh[cc];
        y += qh[cc] * kvw[cc * 16 + dd];
    }
    Y[pt * 256 + 128 + c] = y / (z + 1e-3f);
}

// ---------------- bn apply: FB = bn1(F); F[:,96:128] = 2*FB ----------------
__global__ void bn_apply(float* F, float* FB,
                         const float* __restrict__ scale, const float* __restrict__ shift)
{
    int i = blockIdx.x * 256 + threadIdx.x;
    int n = i >> 5;
    int c4 = (i & 31) * 4;
    float4 v = *reinterpret_cast<const float4*>(&F[n * CCH + c4]);
    float4 o;
    o.x = v.x * scale[c4 + 0] + shift[c4 + 0];
    o.y = v.y * scale[c4 + 1] + shift[c4 + 1];
    o.z = v.z * scale[c4 + 2] + shift[c4 + 2];
    o.w = v.w * scale[c4 + 3] + shift[c4 + 3];
    *reinterpret_cast<float4*>(&FB[n * 256 + c4]) = o;
    if (c4 >= 96) {
        float4 t = make_float4(2.f * o.x, 2.f * o.y, 2.f * o.z, 2.f * o.w);
        *reinterpret_cast<float4*>(&F[n * CCH + c4]) = t;
    }
}

// ---------------- submanifold conv ----------------
template<int KN>
__global__ __launch_bounds__(256) void conv_g(
    const int* __restrict__ nbr, const float* __restrict__ Wc,
    const float* __restrict__ FB, int goff,
    float* __restrict__ Fout, int outoff)
{
    int t = blockIdx.x * 256 + threadIdx.x;
    int pt = t >> 3;
    int so = (t & 7) * 4;
    if (pt >= NPTS) return;
    float acc0 = 0.f, acc1 = 0.f, acc2 = 0.f, acc3 = 0.f;
    const int* nb = &nbr[pt * KN];
#pragma unroll 1
    for (int k = 0; k < KN; k++) {
        int idx = nb[k];
        if (idx >= NPTS) continue;   // sentinel row = zeros
        const float* rr = &FB[idx * 256 + goff];
        const float* wk = &Wc[k * 1024 + so];
#pragma unroll
        for (int c = 0; c < 32; c += 4) {
            float4 rv = *reinterpret_cast<const float4*>(&rr[c]);
            float4 w0 = *reinterpret_cast<const float4*>(&wk[(c + 0) * 32]);
            float4 w1 = *reinterpret_cast<const float4*>(&wk[(c + 1) * 32]);
            float4 w2 = *reinterpret_cast<const float4*>(&wk[(c + 2) * 32]);
            float4 w3 = *reinterpret_cast<const float4*>(&wk[(c + 3) * 32]);
            acc0 += rv.x * w0.x + rv.y * w1.x + rv.z * w2.x + rv.w * w3.x;
            acc1 += rv.x * w0.y + rv.y * w1.y + rv.z * w2.y + rv.w * w3.y;
            acc2 += rv.x * w0.z + rv.y * w1.z + rv.z * w2.z + rv.w * w3.z;
            acc3 += rv.x * w0.w + rv.y * w1.w + rv.z * w2.w + rv.w * w3.w;
        }
    }
    float4 fb = *reinterpret_cast<const float4*>(&FB[pt * 256 + goff + so]);
    float4 o = make_float4(fb.x + acc0, fb.y + acc1, fb.z + acc2, fb.w + acc3);
    *reinterpret_cast<float4*>(&Fout[pt * CCH + outoff + so]) = o;
}

// ---------------- launch ----------------
extern "C" void kernel_launch(void* const* d_in, const int* in_sizes, int n_in,
                              void* d_out, int out_size, void* d_ws, size_t ws_size,
                              hipStream_t stream)
{
    const float* feats   = (const float*)d_in[0];
    const int*   win_inds= (const int*)d_in[1];
    const int*   nbr_k   = (const int*)d_in[2];
    const int*   nbr_h   = (const int*)d_in[3];
    const int*   nbr_w   = (const int*)d_in[4];
    const float* bn_g    = (const float*)d_in[5];
    const float* bn_b    = (const float*)d_in[6];
    const float* Wqkv    = (const float*)d_in[7];
    const float* Wproj   = (const float*)d_in[8];
    const float* bproj   = (const float*)d_in[9];
    const float* bn1_g   = (const float*)d_in[10];
    const float* bn1_b   = (const float*)d_in[11];
    const float* Wk      = (const float*)d_in[12];
    const float* Wh      = (const float*)d_in[13];
    const float* Ww      = (const float*)d_in[14];
    const float* bn2_g   = (const float*)d_in[15];
    const float* bn2_b   = (const float*)d_in[16];
    const float* fc1_W   = (const float*)d_in[17];
    const float* fc1_b   = (const float*)d_in[18];
    const float* fc2_W   = (const float*)d_in[19];
    const float* fc2_b   = (const float*)d_in[20];

    float* F  = (float*)d_out;
    float* R0 = (float*)d_ws;                       // NPTS*256
    float* KV = R0 + (size_t)NPTS * 256;            // NWIN*2048
    float* SB = KV + NWIN * 2048;                   // NWIN*128
    float* ST = SB + NWIN * 128;                    // 6*128
    float* PART = ST + 768;                         // NBLK_STATS*256
    int* HIST = (int*)(PART + NBLK_STATS * 256);    // 256
    int* OFFS = HIST + 256;                         // 256 (201 used)
    int* LIST = OFFS + 256;                         // NPTS
    int* BH   = LIST + NPTS;                        // NBLK_SORT*256
    int* OFFB = BH + NBLK_SORT * 256;               // NBLK_SORT*256
    int* WSORT= OFFB + NBLK_SORT * 256;             // NPTS

    hipMemcpyAsync(F, feats, (size_t)NPTS * CCH * sizeof(float),
                   hipMemcpyDeviceToDevice, stream);

    dim3 gA(782, 4), gB(782, 2);    // 782 = ceil(100000/128)

    for (int d = 0; d < 2; d++) {
        const int* wi = win_inds + (size_t)d * NPTS;
        float* SC0 = ST, *SH0 = ST + 128, *SC1 = ST + 256, *SH1 = ST + 384,
             * SC2 = ST + 512, *SH2 = ST + 640;

        // ---- BN0 ----
        bn_partial<<<NBLK_STATS, 128, 0, stream>>>(F, PART);
        bn_finalize<<<1, 128, 0, stream>>>(PART, bn_g + d * CCH, bn_b + d * CCH, SC0, SH0);

        // ---- k,v = relu/id( bn0(F) @ Wqkv[:,128:384] ) -> R0 ----
        gemm_bf16<<<gA, 256, 0, stream>>>(F, CCH, SC0, SH0,
                                          Wqkv + (size_t)d * CCH * 384 + 128, 384, CCH,
                                          nullptr, R0, 256, 128, 0);

        // ---- window lists (contention-free counting sort) ----
        hipMemsetAsync(HIST, 0, 256 * sizeof(int), stream);
        hist2_k<<<NBLK_SORT, 256, 0, stream>>>(wi, BH, HIST);
        scan_k<<<1, 64, 0, stream>>>(HIST, OFFS);
        colscan_k<<<1, 256, 0, stream>>>(BH, OFFS, OFFB);
        scatter2_k<<<NBLK_SORT, 256, 0, stream>>>(wi, OFFB, LIST, WSORT);

        // ---- per-window KV, S (chunk-parallel, pipelined, atomic reduce) ----
        hipMemsetAsync(KV, 0, (size_t)(NWIN * 2048 + NWIN * 128) * sizeof(float), stream);
        window_kv_chunk<<<(NPTS + KVCHUNK - 1) / KVCHUNK, 256, 0, stream>>>(
            R0, LIST, WSORT, KV, SB);

        // ---- q = relu( bn0(F) @ Wqkv[:,0:128] ) -> R0 col 0 (over dead k) ----
        gemm_bf16<<<gB, 256, 0, stream>>>(F, CCH, SC0, SH0,
                                          Wqkv + (size_t)d * CCH * 384, 384, CCH,
                                          nullptr, R0, 256, 128, 0);

        // ---- y -> R0 col 128 (over dead v) ----
        attn_y<<<50000, 256, 0, stream>>>(R0, wi, KV, SB, R0);

        // ---- F += y @ Wproj + bproj ----
        gemm_bf16<<<gB, 256, 0, stream>>>(R0 + 128, 256, nullptr, nullptr,
                                          Wproj + (size_t)d * CCH * CCH, CCH, CCH,
                                          bproj + d * CCH, F, CCH, 0, 1);

        // ---- BN1 -> FB (R0 col 0..127), F[:,96:] = 2*FB ----
        bn_partial<<<NBLK_STATS, 128, 0, stream>>>(F, PART);
        bn_finalize<<<1, 128, 0, stream>>>(PART, bn1_g + d * CCH, bn1_b + d * CCH, SC1, SH1);
        bn_apply<<<12500, 256, 0, stream>>>(F, R0, SC1, SH1);

        // ---- submanifold convs (residual fused) ----
        conv_g<27><<<3125, 256, 0, stream>>>(nbr_k, Wk + (size_t)d * 27 * 1024, R0, 0,  F, 0);
        conv_g<13><<<3125, 256, 0, stream>>>(nbr_h, Wh + (size_t)d * 13 * 1024, R0, 32, F, 32);
        conv_g<13><<<3125, 256, 0, stream>>>(nbr_w, Ww + (size_t)d * 13 * 1024, R0, 64, F, 64);

        // ---- BN2 + MLP ----
        bn_partial<<<NBLK_STATS, 128, 0, stream>>>(F, PART);
        bn_finalize<<<1, 128, 0, stream>>>(PART, bn2_g + d * CCH, bn2_b + d * CCH, SC2, SH2);

        gemm_bf16<<<gA, 256, 0, stream>>>(F, CCH, SC2, SH2,
                                          fc1_W + (size_t)d * CCH * 256, 256, CCH,
                                          fc1_b + d * 256, R0, 256, 256, 0);
        gemm_bf16<<<gB, 256, 0, stream>>>(R0, 256, nullptr, nullptr,
                                          fc2_W + (size_t)d * 256 * CCH, CCH, 256,
                                          fc2_b + d * CCH, F, CCH, 0, 1);
    }
}

// Round 6
// 1549.015 us; speedup vs baseline: 2.3878x; 1.0819x over previous
//
#include <hip/hip_runtime.h>
#include <math.h>

#define NPTS 100000
#define CCH 128
#define NWIN 200
#define NBLK_STATS 512
#define NBLK_SORT 391   // ceil(NPTS/256)
#define SEGSZ 128
#define NSEG_MAX 1024   // >= 200 + ceil(100000/128) = 982

#define BM 128
#define BN 64
#define BK 64

typedef __attribute__((ext_vector_type(8))) short bf16x8;
typedef __attribute__((ext_vector_type(4))) float f32x4;
typedef __attribute__((ext_vector_type(4))) unsigned short u16x4;

__device__ __forceinline__ unsigned short f2bf(float f) {
    union { float f; unsigned u; } x; x.f = f;
    unsigned r = x.u + 0x7fff + ((x.u >> 16) & 1);   // RNE (no NaN inputs here)
    return (unsigned short)(r >> 16);
}

// ---------------- BN statistics ----------------
__global__ void bn_partial(const float* __restrict__ F, float* __restrict__ part) {
    int c = threadIdx.x;            // 128 threads: one per channel
    int b = blockIdx.x;
    float s = 0.f, q = 0.f;
    for (int n = b; n < NPTS; n += NBLK_STATS) {
        float v = F[n * CCH + c];
        s += v; q += v * v;
    }
    part[b * 256 + c] = s;
    part[b * 256 + 128 + c] = q;
}

__global__ void bn_finalize(const float* __restrict__ part,
                            const float* __restrict__ g, const float* __restrict__ bb,
                            float* __restrict__ scale, float* __restrict__ shift) {
    int c = threadIdx.x;            // 128 threads
    double s = 0.0, q = 0.0;
    for (int b = 0; b < NBLK_STATS; b++) {
        s += (double)part[b * 256 + c];
        q += (double)part[b * 256 + 128 + c];
    }
    double m = s / (double)NPTS;
    double var = q / (double)NPTS - m * m;
    double rstd = 1.0 / sqrt(var + 1e-3);
    float sc = (float)rstd * g[c];
    scale[c] = sc;
    shift[c] = bb[c] - (float)m * sc;
}

// ---------------- bf16 MFMA GEMM with BN-fold / bias / relu / residual ----------------
__global__ __launch_bounds__(256) void gemm_bf16(
    const float* __restrict__ A, int lda,
    const float* __restrict__ scale, const float* __restrict__ shift,
    const float* __restrict__ W, int ldw, int K,
    const float* __restrict__ bias,
    float* __restrict__ Out, int ldo,
    int reluLim, int addFlag)
{
    __shared__ unsigned short As[BM * BK];   // [128][64] bf16, slot-XOR-swizzled
    __shared__ unsigned short Bs[BN * BK];   // [64][64] = B^T (col-major W), swizzled

    const int tid  = threadIdx.x;
    const int wave = tid >> 6;
    const int lane = tid & 63;
    const int bm = blockIdx.x * BM;
    const int bn = blockIdx.y * BN;

    f32x4 acc[2][4];
#pragma unroll
    for (int i = 0; i < 2; i++)
#pragma unroll
        for (int j = 0; j < 4; j++)
            acc[i][j] = (f32x4){0.f, 0.f, 0.f, 0.f};

    const int arow_t = tid >> 4;          // 0..15
    const int acol   = (tid & 15) * 4;    // 0..60
    const int kq = (tid >> 4) * 4;        // B micro-tile k0
    const int cq = (tid & 15) * 4;        // B micro-tile col0
    const int lrow = lane & 15;
    const int lhk  = lane >> 4;           // 0..3

    for (int kk = 0; kk < K; kk += BK) {
#pragma unroll
        for (int pass = 0; pass < 8; pass++) {
            int row = pass * 16 + arow_t;
            int grow = bm + row;
            float4 v = make_float4(0.f, 0.f, 0.f, 0.f);
            if (grow < NPTS)
                v = *reinterpret_cast<const float4*>(&A[(size_t)grow * lda + kk + acol]);
            if (scale) {
                v.x = v.x * scale[kk + acol + 0] + shift[kk + acol + 0];
                v.y = v.y * scale[kk + acol + 1] + shift[kk + acol + 1];
                v.z = v.z * scale[kk + acol + 2] + shift[kk + acol + 2];
                v.w = v.w * scale[kk + acol + 3] + shift[kk + acol + 3];
            }
            u16x4 h = { f2bf(v.x), f2bf(v.y), f2bf(v.z), f2bf(v.w) };
            int s = acol >> 3;                       // 16B slot (0..7)
            int sw = s ^ (row & 7);
            *reinterpret_cast<u16x4*>(&As[row * 64 + sw * 8 + (acol & 7)]) = h;
        }
        {
            float4 wv[4];
#pragma unroll
            for (int i = 0; i < 4; i++)
                wv[i] = *reinterpret_cast<const float4*>(&W[(size_t)(kk + kq + i) * ldw + bn + cq]);
            const float* wp = reinterpret_cast<const float*>(wv);
#pragma unroll
            for (int j = 0; j < 4; j++) {
                int col = cq + j;
                u16x4 h = { f2bf(wp[0 * 4 + j]), f2bf(wp[1 * 4 + j]),
                            f2bf(wp[2 * 4 + j]), f2bf(wp[3 * 4 + j]) };
                int s = kq >> 3;
                int sw = s ^ (col & 7);
                *reinterpret_cast<u16x4*>(&Bs[col * 64 + sw * 8 + (kq & 7)]) = h;
            }
        }
        __syncthreads();

#pragma unroll
        for (int ks = 0; ks < 2; ks++) {
            bf16x8 af[2], bfr[4];
#pragma unroll
            for (int fi = 0; fi < 2; fi++) {
                int row = wave * 32 + fi * 16 + lrow;
                int sw = (ks * 4 + lhk) ^ (row & 7);
                af[fi] = *reinterpret_cast<const bf16x8*>(&As[row * 64 + sw * 8]);
            }
#pragma unroll
            for (int fj = 0; fj < 4; fj++) {
                int col = fj * 16 + lrow;
                int sw = (ks * 4 + lhk) ^ (col & 7);
                bfr[fj] = *reinterpret_cast<const bf16x8*>(&Bs[col * 64 + sw * 8]);
            }
#pragma unroll
            for (int fi = 0; fi < 2; fi++)
#pragma unroll
                for (int fj = 0; fj < 4; fj++)
                    acc[fi][fj] = __builtin_amdgcn_mfma_f32_16x16x32_bf16(
                        af[fi], bfr[fj], acc[fi][fj], 0, 0, 0);
        }
        __syncthreads();
    }

#pragma unroll
    for (int fi = 0; fi < 2; fi++) {
        int grow0 = bm + wave * 32 + fi * 16 + (lane >> 4) * 4;
#pragma unroll
        for (int fj = 0; fj < 4; fj++) {
            int col = bn + fj * 16 + (lane & 15);
            float bv = bias ? bias[col] : 0.f;
            bool rl = (col < reluLim);
#pragma unroll
            for (int r = 0; r < 4; r++) {
                int rr = grow0 + r;
                if (rr >= NPTS) continue;
                float v = acc[fi][fj][r] + bv;
                if (rl) v = fmaxf(v, 0.f);
                float* o = &Out[(size_t)rr * ldo + col];
                if (addFlag) *o += v; else *o = v;
            }
        }
    }
}

// ---------------- window list build (block-local counting sort) ----------------
__global__ __launch_bounds__(256) void hist2_k(const int* __restrict__ wi,
                                               int* __restrict__ BH, int* __restrict__ HIST) {
    __shared__ int h[NWIN];
    int t = threadIdx.x;
    if (t < NWIN) h[t] = 0;
    __syncthreads();
    int n = blockIdx.x * 256 + t;
    if (n < NPTS) atomicAdd(&h[wi[n]], 1);
    __syncthreads();
    if (t < NWIN) {
        BH[blockIdx.x * 256 + t] = h[t];
        if (h[t]) atomicAdd(&HIST[t], h[t]);
    }
}

__global__ void scan_k(const int* __restrict__ hist, int* __restrict__ offs) {
    if (threadIdx.x == 0 && blockIdx.x == 0) {
        int a = 0;
        for (int w = 0; w < NWIN; w++) { offs[w] = a; a += hist[w]; }
        offs[NWIN] = a;
    }
}

__global__ void colscan_k(const int* __restrict__ BH, const int* __restrict__ OFFS,
                          int* __restrict__ OFFB) {
    int w = threadIdx.x;
    if (w >= NWIN) return;
    int a = OFFS[w];
    for (int b = 0; b < NBLK_SORT; b++) {
        OFFB[b * 256 + w] = a;
        a += BH[b * 256 + w];
    }
}

__global__ __launch_bounds__(256) void scatter2_k(const int* __restrict__ wi,
                                                  const int* __restrict__ OFFB,
                                                  int* __restrict__ list) {
    __shared__ int h[NWIN];
    int t = threadIdx.x;
    if (t < NWIN) h[t] = 0;
    __syncthreads();
    int n = blockIdx.x * 256 + t;
    if (n < NPTS) {
        int w = wi[n];
        int r = atomicAdd(&h[w], 1);
        list[OFFB[blockIdx.x * 256 + w] + r] = n;
    }
}

// ---------------- segment build: window-aligned segments of <= SEGSZ points ----------------
__global__ void segbuild_k(const int* __restrict__ OFFS,
                           int* __restrict__ SEGW, int* __restrict__ SEGP0,
                           int* __restrict__ SEGP1, int* __restrict__ SEGBASE) {
    __shared__ int base[NWIN];
    int w = threadIdx.x;
    if (w < NWIN) {
        int n = OFFS[w + 1] - OFFS[w];
        base[w] = (n + SEGSZ - 1) / SEGSZ;
    }
    __syncthreads();
    if (threadIdx.x == 0) {
        int a = 0;
        for (int i = 0; i < NWIN; i++) { int c = base[i]; base[i] = a; SEGBASE[i] = a; a += c; }
        SEGBASE[NWIN] = a;
    }
    __syncthreads();
    if (w < NWIN) {
        int b = base[w];
        int p0 = OFFS[w], p1 = OFFS[w + 1];
        for (int p = p0; p < p1; p += SEGSZ) {
            SEGW[b] = w; SEGP0[b] = p; SEGP1[b] = min(p + SEGSZ, p1); b++;
        }
    }
}

// ---------------- per-segment K^T V and sum(K): register acc, PLAIN stores ----------------
// R0 rows: [k(128) | v(128)], ld 256. One block per segment (single window).
// Partial out: PKV[sid][0..2047]=KV, [2048..2175]=sum(K).
__global__ __launch_bounds__(256) void window_kv_seg(
    const float* __restrict__ R0,
    const int* __restrict__ list,
    const int* __restrict__ SEGP0, const int* __restrict__ SEGP1,
    const int* __restrict__ SEGBASE,
    float* __restrict__ PKV)
{
    int sid = blockIdx.x;
    if (sid >= SEGBASE[NWIN]) return;
    int t = threadIdx.x;
    int p0 = SEGP0[sid], p1 = SEGP1[sid];
    __shared__ float buf[8][256];
    float acc[8] = {0.f,0.f,0.f,0.f,0.f,0.f,0.f,0.f};
    float sa = 0.f;
    int f0 = t * 8;
    int h = f0 >> 8;
    int c = (f0 >> 4) & 15;
    int d0 = f0 & 15;
    const int sr = t >> 5;          // staging row 0..7
    const int sc4 = (t & 31) * 4;   // staging float4 col

    for (int g = p0; g < p1; g += 8) {
        int m = min(8, p1 - g);
        int nj[8];
#pragma unroll
        for (int j = 0; j < 8; j++)
            nj[j] = list[(g + j < p1) ? g + j : p1 - 1];
        __syncthreads();   // buf free (previous group consumed)
        {
            const float* row = &R0[(size_t)nj[sr] * 256];
            *reinterpret_cast<float4*>(&buf[sr][sc4]) =
                *reinterpret_cast<const float4*>(&row[sc4]);
            *reinterpret_cast<float4*>(&buf[sr][128 + sc4]) =
                *reinterpret_cast<const float4*>(&row[128 + sc4]);
        }
        __syncthreads();
#pragma unroll
        for (int j = 0; j < 8; j++) {
            if (j >= m) break;
            float kc = buf[j][h * 16 + c];
#pragma unroll
            for (int i = 0; i < 8; i++) acc[i] += kc * buf[j][128 + h * 16 + d0 + i];
            if (t < 128) sa += buf[j][t];
        }
    }
    float* out = &PKV[(size_t)sid * 2176];
#pragma unroll
    for (int i = 0; i < 8; i++) out[f0 + i] = acc[i];
    if (t < 128) out[2048 + t] = sa;
}

// ---------------- reduce segment partials per window ----------------
__global__ __launch_bounds__(256) void kv_reduce(
    const float* __restrict__ PKV, const int* __restrict__ SEGBASE,
    float* __restrict__ KV, float* __restrict__ SB)
{
    int w = blockIdx.x;
    int t = threadIdx.x;
    int s0 = SEGBASE[w], s1 = SEGBASE[w + 1];
    float a[8] = {0.f,0.f,0.f,0.f,0.f,0.f,0.f,0.f};
    float sb = 0.f;
    for (int s = s0; s < s1; s++) {
        const float* p = &PKV[(size_t)s * 2176];
#pragma unroll
        for (int i = 0; i < 8; i++) a[i] += p[t * 8 + i];
        if (t < 128) sb += p[2048 + t];
    }
#pragma unroll
    for (int i = 0; i < 8; i++) KV[w * 2048 + t * 8 + i] = a[i];
    if (t < 128) SB[w * 128 + t] = sb;
}

// ---------------- y = (q . kv[w]) / (q . s[w] + eps) ----------------
__global__ __launch_bounds__(256) void attn_y(
    const float* Q, const int* __restrict__ wi,
    const float* __restrict__ KV, const float* __restrict__ SB,
    float* Y)
{
    __shared__ float qs[2][128];
    int half = threadIdx.x >> 7;
    int c = threadIdx.x & 127;
    int pt = blockIdx.x * 2 + half;
    if (pt < NPTS) qs[half][c] = Q[pt * 256 + c];
    __syncthreads();
    if (pt >= NPTS) return;
    int w = wi[pt];
    int h = c >> 4, dd = c & 15;
    const float* qh = &qs[half][h * 16];
    const float* kvw = &KV[w * 2048 + h * 256];
    const float* sw = &SB[w * 128 + h * 16];
    float z = 0.f, y = 0.f;
#pragma unroll
    for (int cc = 0; cc < 16; cc++) {
        z += sw[cc] * qh[cc];
        y += qh[cc] * kvw[cc * 16 + dd];
    }
    Y[pt * 256 + 128 + c] = y / (z + 1e-3f);
}

// ---------------- bn apply: FB = bn1(F); F[:,96:128] = 2*FB ----------------
__global__ void bn_apply(float* F, float* FB,
                         const float* __restrict__ scale, const float* __restrict__ shift)
{
    int i = blockIdx.x * 256 + threadIdx.x;
    int n = i >> 5;
    int c4 = (i & 31) * 4;
    float4 v = *reinterpret_cast<const float4*>(&F[n * CCH + c4]);
    float4 o;
    o.x = v.x * scale[c4 + 0] + shift[c4 + 0];
    o.y = v.y * scale[c4 + 1] + shift[c4 + 1];
    o.z = v.z * scale[c4 + 2] + shift[c4 + 2];
    o.w = v.w * scale[c4 + 3] + shift[c4 + 3];
    *reinterpret_cast<float4*>(&FB[n * 256 + c4]) = o;
    if (c4 >= 96) {
        float4 t = make_float4(2.f * o.x, 2.f * o.y, 2.f * o.z, 2.f * o.w);
        *reinterpret_cast<float4*>(&F[n * CCH + c4]) = t;
    }
}

// ---------------- submanifold conv ----------------
template<int KN>
__global__ __launch_bounds__(256) void conv_g(
    const int* __restrict__ nbr, const float* __restrict__ Wc,
    const float* __restrict__ FB, int goff,
    float* __restrict__ Fout, int outoff)
{
    int t = blockIdx.x * 256 + threadIdx.x;
    int pt = t >> 3;
    int so = (t & 7) * 4;
    if (pt >= NPTS) return;
    float acc0 = 0.f, acc1 = 0.f, acc2 = 0.f, acc3 = 0.f;
    const int* nb = &nbr[pt * KN];
#pragma unroll 1
    for (int k = 0; k < KN; k++) {
        int idx = nb[k];
        if (idx >= NPTS) continue;   // sentinel row = zeros
        const float* rr = &FB[idx * 256 + goff];
        const float* wk = &Wc[k * 1024 + so];
#pragma unroll
        for (int c = 0; c < 32; c += 4) {
            float4 rv = *reinterpret_cast<const float4*>(&rr[c]);
            float4 w0 = *reinterpret_cast<const float4*>(&wk[(c + 0) * 32]);
            float4 w1 = *reinterpret_cast<const float4*>(&wk[(c + 1) * 32]);
            float4 w2 = *reinterpret_cast<const float4*>(&wk[(c + 2) * 32]);
            float4 w3 = *reinterpret_cast<const float4*>(&wk[(c + 3) * 32]);
            acc0 += rv.x * w0.x + rv.y * w1.x + rv.z * w2.x + rv.w * w3.x;
            acc1 += rv.x * w0.y + rv.y * w1.y + rv.z * w2.y + rv.w * w3.y;
            acc2 += rv.x * w0.z + rv.y * w1.z + rv.z * w2.z + rv.w * w3.z;
            acc3 += rv.x * w0.w + rv.y * w1.w + rv.z * w2.w + rv.w * w3.w;
        }
    }
    float4 fb = *reinterpret_cast<const float4*>(&FB[pt * 256 + goff + so]);
    float4 o = make_float4(fb.x + acc0, fb.y + acc1, fb.z + acc2, fb.w + acc3);
    *reinterpret_cast<float4*>(&Fout[pt * CCH + outoff + so]) = o;
}

// ---------------- launch ----------------
extern "C" void kernel_launch(void* const* d_in, const int* in_sizes, int n_in,
                              void* d_out, int out_size, void* d_ws, size_t ws_size,
                              hipStream_t stream)
{
    const float* feats   = (const float*)d_in[0];
    const int*   win_inds= (const int*)d_in[1];
    const int*   nbr_k   = (const int*)d_in[2];
    const int*   nbr_h   = (const int*)d_in[3];
    const int*   nbr_w   = (const int*)d_in[4];
    const float* bn_g    = (const float*)d_in[5];
    const float* bn_b    = (const float*)d_in[6];
    const float* Wqkv    = (const float*)d_in[7];
    const float* Wproj   = (const float*)d_in[8];
    const float* bproj   = (const float*)d_in[9];
    const float* bn1_g   = (const float*)d_in[10];
    const float* bn1_b   = (const float*)d_in[11];
    const float* Wk      = (const float*)d_in[12];
    const float* Wh      = (const float*)d_in[13];
    const float* Ww      = (const float*)d_in[14];
    const float* bn2_g   = (const float*)d_in[15];
    const float* bn2_b   = (const float*)d_in[16];
    const float* fc1_W   = (const float*)d_in[17];
    const float* fc1_b   = (const float*)d_in[18];
    const float* fc2_W   = (const float*)d_in[19];
    const float* fc2_b   = (const float*)d_in[20];

    float* F  = (float*)d_out;
    float* R0 = (float*)d_ws;                       // NPTS*256
    float* KV = R0 + (size_t)NPTS * 256;            // NWIN*2048
    float* SB = KV + NWIN * 2048;                   // NWIN*128
    float* ST = SB + NWIN * 128;                    // 6*128
    float* PART = ST + 768;                         // NBLK_STATS*256
    float* PKV = PART + NBLK_STATS * 256;           // NSEG_MAX*2176
    int* HIST = (int*)(PKV + (size_t)NSEG_MAX * 2176);  // 256
    int* OFFS = HIST + 256;                         // 256 (201 used)
    int* LIST = OFFS + 256;                         // NPTS
    int* BH   = LIST + NPTS;                        // NBLK_SORT*256
    int* OFFB = BH + NBLK_SORT * 256;               // NBLK_SORT*256
    int* SEGW = OFFB + NBLK_SORT * 256;             // NSEG_MAX
    int* SEGP0= SEGW + NSEG_MAX;                    // NSEG_MAX
    int* SEGP1= SEGP0 + NSEG_MAX;                   // NSEG_MAX
    int* SEGBASE = SEGP1 + NSEG_MAX;                // 256

    hipMemcpyAsync(F, feats, (size_t)NPTS * CCH * sizeof(float),
                   hipMemcpyDeviceToDevice, stream);

    dim3 gA(782, 4), gB(782, 2);    // 782 = ceil(100000/128)

    for (int d = 0; d < 2; d++) {
        const int* wi = win_inds + (size_t)d * NPTS;
        float* SC0 = ST, *SH0 = ST + 128, *SC1 = ST + 256, *SH1 = ST + 384,
             * SC2 = ST + 512, *SH2 = ST + 640;

        // ---- BN0 ----
        bn_partial<<<NBLK_STATS, 128, 0, stream>>>(F, PART);
        bn_finalize<<<1, 128, 0, stream>>>(PART, bn_g + d * CCH, bn_b + d * CCH, SC0, SH0);

        // ---- k,v = relu/id( bn0(F) @ Wqkv[:,128:384] ) -> R0 ----
        gemm_bf16<<<gA, 256, 0, stream>>>(F, CCH, SC0, SH0,
                                          Wqkv + (size_t)d * CCH * 384 + 128, 384, CCH,
                                          nullptr, R0, 256, 128, 0);

        // ---- window lists (contention-free counting sort) ----
        hipMemsetAsync(HIST, 0, 256 * sizeof(int), stream);
        hist2_k<<<NBLK_SORT, 256, 0, stream>>>(wi, BH, HIST);
        scan_k<<<1, 64, 0, stream>>>(HIST, OFFS);
        colscan_k<<<1, 256, 0, stream>>>(BH, OFFS, OFFB);
        scatter2_k<<<NBLK_SORT, 256, 0, stream>>>(wi, OFFB, LIST);

        // ---- segments + per-segment KV partials (plain stores) + reduce ----
        segbuild_k<<<1, 256, 0, stream>>>(OFFS, SEGW, SEGP0, SEGP1, SEGBASE);
        window_kv_seg<<<NSEG_MAX, 256, 0, stream>>>(R0, LIST, SEGP0, SEGP1, SEGBASE, PKV);
        kv_reduce<<<NWIN, 256, 0, stream>>>(PKV, SEGBASE, KV, SB);

        // ---- q = relu( bn0(F) @ Wqkv[:,0:128] ) -> R0 col 0 (over dead k) ----
        gemm_bf16<<<gB, 256, 0, stream>>>(F, CCH, SC0, SH0,
                                          Wqkv + (size_t)d * CCH * 384, 384, CCH,
                                          nullptr, R0, 256, 128, 0);

        // ---- y -> R0 col 128 (over dead v) ----
        attn_y<<<50000, 256, 0, stream>>>(R0, wi, KV, SB, R0);

        // ---- F += y @ Wproj + bproj ----
        gemm_bf16<<<gB, 256, 0, stream>>>(R0 + 128, 256, nullptr, nullptr,
                                          Wproj + (size_t)d * CCH * CCH, CCH, CCH,
                                          bproj + d * CCH, F, CCH, 0, 1);

        // ---- BN1 -> FB (R0 col 0..127), F[:,96:] = 2*FB ----
        bn_partial<<<NBLK_STATS, 128, 0, stream>>>(F, PART);
        bn_finalize<<<1, 128, 0, stream>>>(PART, bn1_g + d * CCH, bn1_b + d * CCH, SC1, SH1);
        bn_apply<<<12500, 256, 0, stream>>>(F, R0, SC1, SH1);

        // ---- submanifold convs (residual fused) ----
        conv_g<27><<<3125, 256, 0, stream>>>(nbr_k, Wk + (size_t)d * 27 * 1024, R0, 0,  F, 0);
        conv_g<13><<<3125, 256, 0, stream>>>(nbr_h, Wh + (size_t)d * 13 * 1024, R0, 32, F, 32);
        conv_g<13><<<3125, 256, 0, stream>>>(nbr_w, Ww + (size_t)d * 13 * 1024, R0, 64, F, 64);

        // ---- BN2 + MLP ----
        bn_partial<<<NBLK_STATS, 128, 0, stream>>>(F, PART);
        bn_finalize<<<1, 128, 0, stream>>>(PART, bn2_g + d * CCH, bn2_b + d * CCH, SC2, SH2);

        gemm_bf16<<<gA, 256, 0, stream>>>(F, CCH, SC2, SH2,
                                          fc1_W + (size_t)d * CCH * 256, 256, CCH,
                                          fc1_b + d * 256, R0, 256, 256, 0);
        gemm_bf16<<<gB, 256, 0, stream>>>(R0, 256, nullptr, nullptr,
                                          fc2_W + (size_t)d * 256 * CCH, CCH, 256,
                                          fc2_b + d * CCH, F, CCH, 0, 1);
    }
}

// Round 7
// 1424.492 us; speedup vs baseline: 2.5965x; 1.0874x over previous
//
#include <hip/hip_runtime.h>
#include <math.h>

#define NPTS 100000
#define CCH 128
#define NWIN 200
#define NBLK_STATS 512
#define NBLK_SORT 391   // ceil(NPTS/256)
#define SEGSZ 128
#define NSEG_MAX 1024   // >= 200 + ceil(100000/128) = 982

#define BM 128
#define BN 128
#define BK 64

typedef __attribute__((ext_vector_type(8))) short bf16x8;
typedef __attribute__((ext_vector_type(4))) float f32x4;
typedef __attribute__((ext_vector_type(4))) unsigned short u16x4;

__device__ __forceinline__ unsigned short f2bf(float f) {
    union { float f; unsigned u; } x; x.f = f;
    unsigned r = x.u + 0x7fff + ((x.u >> 16) & 1);   // RNE (no NaN inputs here)
    return (unsigned short)(r >> 16);
}

// ---------------- BN statistics ----------------
__global__ void bn_partial(const float* __restrict__ F, float* __restrict__ part) {
    int c = threadIdx.x;            // 128 threads: one per channel
    int b = blockIdx.x;
    float s = 0.f, q = 0.f;
    for (int n = b; n < NPTS; n += NBLK_STATS) {
        float v = F[n * CCH + c];
        s += v; q += v * v;
    }
    part[b * 256 + c] = s;
    part[b * 256 + 128 + c] = q;
}

__global__ void bn_finalize(const float* __restrict__ part,
                            const float* __restrict__ g, const float* __restrict__ bb,
                            float* __restrict__ scale, float* __restrict__ shift) {
    int c = threadIdx.x;            // 128 threads
    double s = 0.0, q = 0.0;
    for (int b = 0; b < NBLK_STATS; b++) {
        s += (double)part[b * 256 + c];
        q += (double)part[b * 256 + 128 + c];
    }
    double m = s / (double)NPTS;
    double var = q / (double)NPTS - m * m;
    double rstd = 1.0 / sqrt(var + 1e-3);
    float sc = (float)rstd * g[c];
    scale[c] = sc;
    shift[c] = bb[c] - (float)m * sc;
}

// ---------------- W prep: WT[n][k] = bf16(scale[k]*W[k][n]); biasf[n] = sum_k shift[k]*W[k][n] + bias[n]
__global__ __launch_bounds__(128) void wprep(
    const float* __restrict__ W, int K, int N,
    const float* __restrict__ sc, const float* __restrict__ sh,
    const float* __restrict__ bias,
    unsigned short* __restrict__ WT, float* __restrict__ biasf)
{
    int n = blockIdx.x;
    int t = threadIdx.x;
    float part = 0.f;
    for (int k = t; k < K; k += 128) {
        float w = W[(size_t)k * N + n];
        float s = sc ? sc[k] * w : w;
        WT[(size_t)n * K + k] = f2bf(s);
        if (sh) part += sh[k] * w;
    }
    __shared__ float red[128];
    red[t] = part;
    __syncthreads();
    for (int o = 64; o > 0; o >>= 1) {
        if (t < o) red[t] += red[t + o];
        __syncthreads();
    }
    if (t == 0) biasf[n] = red[0] + (bias ? bias[n] : 0.f);
}

// ---------------- bf16 MFMA GEMM (BN pre-folded into WT/biasf) ----------------
// Out[r, bn+c] (= or +=) sum_k A[r,k] * WT[bn+c][k] + biasf[bn+c]; relu on col<reluLim
__global__ __launch_bounds__(256) void gemm_bf16(
    const float* __restrict__ A, int lda,
    const unsigned short* __restrict__ WT, const float* __restrict__ biasf,
    int K,
    float* __restrict__ Out, int ldo,
    int reluLim, int addFlag)
{
    __shared__ __align__(16) char smem[34048];
    unsigned short* As = (unsigned short*)smem;          // [128][64] bf16, swizzled
    unsigned short* Bs = As + BM * BK;                   // [128][64] bf16, swizzled
    float* Ep = (float*)smem;                            // [64][132] f32 epilogue

    const int tid  = threadIdx.x;
    const int wave = tid >> 6;
    const int lane = tid & 63;
    const int bm = blockIdx.x * BM;
    const int bn = blockIdx.y * BN;

    f32x4 acc[2][8];
#pragma unroll
    for (int i = 0; i < 2; i++)
#pragma unroll
        for (int j = 0; j < 8; j++)
            acc[i][j] = (f32x4){0.f, 0.f, 0.f, 0.f};

    const int arow_t = tid >> 4;          // 0..15
    const int acol   = (tid & 15) * 4;    // 0..60
    const int brow_t = tid >> 3;          // 0..31
    const int bslot  = tid & 7;           // 0..7
    const int lrow = lane & 15;
    const int lhk  = lane >> 4;           // 0..3

    for (int kk = 0; kk < K; kk += BK) {
        // ---- stage A: 8 passes x (16 rows x 64 k), cvt bf16, swizzled ----
#pragma unroll
        for (int pass = 0; pass < 8; pass++) {
            int row = pass * 16 + arow_t;
            int grow = bm + row;
            float4 v = make_float4(0.f, 0.f, 0.f, 0.f);
            if (grow < NPTS)
                v = *reinterpret_cast<const float4*>(&A[(size_t)grow * lda + kk + acol]);
            u16x4 h = { f2bf(v.x), f2bf(v.y), f2bf(v.z), f2bf(v.w) };
            int s = acol >> 3;
            int sw = s ^ (row & 7);
            *reinterpret_cast<u16x4*>(&As[row * 64 + sw * 8 + (acol & 7)]) = h;
        }
        // ---- stage B: 4 passes x (32 n-rows x 1 slot), straight bf16 copy, swizzled ----
#pragma unroll
        for (int pass = 0; pass < 4; pass++) {
            int n = pass * 32 + brow_t;
            bf16x8 w = *reinterpret_cast<const bf16x8*>(&WT[(size_t)(bn + n) * K + kk + bslot * 8]);
            int sw = bslot ^ (n & 7);
            *reinterpret_cast<bf16x8*>(&Bs[n * 64 + sw * 8]) = w;
        }
        __syncthreads();

        // ---- compute: 2 k-steps of 32 ----
#pragma unroll
        for (int ks = 0; ks < 2; ks++) {
            bf16x8 af[2], bfr[8];
#pragma unroll
            for (int fi = 0; fi < 2; fi++) {
                int row = wave * 32 + fi * 16 + lrow;
                int sw = (ks * 4 + lhk) ^ (row & 7);
                af[fi] = *reinterpret_cast<const bf16x8*>(&As[row * 64 + sw * 8]);
            }
#pragma unroll
            for (int fj = 0; fj < 8; fj++) {
                int col = fj * 16 + lrow;
                int sw = (ks * 4 + lhk) ^ (col & 7);
                bfr[fj] = *reinterpret_cast<const bf16x8*>(&Bs[col * 64 + sw * 8]);
            }
#pragma unroll
            for (int fi = 0; fi < 2; fi++)
#pragma unroll
                for (int fj = 0; fj < 8; fj++)
                    acc[fi][fj] = __builtin_amdgcn_mfma_f32_16x16x32_bf16(
                        af[fi], bfr[fj], acc[fi][fj], 0, 0, 0);
        }
        __syncthreads();
    }

    // ---- epilogue: LDS bounce -> coalesced float4 stores (bias/relu/residual fused) ----
    for (int hh = 0; hh < 2; hh++) {
        if ((wave >> 1) == hh) {
#pragma unroll
            for (int fi = 0; fi < 2; fi++) {
                int row = (wave & 1) * 32 + fi * 16 + (lane >> 4) * 4;
#pragma unroll
                for (int fj = 0; fj < 8; fj++) {
                    int col = fj * 16 + (lane & 15);
#pragma unroll
                    for (int r = 0; r < 4; r++)
                        Ep[(row + r) * 132 + col] = acc[fi][fj][r];
                }
            }
        }
        __syncthreads();
#pragma unroll
        for (int pass = 0; pass < 8; pass++) {
            int idx = pass * 256 + tid;     // 0..2047
            int r = idx >> 5;               // 0..63
            int c4 = (idx & 31) * 4;        // 0..124
            int rr = bm + hh * 64 + r;
            if (rr < NPTS) {
                float4 v = *reinterpret_cast<const float4*>(&Ep[r * 132 + c4]);
                float4 b = *reinterpret_cast<const float4*>(&biasf[bn + c4]);
                v.x += b.x; v.y += b.y; v.z += b.z; v.w += b.w;
                int col = bn + c4;
                if (col + 0 < reluLim) v.x = fmaxf(v.x, 0.f);
                if (col + 1 < reluLim) v.y = fmaxf(v.y, 0.f);
                if (col + 2 < reluLim) v.z = fmaxf(v.z, 0.f);
                if (col + 3 < reluLim) v.w = fmaxf(v.w, 0.f);
                float* o = &Out[(size_t)rr * ldo + bn + c4];
                if (addFlag) {
                    float4 ov = *reinterpret_cast<const float4*>(o);
                    v.x += ov.x; v.y += ov.y; v.z += ov.z; v.w += ov.w;
                }
                *reinterpret_cast<float4*>(o) = v;
            }
        }
        __syncthreads();
    }
}

// ---------------- window list build (block-local counting sort) ----------------
__global__ __launch_bounds__(256) void hist2_k(const int* __restrict__ wi,
                                               int* __restrict__ BH, int* __restrict__ HIST) {
    __shared__ int h[NWIN];
    int t = threadIdx.x;
    if (t < NWIN) h[t] = 0;
    __syncthreads();
    int n = blockIdx.x * 256 + t;
    if (n < NPTS) atomicAdd(&h[wi[n]], 1);
    __syncthreads();
    if (t < NWIN) {
        BH[blockIdx.x * 256 + t] = h[t];
        if (h[t]) atomicAdd(&HIST[t], h[t]);
    }
}

__global__ void scan_k(const int* __restrict__ hist, int* __restrict__ offs) {
    if (threadIdx.x == 0 && blockIdx.x == 0) {
        int a = 0;
        for (int w = 0; w < NWIN; w++) { offs[w] = a; a += hist[w]; }
        offs[NWIN] = a;
    }
}

__global__ void colscan_k(const int* __restrict__ BH, const int* __restrict__ OFFS,
                          int* __restrict__ OFFB) {
    int w = threadIdx.x;
    if (w >= NWIN) return;
    int a = OFFS[w];
    for (int b = 0; b < NBLK_SORT; b++) {
        OFFB[b * 256 + w] = a;
        a += BH[b * 256 + w];
    }
}

__global__ __launch_bounds__(256) void scatter2_k(const int* __restrict__ wi,
                                                  const int* __restrict__ OFFB,
                                                  int* __restrict__ list) {
    __shared__ int h[NWIN];
    int t = threadIdx.x;
    if (t < NWIN) h[t] = 0;
    __syncthreads();
    int n = blockIdx.x * 256 + t;
    if (n < NPTS) {
        int w = wi[n];
        int r = atomicAdd(&h[w], 1);
        list[OFFB[blockIdx.x * 256 + w] + r] = n;
    }
}

// ---------------- segment build: window-aligned segments of <= SEGSZ points ----------------
__global__ void segbuild_k(const int* __restrict__ OFFS,
                           int* __restrict__ SEGW, int* __restrict__ SEGP0,
                           int* __restrict__ SEGP1, int* __restrict__ SEGBASE) {
    __shared__ int base[NWIN];
    int w = threadIdx.x;
    if (w < NWIN) {
        int n = OFFS[w + 1] - OFFS[w];
        base[w] = (n + SEGSZ - 1) / SEGSZ;
    }
    __syncthreads();
    if (threadIdx.x == 0) {
        int a = 0;
        for (int i = 0; i < NWIN; i++) { int c = base[i]; base[i] = a; SEGBASE[i] = a; a += c; }
        SEGBASE[NWIN] = a;
    }
    __syncthreads();
    if (w < NWIN) {
        int b = base[w];
        int p0 = OFFS[w], p1 = OFFS[w + 1];
        for (int p = p0; p < p1; p += SEGSZ) {
            SEGW[b] = w; SEGP0[b] = p; SEGP1[b] = min(p + SEGSZ, p1); b++;
        }
    }
}

// ---------------- per-segment K^T V and sum(K): register acc, PLAIN stores ----------------
__global__ __launch_bounds__(256) void window_kv_seg(
    const float* __restrict__ R0,
    const int* __restrict__ list,
    const int* __restrict__ SEGP0, const int* __restrict__ SEGP1,
    const int* __restrict__ SEGBASE,
    float* __restrict__ PKV)
{
    int sid = blockIdx.x;
    if (sid >= SEGBASE[NWIN]) return;
    int t = threadIdx.x;
    int p0 = SEGP0[sid], p1 = SEGP1[sid];
    __shared__ float buf[8][256];
    float acc[8] = {0.f,0.f,0.f,0.f,0.f,0.f,0.f,0.f};
    float sa = 0.f;
    int f0 = t * 8;
    int h = f0 >> 8;
    int c = (f0 >> 4) & 15;
    int d0 = f0 & 15;
    const int sr = t >> 5;          // staging row 0..7
    const int sc4 = (t & 31) * 4;   // staging float4 col

    for (int g = p0; g < p1; g += 8) {
        int m = min(8, p1 - g);
        int nj[8];
#pragma unroll
        for (int j = 0; j < 8; j++)
            nj[j] = list[(g + j < p1) ? g + j : p1 - 1];
        __syncthreads();   // buf free (previous group consumed)
        {
            const float* row = &R0[(size_t)nj[sr] * 256];
            *reinterpret_cast<float4*>(&buf[sr][sc4]) =
                *reinterpret_cast<const float4*>(&row[sc4]);
            *reinterpret_cast<float4*>(&buf[sr][128 + sc4]) =
                *reinterpret_cast<const float4*>(&row[128 + sc4]);
        }
        __syncthreads();
#pragma unroll
        for (int j = 0; j < 8; j++) {
            if (j >= m) break;
            float kc = buf[j][h * 16 + c];
#pragma unroll
            for (int i = 0; i < 8; i++) acc[i] += kc * buf[j][128 + h * 16 + d0 + i];
            if (t < 128) sa += buf[j][t];
        }
    }
    float* out = &PKV[(size_t)sid * 2176];
#pragma unroll
    for (int i = 0; i < 8; i++) out[f0 + i] = acc[i];
    if (t < 128) out[2048 + t] = sa;
}

// ---------------- reduce segment partials per window ----------------
__global__ __launch_bounds__(256) void kv_reduce(
    const float* __restrict__ PKV, const int* __restrict__ SEGBASE,
    float* __restrict__ KV, float* __restrict__ SB)
{
    int w = blockIdx.x;
    int t = threadIdx.x;
    int s0 = SEGBASE[w], s1 = SEGBASE[w + 1];
    float a[8] = {0.f,0.f,0.f,0.f,0.f,0.f,0.f,0.f};
    float sb = 0.f;
    for (int s = s0; s < s1; s++) {
        const float* p = &PKV[(size_t)s * 2176];
#pragma unroll
        for (int i = 0; i < 8; i++) a[i] += p[t * 8 + i];
        if (t < 128) sb += p[2048 + t];
    }
#pragma unroll
    for (int i = 0; i < 8; i++) KV[w * 2048 + t * 8 + i] = a[i];
    if (t < 128) SB[w * 128 + t] = sb;
}

// ---------------- y = (q . kv[w]) / (q . s[w] + eps) ----------------
__global__ __launch_bounds__(256) void attn_y(
    const float* Q, const int* __restrict__ wi,
    const float* __restrict__ KV, const float* __restrict__ SB,
    float* Y)
{
    __shared__ float qs[2][128];
    int half = threadIdx.x >> 7;
    int c = threadIdx.x & 127;
    int pt = blockIdx.x * 2 + half;
    if (pt < NPTS) qs[half][c] = Q[pt * 256 + c];
    __syncthreads();
    if (pt >= NPTS) return;
    int w = wi[pt];
    int h = c >> 4, dd = c & 15;
    const float* qh = &qs[half][h * 16];
    const float* kvw = &KV[w * 2048 + h * 256];
    const float* sw = &SB[w * 128 + h * 16];
    float z = 0.f, y = 0.f;
#pragma unroll
    for (int cc = 0; cc < 16; cc++) {
        z += sw[cc] * qh[cc];
        y += qh[cc] * kvw[cc * 16 + dd];
    }
    Y[pt * 256 + 128 + c] = y / (z + 1e-3f);
}

// ---------------- bn apply: FB = bn1(F); F[:,96:128] = 2*FB ----------------
__global__ void bn_apply(float* F, float* FB,
                         const float* __restrict__ scale, const float* __restrict__ shift)
{
    int i = blockIdx.x * 256 + threadIdx.x;
    int n = i >> 5;
    int c4 = (i & 31) * 4;
    float4 v = *reinterpret_cast<const float4*>(&F[n * CCH + c4]);
    float4 o;
    o.x = v.x * scale[c4 + 0] + shift[c4 + 0];
    o.y = v.y * scale[c4 + 1] + shift[c4 + 1];
    o.z = v.z * scale[c4 + 2] + shift[c4 + 2];
    o.w = v.w * scale[c4 + 3] + shift[c4 + 3];
    *reinterpret_cast<float4*>(&FB[n * 256 + c4]) = o;
    if (c4 >= 96) {
        float4 t = make_float4(2.f * o.x, 2.f * o.y, 2.f * o.z, 2.f * o.w);
        *reinterpret_cast<float4*>(&F[n * CCH + c4]) = t;
    }
}

// ---------------- submanifold conv ----------------
template<int KN>
__global__ __launch_bounds__(256) void conv_g(
    const int* __restrict__ nbr, const float* __restrict__ Wc,
    const float* __restrict__ FB, int goff,
    float* __restrict__ Fout, int outoff)
{
    int t = blockIdx.x * 256 + threadIdx.x;
    int pt = t >> 3;
    int so = (t & 7) * 4;
    if (pt >= NPTS) return;
    float acc0 = 0.f, acc1 = 0.f, acc2 = 0.f, acc3 = 0.f;
    const int* nb = &nbr[pt * KN];
#pragma unroll 1
    for (int k = 0; k < KN; k++) {
        int idx = nb[k];
        if (idx >= NPTS) continue;   // sentinel row = zeros
        const float* rr = &FB[idx * 256 + goff];
        const float* wk = &Wc[k * 1024 + so];
#pragma unroll
        for (int c = 0; c < 32; c += 4) {
            float4 rv = *reinterpret_cast<const float4*>(&rr[c]);
            float4 w0 = *reinterpret_cast<const float4*>(&wk[(c + 0) * 32]);
            float4 w1 = *reinterpret_cast<const float4*>(&wk[(c + 1) * 32]);
            float4 w2 = *reinterpret_cast<const float4*>(&wk[(c + 2) * 32]);
            float4 w3 = *reinterpret_cast<const float4*>(&wk[(c + 3) * 32]);
            acc0 += rv.x * w0.x + rv.y * w1.x + rv.z * w2.x + rv.w * w3.x;
            acc1 += rv.x * w0.y + rv.y * w1.y + rv.z * w2.y + rv.w * w3.y;
            acc2 += rv.x * w0.z + rv.y * w1.z + rv.z * w2.z + rv.w * w3.z;
            acc3 += rv.x * w0.w + rv.y * w1.w + rv.z * w2.w + rv.w * w3.w;
        }
    }
    float4 fb = *reinterpret_cast<const float4*>(&FB[pt * 256 + goff + so]);
    float4 o = make_float4(fb.x + acc0, fb.y + acc1, fb.z + acc2, fb.w + acc3);
    *reinterpret_cast<float4*>(&Fout[pt * CCH + outoff + so]) = o;
}

// ---------------- launch ----------------
extern "C" void kernel_launch(void* const* d_in, const int* in_sizes, int n_in,
                              void* d_out, int out_size, void* d_ws, size_t ws_size,
                              hipStream_t stream)
{
    const float* feats   = (const float*)d_in[0];
    const int*   win_inds= (const int*)d_in[1];
    const int*   nbr_k   = (const int*)d_in[2];
    const int*   nbr_h   = (const int*)d_in[3];
    const int*   nbr_w   = (const int*)d_in[4];
    const float* bn_g    = (const float*)d_in[5];
    const float* bn_b    = (const float*)d_in[6];
    const float* Wqkv    = (const float*)d_in[7];
    const float* Wproj   = (const float*)d_in[8];
    const float* bproj   = (const float*)d_in[9];
    const float* bn1_g   = (const float*)d_in[10];
    const float* bn1_b   = (const float*)d_in[11];
    const float* Wk      = (const float*)d_in[12];
    const float* Wh      = (const float*)d_in[13];
    const float* Ww      = (const float*)d_in[14];
    const float* bn2_g   = (const float*)d_in[15];
    const float* bn2_b   = (const float*)d_in[16];
    const float* fc1_W   = (const float*)d_in[17];
    const float* fc1_b   = (const float*)d_in[18];
    const float* fc2_W   = (const float*)d_in[19];
    const float* fc2_b   = (const float*)d_in[20];

    float* F  = (float*)d_out;
    float* R0 = (float*)d_ws;                       // NPTS*256
    float* KV = R0 + (size_t)NPTS * 256;            // NWIN*2048
    float* SB = KV + NWIN * 2048;                   // NWIN*128
    float* ST = SB + NWIN * 128;                    // 6*128
    float* PART = ST + 768;                         // NBLK_STATS*256
    float* PKV = PART + NBLK_STATS * 256;           // NSEG_MAX*2176
    int* HIST = (int*)(PKV + (size_t)NSEG_MAX * 2176);  // 256
    int* OFFS = HIST + 256;                         // 256 (201 used)
    int* LIST = OFFS + 256;                         // 100096 (NPTS rounded)
    int* BH   = LIST + 100096;                      // NBLK_SORT*256
    int* OFFB = BH + NBLK_SORT * 256;               // NBLK_SORT*256
    int* SEGW = OFFB + NBLK_SORT * 256;             // NSEG_MAX
    int* SEGP0= SEGW + NSEG_MAX;                    // NSEG_MAX
    int* SEGP1= SEGP0 + NSEG_MAX;                   // NSEG_MAX
    int* SEGBASE = SEGP1 + NSEG_MAX;                // 256
    unsigned short* WQKVT = (unsigned short*)(SEGBASE + 256);   // 384*128
    unsigned short* WPROJT = WQKVT + 384 * 128;                 // 128*128
    unsigned short* WFC1T  = WPROJT + 128 * 128;                // 256*128
    unsigned short* WFC2T  = WFC1T + 256 * 128;                 // 128*256
    float* BQKV  = (float*)(WFC2T + 128 * 256);     // 384
    float* BPROJ = BQKV + 384;                      // 128
    float* BFC1  = BPROJ + 128;                     // 256
    float* BFC2  = BFC1 + 256;                      // 128

    hipMemcpyAsync(F, feats, (size_t)NPTS * CCH * sizeof(float),
                   hipMemcpyDeviceToDevice, stream);

    dim3 g2(782, 2), g1(782, 1);    // 782 = ceil(100000/128)

    for (int d = 0; d < 2; d++) {
        const int* wi = win_inds + (size_t)d * NPTS;
        float* SC0 = ST, *SH0 = ST + 128, *SC1 = ST + 256, *SH1 = ST + 384,
             * SC2 = ST + 512, *SH2 = ST + 640;

        // ---- BN0 stats + folded W for qkv ----
        bn_partial<<<NBLK_STATS, 128, 0, stream>>>(F, PART);
        bn_finalize<<<1, 128, 0, stream>>>(PART, bn_g + d * CCH, bn_b + d * CCH, SC0, SH0);
        wprep<<<384, 128, 0, stream>>>(Wqkv + (size_t)d * CCH * 384, 128, 384,
                                       SC0, SH0, nullptr, WQKVT, BQKV);
        wprep<<<128, 128, 0, stream>>>(Wproj + (size_t)d * CCH * CCH, 128, 128,
                                       nullptr, nullptr, bproj + d * CCH, WPROJT, BPROJ);

        // ---- k,v = relu/id( bn0(F) @ Wqkv[:,128:384] ) -> R0 cols 0..255 ----
        gemm_bf16<<<g2, 256, 0, stream>>>(F, CCH, WQKVT + 128 * 128, BQKV + 128, 128,
                                          R0, 256, 128, 0);

        // ---- window lists (contention-free counting sort) ----
        hipMemsetAsync(HIST, 0, 256 * sizeof(int), stream);
        hist2_k<<<NBLK_SORT, 256, 0, stream>>>(wi, BH, HIST);
        scan_k<<<1, 64, 0, stream>>>(HIST, OFFS);
        colscan_k<<<1, 256, 0, stream>>>(BH, OFFS, OFFB);
        scatter2_k<<<NBLK_SORT, 256, 0, stream>>>(wi, OFFB, LIST);

        // ---- segments + per-segment KV partials (plain stores) + reduce ----
        segbuild_k<<<1, 256, 0, stream>>>(OFFS, SEGW, SEGP0, SEGP1, SEGBASE);
        window_kv_seg<<<NSEG_MAX, 256, 0, stream>>>(R0, LIST, SEGP0, SEGP1, SEGBASE, PKV);
        kv_reduce<<<NWIN, 256, 0, stream>>>(PKV, SEGBASE, KV, SB);

        // ---- q = relu( bn0(F) @ Wqkv[:,0:128] ) -> R0 cols 0..127 (over dead k) ----
        gemm_bf16<<<g1, 256, 0, stream>>>(F, CCH, WQKVT, BQKV, 128,
                                          R0, 256, 128, 0);

        // ---- y -> R0 cols 128..255 (over dead v) ----
        attn_y<<<50000, 256, 0, stream>>>(R0, wi, KV, SB, R0);

        // ---- F += y @ Wproj + bproj ----
        gemm_bf16<<<g1, 256, 0, stream>>>(R0 + 128, 256, WPROJT, BPROJ, 128,
                                          F, CCH, 0, 1);

        // ---- BN1 -> FB (R0 cols 0..127 of ld 256), F[:,96:] = 2*FB ----
        bn_partial<<<NBLK_STATS, 128, 0, stream>>>(F, PART);
        bn_finalize<<<1, 128, 0, stream>>>(PART, bn1_g + d * CCH, bn1_b + d * CCH, SC1, SH1);
        bn_apply<<<12500, 256, 0, stream>>>(F, R0, SC1, SH1);

        // ---- submanifold convs (residual fused) ----
        conv_g<27><<<3125, 256, 0, stream>>>(nbr_k, Wk + (size_t)d * 27 * 1024, R0, 0,  F, 0);
        conv_g<13><<<3125, 256, 0, stream>>>(nbr_h, Wh + (size_t)d * 13 * 1024, R0, 32, F, 32);
        conv_g<13><<<3125, 256, 0, stream>>>(nbr_w, Ww + (size_t)d * 13 * 1024, R0, 64, F, 64);

        // ---- BN2 stats + folded W for fc1; fc2 prep ----
        bn_partial<<<NBLK_STATS, 128, 0, stream>>>(F, PART);
        bn_finalize<<<1, 128, 0, stream>>>(PART, bn2_g + d * CCH, bn2_b + d * CCH, SC2, SH2);
        wprep<<<256, 128, 0, stream>>>(fc1_W + (size_t)d * CCH * 256, 128, 256,
                                       SC2, SH2, fc1_b + d * 256, WFC1T, BFC1);
        wprep<<<128, 128, 0, stream>>>(fc2_W + (size_t)d * 256 * CCH, 256, 128,
                                       nullptr, nullptr, fc2_b + d * CCH, WFC2T, BFC2);

        // ---- MLP ----
        gemm_bf16<<<g2, 256, 0, stream>>>(F, CCH, WFC1T, BFC1, 128,
                                          R0, 256, 256, 0);
        gemm_bf16<<<g1, 256, 0, stream>>>(R0, 256, WFC2T, BFC2, 256,
                                          F, CCH, 0, 1);
    }
}

// Round 8
// 1353.750 us; speedup vs baseline: 2.7322x; 1.0523x over previous
//
#include <hip/hip_runtime.h>
#include <math.h>

#define NPTS 100000
#define CCH 128
#define NWIN 200
#define NBLK_STATS 512
#define NBLK_SORT 391   // ceil(NPTS/256)
#define SEGSZ 128
#define NSEG_MAX 1024   // >= 200 + ceil(100000/128) = 982

#define BM 128
#define BN 128
#define BK 64

typedef __attribute__((ext_vector_type(8))) short bf16x8;
typedef __attribute__((ext_vector_type(4))) float f32x4;
typedef __attribute__((ext_vector_type(4))) unsigned short u16x4;

__device__ __forceinline__ unsigned short f2bf(float f) {
    union { float f; unsigned u; } x; x.f = f;
    unsigned r = x.u + 0x7fff + ((x.u >> 16) & 1);   // RNE (no NaN inputs here)
    return (unsigned short)(r >> 16);
}

// ---------------- BN statistics ----------------
__global__ void bn_partial(const float* __restrict__ F, float* __restrict__ part) {
    int c = threadIdx.x;            // 128 threads: one per channel
    int b = blockIdx.x;
    float s = 0.f, q = 0.f;
    for (int n = b; n < NPTS; n += NBLK_STATS) {
        float v = F[n * CCH + c];
        s += v; q += v * v;
    }
    part[b * 256 + c] = s;
    part[b * 256 + 128 + c] = q;
}

__global__ void bn_finalize(const float* __restrict__ part,
                            const float* __restrict__ g, const float* __restrict__ bb,
                            float* __restrict__ scale, float* __restrict__ shift) {
    int c = threadIdx.x;            // 128 threads
    double s = 0.0, q = 0.0;
    for (int b = 0; b < NBLK_STATS; b++) {
        s += (double)part[b * 256 + c];
        q += (double)part[b * 256 + 128 + c];
    }
    double m = s / (double)NPTS;
    double var = q / (double)NPTS - m * m;
    double rstd = 1.0 / sqrt(var + 1e-3);
    float sc = (float)rstd * g[c];
    scale[c] = sc;
    shift[c] = bb[c] - (float)m * sc;
}

// ---------------- W prep: WT[n][k] = bf16(scale[k]*W[k][n]); biasf[n] = sum_k shift[k]*W[k][n] + bias[n]
__global__ __launch_bounds__(128) void wprep(
    const float* __restrict__ W, int K, int N,
    const float* __restrict__ sc, const float* __restrict__ sh,
    const float* __restrict__ bias,
    unsigned short* __restrict__ WT, float* __restrict__ biasf)
{
    int n = blockIdx.x;
    int t = threadIdx.x;
    float part = 0.f;
    for (int k = t; k < K; k += 128) {
        float w = W[(size_t)k * N + n];
        float s = sc ? sc[k] * w : w;
        WT[(size_t)n * K + k] = f2bf(s);
        if (sh) part += sh[k] * w;
    }
    __shared__ float red[128];
    red[t] = part;
    __syncthreads();
    for (int o = 64; o > 0; o >>= 1) {
        if (t < o) red[t] += red[t + o];
        __syncthreads();
    }
    if (t == 0) biasf[n] = red[0] + (bias ? bias[n] : 0.f);
}

// ---------------- bf16 MFMA GEMM (BN pre-folded into WT/biasf) ----------------
__global__ __launch_bounds__(256) void gemm_bf16(
    const float* __restrict__ A, int lda,
    const unsigned short* __restrict__ WT, const float* __restrict__ biasf,
    int K,
    float* __restrict__ Out, int ldo,
    int reluLim, int addFlag)
{
    __shared__ __align__(16) char smem[34048];
    unsigned short* As = (unsigned short*)smem;          // [128][64] bf16, swizzled
    unsigned short* Bs = As + BM * BK;                   // [128][64] bf16, swizzled
    float* Ep = (float*)smem;                            // [64][132] f32 epilogue

    const int tid  = threadIdx.x;
    const int wave = tid >> 6;
    const int lane = tid & 63;
    const int bm = blockIdx.x * BM;
    const int bn = blockIdx.y * BN;

    f32x4 acc[2][8];
#pragma unroll
    for (int i = 0; i < 2; i++)
#pragma unroll
        for (int j = 0; j < 8; j++)
            acc[i][j] = (f32x4){0.f, 0.f, 0.f, 0.f};

    const int arow_t = tid >> 4;          // 0..15
    const int acol   = (tid & 15) * 4;    // 0..60
    const int brow_t = tid >> 3;          // 0..31
    const int bslot  = tid & 7;           // 0..7
    const int lrow = lane & 15;
    const int lhk  = lane >> 4;           // 0..3

    for (int kk = 0; kk < K; kk += BK) {
#pragma unroll
        for (int pass = 0; pass < 8; pass++) {
            int row = pass * 16 + arow_t;
            int grow = bm + row;
            float4 v = make_float4(0.f, 0.f, 0.f, 0.f);
            if (grow < NPTS)
                v = *reinterpret_cast<const float4*>(&A[(size_t)grow * lda + kk + acol]);
            u16x4 h = { f2bf(v.x), f2bf(v.y), f2bf(v.z), f2bf(v.w) };
            int s = acol >> 3;
            int sw = s ^ (row & 7);
            *reinterpret_cast<u16x4*>(&As[row * 64 + sw * 8 + (acol & 7)]) = h;
        }
#pragma unroll
        for (int pass = 0; pass < 4; pass++) {
            int n = pass * 32 + brow_t;
            bf16x8 w = *reinterpret_cast<const bf16x8*>(&WT[(size_t)(bn + n) * K + kk + bslot * 8]);
            int sw = bslot ^ (n & 7);
            *reinterpret_cast<bf16x8*>(&Bs[n * 64 + sw * 8]) = w;
        }
        __syncthreads();

#pragma unroll
        for (int ks = 0; ks < 2; ks++) {
            bf16x8 af[2], bfr[8];
#pragma unroll
            for (int fi = 0; fi < 2; fi++) {
                int row = wave * 32 + fi * 16 + lrow;
                int sw = (ks * 4 + lhk) ^ (row & 7);
                af[fi] = *reinterpret_cast<const bf16x8*>(&As[row * 64 + sw * 8]);
            }
#pragma unroll
            for (int fj = 0; fj < 8; fj++) {
                int col = fj * 16 + lrow;
                int sw = (ks * 4 + lhk) ^ (col & 7);
                bfr[fj] = *reinterpret_cast<const bf16x8*>(&Bs[col * 64 + sw * 8]);
            }
#pragma unroll
            for (int fi = 0; fi < 2; fi++)
#pragma unroll
                for (int fj = 0; fj < 8; fj++)
                    acc[fi][fj] = __builtin_amdgcn_mfma_f32_16x16x32_bf16(
                        af[fi], bfr[fj], acc[fi][fj], 0, 0, 0);
        }
        __syncthreads();
    }

    for (int hh = 0; hh < 2; hh++) {
        if ((wave >> 1) == hh) {
#pragma unroll
            for (int fi = 0; fi < 2; fi++) {
                int row = (wave & 1) * 32 + fi * 16 + (lane >> 4) * 4;
#pragma unroll
                for (int fj = 0; fj < 8; fj++) {
                    int col = fj * 16 + (lane & 15);
#pragma unroll
                    for (int r = 0; r < 4; r++)
                        Ep[(row + r) * 132 + col] = acc[fi][fj][r];
                }
            }
        }
        __syncthreads();
#pragma unroll
        for (int pass = 0; pass < 8; pass++) {
            int idx = pass * 256 + tid;     // 0..2047
            int r = idx >> 5;               // 0..63
            int c4 = (idx & 31) * 4;        // 0..124
            int rr = bm + hh * 64 + r;
            if (rr < NPTS) {
                float4 v = *reinterpret_cast<const float4*>(&Ep[r * 132 + c4]);
                float4 b = *reinterpret_cast<const float4*>(&biasf[bn + c4]);
                v.x += b.x; v.y += b.y; v.z += b.z; v.w += b.w;
                int col = bn + c4;
                if (col + 0 < reluLim) v.x = fmaxf(v.x, 0.f);
                if (col + 1 < reluLim) v.y = fmaxf(v.y, 0.f);
                if (col + 2 < reluLim) v.z = fmaxf(v.z, 0.f);
                if (col + 3 < reluLim) v.w = fmaxf(v.w, 0.f);
                float* o = &Out[(size_t)rr * ldo + bn + c4];
                if (addFlag) {
                    float4 ov = *reinterpret_cast<const float4*>(o);
                    v.x += ov.x; v.y += ov.y; v.z += ov.z; v.w += ov.w;
                }
                *reinterpret_cast<float4*>(o) = v;
            }
        }
        __syncthreads();
    }
}

// ---------------- window list build (block-local counting sort) ----------------
__global__ __launch_bounds__(256) void hist2_k(const int* __restrict__ wi,
                                               int* __restrict__ BH, int* __restrict__ HIST) {
    __shared__ int h[NWIN];
    int t = threadIdx.x;
    if (t < NWIN) h[t] = 0;
    __syncthreads();
    int n = blockIdx.x * 256 + t;
    if (n < NPTS) atomicAdd(&h[wi[n]], 1);
    __syncthreads();
    if (t < NWIN) {
        BH[blockIdx.x * 256 + t] = h[t];
        if (h[t]) atomicAdd(&HIST[t], h[t]);
    }
}

__global__ void scan_k(const int* __restrict__ hist, int* __restrict__ offs) {
    if (threadIdx.x == 0 && blockIdx.x == 0) {
        int a = 0;
        for (int w = 0; w < NWIN; w++) { offs[w] = a; a += hist[w]; }
        offs[NWIN] = a;
    }
}

__global__ void colscan_k(const int* __restrict__ BH, const int* __restrict__ OFFS,
                          int* __restrict__ OFFB) {
    int w = threadIdx.x;
    if (w >= NWIN) return;
    int a = OFFS[w];
    for (int b = 0; b < NBLK_SORT; b++) {
        OFFB[b * 256 + w] = a;
        a += BH[b * 256 + w];
    }
}

__global__ __launch_bounds__(256) void scatter2_k(const int* __restrict__ wi,
                                                  const int* __restrict__ OFFB,
                                                  int* __restrict__ list) {
    __shared__ int h[NWIN];
    int t = threadIdx.x;
    if (t < NWIN) h[t] = 0;
    __syncthreads();
    int n = blockIdx.x * 256 + t;
    if (n < NPTS) {
        int w = wi[n];
        int r = atomicAdd(&h[w], 1);
        list[OFFB[blockIdx.x * 256 + w] + r] = n;
    }
}

// ---------------- segment build: window-aligned segments of <= SEGSZ points ----------------
__global__ void segbuild_k(const int* __restrict__ OFFS,
                           int* __restrict__ SEGW, int* __restrict__ SEGP0,
                           int* __restrict__ SEGP1, int* __restrict__ SEGBASE) {
    __shared__ int base[NWIN];
    int w = threadIdx.x;
    if (w < NWIN) {
        int n = OFFS[w + 1] - OFFS[w];
        base[w] = (n + SEGSZ - 1) / SEGSZ;
    }
    __syncthreads();
    if (threadIdx.x == 0) {
        int a = 0;
        for (int i = 0; i < NWIN; i++) { int c = base[i]; base[i] = a; SEGBASE[i] = a; a += c; }
        SEGBASE[NWIN] = a;
    }
    __syncthreads();
    if (w < NWIN) {
        int b = base[w];
        int p0 = OFFS[w], p1 = OFFS[w + 1];
        for (int p = p0; p < p1; p += SEGSZ) {
            SEGW[b] = w; SEGP0[b] = p; SEGP1[b] = min(p + SEGSZ, p1); b++;
        }
    }
}

// ---------------- per-segment K^T V and sum(K): register acc, PLAIN stores ----------------
__global__ __launch_bounds__(256) void window_kv_seg(
    const float* __restrict__ R0,
    const int* __restrict__ list,
    const int* __restrict__ SEGP0, const int* __restrict__ SEGP1,
    const int* __restrict__ SEGBASE,
    float* __restrict__ PKV)
{
    int sid = blockIdx.x;
    if (sid >= SEGBASE[NWIN]) return;
    int t = threadIdx.x;
    int p0 = SEGP0[sid], p1 = SEGP1[sid];
    __shared__ float buf[8][256];
    float acc[8] = {0.f,0.f,0.f,0.f,0.f,0.f,0.f,0.f};
    float sa = 0.f;
    int f0 = t * 8;
    int h = f0 >> 8;
    int c = (f0 >> 4) & 15;
    int d0 = f0 & 15;
    const int sr = t >> 5;          // staging row 0..7
    const int sc4 = (t & 31) * 4;   // staging float4 col

    for (int g = p0; g < p1; g += 8) {
        int m = min(8, p1 - g);
        int nj[8];
#pragma unroll
        for (int j = 0; j < 8; j++)
            nj[j] = list[(g + j < p1) ? g + j : p1 - 1];
        __syncthreads();   // buf free (previous group consumed)
        {
            const float* row = &R0[(size_t)nj[sr] * 256];
            *reinterpret_cast<float4*>(&buf[sr][sc4]) =
                *reinterpret_cast<const float4*>(&row[sc4]);
            *reinterpret_cast<float4*>(&buf[sr][128 + sc4]) =
                *reinterpret_cast<const float4*>(&row[128 + sc4]);
        }
        __syncthreads();
#pragma unroll
        for (int j = 0; j < 8; j++) {
            if (j >= m) break;
            float kc = buf[j][h * 16 + c];
#pragma unroll
            for (int i = 0; i < 8; i++) acc[i] += kc * buf[j][128 + h * 16 + d0 + i];
            if (t < 128) sa += buf[j][t];
        }
    }
    float* out = &PKV[(size_t)sid * 2176];
#pragma unroll
    for (int i = 0; i < 8; i++) out[f0 + i] = acc[i];
    if (t < 128) out[2048 + t] = sa;
}

// ---------------- reduce segment partials per window ----------------
__global__ __launch_bounds__(256) void kv_reduce(
    const float* __restrict__ PKV, const int* __restrict__ SEGBASE,
    float* __restrict__ KV, float* __restrict__ SB)
{
    int w = blockIdx.x;
    int t = threadIdx.x;
    int s0 = SEGBASE[w], s1 = SEGBASE[w + 1];
    float a[8] = {0.f,0.f,0.f,0.f,0.f,0.f,0.f,0.f};
    float sb = 0.f;
    for (int s = s0; s < s1; s++) {
        const float* p = &PKV[(size_t)s * 2176];
#pragma unroll
        for (int i = 0; i < 8; i++) a[i] += p[t * 8 + i];
        if (t < 128) sb += p[2048 + t];
    }
#pragma unroll
    for (int i = 0; i < 8; i++) KV[w * 2048 + t * 8 + i] = a[i];
    if (t < 128) SB[w * 128 + t] = sb;
}

// ---------------- y = (q . kv[w]) / (q . s[w] + eps), segment-parallel, KV in registers ----------------
// One block per segment (single window w). Thread owns (head h, 4 d's); KV slice
// cached in 64 regs for the whole segment (~up to 128 points of reuse).
// Q read from R0 col 0..127; Y written to R0 col 128..255.
__global__ __launch_bounds__(256) void attn_y_seg(
    float* __restrict__ R0,
    const int* __restrict__ list,
    const int* __restrict__ SEGW, const int* __restrict__ SEGP0,
    const int* __restrict__ SEGP1, const int* __restrict__ SEGBASE,
    const float* __restrict__ KV, const float* __restrict__ SB)
{
    int sid = blockIdx.x;
    if (sid >= SEGBASE[NWIN]) return;
    int t = threadIdx.x;
    int w = SEGW[sid];
    int g  = t >> 5;            // point group 0..7
    int h  = (t >> 2) & 7;      // head
    int d4 = (t & 3) * 4;       // output d offset

    float4 kvr[16];
    const float* kvb = &KV[w * 2048 + h * 256 + d4];
#pragma unroll
    for (int cc = 0; cc < 16; cc++)
        kvr[cc] = *reinterpret_cast<const float4*>(&kvb[cc * 16]);
    float sreg[16];
    const float* sb = &SB[w * 128 + h * 16];
#pragma unroll
    for (int cc = 0; cc < 16; cc++) sreg[cc] = sb[cc];

    int p0 = SEGP0[sid], p1 = SEGP1[sid];
    for (int p = p0 + g; p < p1; p += 8) {
        int n = list[p];
        const float* q = &R0[(size_t)n * 256 + h * 16];
        float4 q0 = *reinterpret_cast<const float4*>(&q[0]);
        float4 q1 = *reinterpret_cast<const float4*>(&q[4]);
        float4 q2 = *reinterpret_cast<const float4*>(&q[8]);
        float4 q3 = *reinterpret_cast<const float4*>(&q[12]);
        float qq[16] = { q0.x,q0.y,q0.z,q0.w, q1.x,q1.y,q1.z,q1.w,
                         q2.x,q2.y,q2.z,q2.w, q3.x,q3.y,q3.z,q3.w };
        float z = 0.f;
        float4 y = make_float4(0.f, 0.f, 0.f, 0.f);
#pragma unroll
        for (int cc = 0; cc < 16; cc++) {
            z += qq[cc] * sreg[cc];
            y.x += qq[cc] * kvr[cc].x;
            y.y += qq[cc] * kvr[cc].y;
            y.z += qq[cc] * kvr[cc].z;
            y.w += qq[cc] * kvr[cc].w;
        }
        float inv = 1.f / (z + 1e-3f);
        float4 o = make_float4(y.x * inv, y.y * inv, y.z * inv, y.w * inv);
        *reinterpret_cast<float4*>(&R0[(size_t)n * 256 + 128 + h * 16 + d4]) = o;
    }
}

// ---------------- bn apply: FB = bn1(F); F[:,96:128] = 2*FB ----------------
__global__ void bn_apply(float* F, float* FB,
                         const float* __restrict__ scale, const float* __restrict__ shift)
{
    int i = blockIdx.x * 256 + threadIdx.x;
    int n = i >> 5;
    int c4 = (i & 31) * 4;
    float4 v = *reinterpret_cast<const float4*>(&F[n * CCH + c4]);
    float4 o;
    o.x = v.x * scale[c4 + 0] + shift[c4 + 0];
    o.y = v.y * scale[c4 + 1] + shift[c4 + 1];
    o.z = v.z * scale[c4 + 2] + shift[c4 + 2];
    o.w = v.w * scale[c4 + 3] + shift[c4 + 3];
    *reinterpret_cast<float4*>(&FB[n * 256 + c4]) = o;
    if (c4 >= 96) {
        float4 t = make_float4(2.f * o.x, 2.f * o.y, 2.f * o.z, 2.f * o.w);
        *reinterpret_cast<float4*>(&F[n * CCH + c4]) = t;
    }
}

// ---------------- submanifold conv ----------------
template<int KN>
__global__ __launch_bounds__(256) void conv_g(
    const int* __restrict__ nbr, const float* __restrict__ Wc,
    const float* __restrict__ FB, int goff,
    float* __restrict__ Fout, int outoff)
{
    int t = blockIdx.x * 256 + threadIdx.x;
    int pt = t >> 3;
    int so = (t & 7) * 4;
    if (pt >= NPTS) return;
    float acc0 = 0.f, acc1 = 0.f, acc2 = 0.f, acc3 = 0.f;
    const int* nb = &nbr[pt * KN];
#pragma unroll 1
    for (int k = 0; k < KN; k++) {
        int idx = nb[k];
        if (idx >= NPTS) continue;   // sentinel row = zeros
        const float* rr = &FB[idx * 256 + goff];
        const float* wk = &Wc[k * 1024 + so];
#pragma unroll
        for (int c = 0; c < 32; c += 4) {
            float4 rv = *reinterpret_cast<const float4*>(&rr[c]);
            float4 w0 = *reinterpret_cast<const float4*>(&wk[(c + 0) * 32]);
            float4 w1 = *reinterpret_cast<const float4*>(&wk[(c + 1) * 32]);
            float4 w2 = *reinterpret_cast<const float4*>(&wk[(c + 2) * 32]);
            float4 w3 = *reinterpret_cast<const float4*>(&wk[(c + 3) * 32]);
            acc0 += rv.x * w0.x + rv.y * w1.x + rv.z * w2.x + rv.w * w3.x;
            acc1 += rv.x * w0.y + rv.y * w1.y + rv.z * w2.y + rv.w * w3.y;
            acc2 += rv.x * w0.z + rv.y * w1.z + rv.z * w2.z + rv.w * w3.z;
            acc3 += rv.x * w0.w + rv.y * w1.w + rv.z * w2.w + rv.w * w3.w;
        }
    }
    float4 fb = *reinterpret_cast<const float4*>(&FB[pt * 256 + goff + so]);
    float4 o = make_float4(fb.x + acc0, fb.y + acc1, fb.z + acc2, fb.w + acc3);
    *reinterpret_cast<float4*>(&Fout[pt * CCH + outoff + so]) = o;
}

// ---------------- launch ----------------
extern "C" void kernel_launch(void* const* d_in, const int* in_sizes, int n_in,
                              void* d_out, int out_size, void* d_ws, size_t ws_size,
                              hipStream_t stream)
{
    const float* feats   = (const float*)d_in[0];
    const int*   win_inds= (const int*)d_in[1];
    const int*   nbr_k   = (const int*)d_in[2];
    const int*   nbr_h   = (const int*)d_in[3];
    const int*   nbr_w   = (const int*)d_in[4];
    const float* bn_g    = (const float*)d_in[5];
    const float* bn_b    = (const float*)d_in[6];
    const float* Wqkv    = (const float*)d_in[7];
    const float* Wproj   = (const float*)d_in[8];
    const float* bproj   = (const float*)d_in[9];
    const float* bn1_g   = (const float*)d_in[10];
    const float* bn1_b   = (const float*)d_in[11];
    const float* Wk      = (const float*)d_in[12];
    const float* Wh      = (const float*)d_in[13];
    const float* Ww      = (const float*)d_in[14];
    const float* bn2_g   = (const float*)d_in[15];
    const float* bn2_b   = (const float*)d_in[16];
    const float* fc1_W   = (const float*)d_in[17];
    const float* fc1_b   = (const float*)d_in[18];
    const float* fc2_W   = (const float*)d_in[19];
    const float* fc2_b   = (const float*)d_in[20];

    float* F  = (float*)d_out;
    float* R0 = (float*)d_ws;                       // NPTS*256
    float* KV = R0 + (size_t)NPTS * 256;            // NWIN*2048
    float* SB = KV + NWIN * 2048;                   // NWIN*128
    float* ST = SB + NWIN * 128;                    // 6*128
    float* PART = ST + 768;                         // NBLK_STATS*256
    float* PKV = PART + NBLK_STATS * 256;           // NSEG_MAX*2176
    int* HIST = (int*)(PKV + (size_t)NSEG_MAX * 2176);  // 256
    int* OFFS = HIST + 256;                         // 256 (201 used)
    int* LIST = OFFS + 256;                         // 100096 (NPTS rounded)
    int* BH   = LIST + 100096;                      // NBLK_SORT*256
    int* OFFB = BH + NBLK_SORT * 256;               // NBLK_SORT*256
    int* SEGW = OFFB + NBLK_SORT * 256;             // NSEG_MAX
    int* SEGP0= SEGW + NSEG_MAX;                    // NSEG_MAX
    int* SEGP1= SEGP0 + NSEG_MAX;                   // NSEG_MAX
    int* SEGBASE = SEGP1 + NSEG_MAX;                // 256
    unsigned short* WQKVT = (unsigned short*)(SEGBASE + 256);   // 384*128
    unsigned short* WPROJT = WQKVT + 384 * 128;                 // 128*128
    unsigned short* WFC1T  = WPROJT + 128 * 128;                // 256*128
    unsigned short* WFC2T  = WFC1T + 256 * 128;                 // 128*256
    float* BQKV  = (float*)(WFC2T + 128 * 256);     // 384
    float* BPROJ = BQKV + 384;                      // 128
    float* BFC1  = BPROJ + 128;                     // 256
    float* BFC2  = BFC1 + 256;                      // 128

    hipMemcpyAsync(F, feats, (size_t)NPTS * CCH * sizeof(float),
                   hipMemcpyDeviceToDevice, stream);

    dim3 g2(782, 2), g1(782, 1);    // 782 = ceil(100000/128)

    for (int d = 0; d < 2; d++) {
        const int* wi = win_inds + (size_t)d * NPTS;
        float* SC0 = ST, *SH0 = ST + 128, *SC1 = ST + 256, *SH1 = ST + 384,
             * SC2 = ST + 512, *SH2 = ST + 640;

        // ---- BN0 stats + folded W for qkv ----
        bn_partial<<<NBLK_STATS, 128, 0, stream>>>(F, PART);
        bn_finalize<<<1, 128, 0, stream>>>(PART, bn_g + d * CCH, bn_b + d * CCH, SC0, SH0);
        wprep<<<384, 128, 0, stream>>>(Wqkv + (size_t)d * CCH * 384, 128, 384,
                                       SC0, SH0, nullptr, WQKVT, BQKV);
        wprep<<<128, 128, 0, stream>>>(Wproj + (size_t)d * CCH * CCH, 128, 128,
                                       nullptr, nullptr, bproj + d * CCH, WPROJT, BPROJ);

        // ---- k,v = relu/id( bn0(F) @ Wqkv[:,128:384] ) -> R0 cols 0..255 ----
        gemm_bf16<<<g2, 256, 0, stream>>>(F, CCH, WQKVT + 128 * 128, BQKV + 128, 128,
                                          R0, 256, 128, 0);

        // ---- window lists (contention-free counting sort) ----
        hipMemsetAsync(HIST, 0, 256 * sizeof(int), stream);
        hist2_k<<<NBLK_SORT, 256, 0, stream>>>(wi, BH, HIST);
        scan_k<<<1, 64, 0, stream>>>(HIST, OFFS);
        colscan_k<<<1, 256, 0, stream>>>(BH, OFFS, OFFB);
        scatter2_k<<<NBLK_SORT, 256, 0, stream>>>(wi, OFFB, LIST);

        // ---- segments + per-segment KV partials (plain stores) + reduce ----
        segbuild_k<<<1, 256, 0, stream>>>(OFFS, SEGW, SEGP0, SEGP1, SEGBASE);
        window_kv_seg<<<NSEG_MAX, 256, 0, stream>>>(R0, LIST, SEGP0, SEGP1, SEGBASE, PKV);
        kv_reduce<<<NWIN, 256, 0, stream>>>(PKV, SEGBASE, KV, SB);

        // ---- q = relu( bn0(F) @ Wqkv[:,0:128] ) -> R0 cols 0..127 (over dead k) ----
        gemm_bf16<<<g1, 256, 0, stream>>>(F, CCH, WQKVT, BQKV, 128,
                                          R0, 256, 128, 0);

        // ---- y -> R0 cols 128..255 (over dead v); segment-parallel, KV in regs ----
        attn_y_seg<<<NSEG_MAX, 256, 0, stream>>>(R0, LIST, SEGW, SEGP0, SEGP1, SEGBASE, KV, SB);

        // ---- F += y @ Wproj + bproj ----
        gemm_bf16<<<g1, 256, 0, stream>>>(R0 + 128, 256, WPROJT, BPROJ, 128,
                                          F, CCH, 0, 1);

        // ---- BN1 -> FB (R0 cols 0..127 of ld 256), F[:,96:] = 2*FB ----
        bn_partial<<<NBLK_STATS, 128, 0, stream>>>(F, PART);
        bn_finalize<<<1, 128, 0, stream>>>(PART, bn1_g + d * CCH, bn1_b + d * CCH, SC1, SH1);
        bn_apply<<<12500, 256, 0, stream>>>(F, R0, SC1, SH1);

        // ---- submanifold convs (residual fused) ----
        conv_g<27><<<3125, 256, 0, stream>>>(nbr_k, Wk + (size_t)d * 27 * 1024, R0, 0,  F, 0);
        conv_g<13><<<3125, 256, 0, stream>>>(nbr_h, Wh + (size_t)d * 13 * 1024, R0, 32, F, 32);
        conv_g<13><<<3125, 256, 0, stream>>>(nbr_w, Ww + (size_t)d * 13 * 1024, R0, 64, F, 64);

        // ---- BN2 stats + folded W for fc1; fc2 prep ----
        bn_partial<<<NBLK_STATS, 128, 0, stream>>>(F, PART);
        bn_finalize<<<1, 128, 0, stream>>>(PART, bn2_g + d * CCH, bn2_b + d * CCH, SC2, SH2);
        wprep<<<256, 128, 0, stream>>>(fc1_W + (size_t)d * CCH * 256, 128, 256,
                                       SC2, SH2, fc1_b + d * 256, WFC1T, BFC1);
        wprep<<<128, 128, 0, stream>>>(fc2_W + (size_t)d * 256 * CCH, 256, 128,
                                       nullptr, nullptr, fc2_b + d * CCH, WFC2T, BFC2);

        // ---- MLP ----
        gemm_bf16<<<g2, 256, 0, stream>>>(F, CCH, WFC1T, BFC1, 128,
                                          R0, 256, 256, 0);
        gemm_bf16<<<g1, 256, 0, stream>>>(R0, 256, WFC2T, BFC2, 256,
                                          F, CCH, 0, 1);
    }
}

// Round 9
// 1093.092 us; speedup vs baseline: 3.3837x; 1.2385x over previous
//
#include <hip/hip_runtime.h>
#include <math.h>

#define NPTS 100000
#define CCH 128
#define NWIN 200
#define NBLK_STATS 512
#define NBLK_SORT 391   // ceil(NPTS/256)
#define SEGSZ 128
#define NSEG_MAX 1024   // >= 200 + ceil(100000/128) = 982

#define BM 128
#define BN 128
#define BK 64

typedef __attribute__((ext_vector_type(8))) short bf16x8;
typedef __attribute__((ext_vector_type(4))) float f32x4;
typedef __attribute__((ext_vector_type(4))) unsigned short u16x4;

__device__ __forceinline__ unsigned short f2bf(float f) {
    union { float f; unsigned u; } x; x.f = f;
    unsigned r = x.u + 0x7fff + ((x.u >> 16) & 1);   // RNE (no NaN inputs here)
    return (unsigned short)(r >> 16);
}

// ---------------- BN statistics: vectorized, 8 rows/block-pass ----------------
// part[b*256 + c] = partial sum of channel c over rows {b*8+rg + 4096*i};
// part[b*256 + 128 + c] = partial sum of squares.
__global__ __launch_bounds__(256) void bn_partial(const float* __restrict__ F,
                                                  float* __restrict__ part) {
    int t = threadIdx.x;
    int b = blockIdx.x;
    int rg = t >> 5;            // row group 0..7
    int c4 = (t & 31) * 4;      // channel quad
    float s0=0.f,s1=0.f,s2=0.f,s3=0.f,q0=0.f,q1=0.f,q2=0.f,q3=0.f;
    for (int n = b * 8 + rg; n < NPTS; n += NBLK_STATS * 8) {
        float4 v = *reinterpret_cast<const float4*>(&F[(size_t)n * CCH + c4]);
        s0 += v.x; s1 += v.y; s2 += v.z; s3 += v.w;
        q0 += v.x*v.x; q1 += v.y*v.y; q2 += v.z*v.z; q3 += v.w*v.w;
    }
    __shared__ float red[8][256];
    red[rg][c4+0] = s0; red[rg][c4+1] = s1; red[rg][c4+2] = s2; red[rg][c4+3] = s3;
    red[rg][128+c4+0] = q0; red[rg][128+c4+1] = q1; red[rg][128+c4+2] = q2; red[rg][128+c4+3] = q3;
    __syncthreads();
    float a = 0.f;
#pragma unroll
    for (int g = 0; g < 8; g++) a += red[g][t];
    part[b * 256 + t] = a;
}

__global__ void bn_finalize(const float* __restrict__ part,
                            const float* __restrict__ g, const float* __restrict__ bb,
                            float* __restrict__ scale, float* __restrict__ shift) {
    int c = threadIdx.x;            // 128 threads
    double s = 0.0, q = 0.0;
    for (int b = 0; b < NBLK_STATS; b++) {
        s += (double)part[b * 256 + c];
        q += (double)part[b * 256 + 128 + c];
    }
    double m = s / (double)NPTS;
    double var = q / (double)NPTS - m * m;
    double rstd = 1.0 / sqrt(var + 1e-3);
    float sc = (float)rstd * g[c];
    scale[c] = sc;
    shift[c] = bb[c] - (float)m * sc;
}

// ---------------- W prep: WT[n][k] = bf16(scale[k]*W[k][n]); biasf[n] = sum_k shift[k]*W[k][n] + bias[n]
__global__ __launch_bounds__(128) void wprep(
    const float* __restrict__ W, int K, int N,
    const float* __restrict__ sc, const float* __restrict__ sh,
    const float* __restrict__ bias,
    unsigned short* __restrict__ WT, float* __restrict__ biasf)
{
    int n = blockIdx.x;
    int t = threadIdx.x;
    float part = 0.f;
    for (int k = t; k < K; k += 128) {
        float w = W[(size_t)k * N + n];
        float s = sc ? sc[k] * w : w;
        WT[(size_t)n * K + k] = f2bf(s);
        if (sh) part += sh[k] * w;
    }
    __shared__ float red[128];
    red[t] = part;
    __syncthreads();
    for (int o = 64; o > 0; o >>= 1) {
        if (t < o) red[t] += red[t + o];
        __syncthreads();
    }
    if (t == 0) biasf[n] = red[0] + (bias ? bias[n] : 0.f);
}

// ---------------- bf16 MFMA GEMM (BN pre-folded into WT/biasf) ----------------
__global__ __launch_bounds__(256) void gemm_bf16(
    const float* __restrict__ A, int lda,
    const unsigned short* __restrict__ WT, const float* __restrict__ biasf,
    int K,
    float* __restrict__ Out, int ldo,
    int reluLim, int addFlag)
{
    __shared__ __align__(16) char smem[34048];
    unsigned short* As = (unsigned short*)smem;          // [128][64] bf16, swizzled
    unsigned short* Bs = As + BM * BK;                   // [128][64] bf16, swizzled
    float* Ep = (float*)smem;                            // [64][132] f32 epilogue

    const int tid  = threadIdx.x;
    const int wave = tid >> 6;
    const int lane = tid & 63;
    const int bm = blockIdx.x * BM;
    const int bn = blockIdx.y * BN;

    f32x4 acc[2][8];
#pragma unroll
    for (int i = 0; i < 2; i++)
#pragma unroll
        for (int j = 0; j < 8; j++)
            acc[i][j] = (f32x4){0.f, 0.f, 0.f, 0.f};

    const int arow_t = tid >> 4;          // 0..15
    const int acol   = (tid & 15) * 4;    // 0..60
    const int brow_t = tid >> 3;          // 0..31
    const int bslot  = tid & 7;           // 0..7
    const int lrow = lane & 15;
    const int lhk  = lane >> 4;           // 0..3

    for (int kk = 0; kk < K; kk += BK) {
#pragma unroll
        for (int pass = 0; pass < 8; pass++) {
            int row = pass * 16 + arow_t;
            int grow = bm + row;
            float4 v = make_float4(0.f, 0.f, 0.f, 0.f);
            if (grow < NPTS)
                v = *reinterpret_cast<const float4*>(&A[(size_t)grow * lda + kk + acol]);
            u16x4 h = { f2bf(v.x), f2bf(v.y), f2bf(v.z), f2bf(v.w) };
            int s = acol >> 3;
            int sw = s ^ (row & 7);
            *reinterpret_cast<u16x4*>(&As[row * 64 + sw * 8 + (acol & 7)]) = h;
        }
#pragma unroll
        for (int pass = 0; pass < 4; pass++) {
            int n = pass * 32 + brow_t;
            bf16x8 w = *reinterpret_cast<const bf16x8*>(&WT[(size_t)(bn + n) * K + kk + bslot * 8]);
            int sw = bslot ^ (n & 7);
            *reinterpret_cast<bf16x8*>(&Bs[n * 64 + sw * 8]) = w;
        }
        __syncthreads();

#pragma unroll
        for (int ks = 0; ks < 2; ks++) {
            bf16x8 af[2], bfr[8];
#pragma unroll
            for (int fi = 0; fi < 2; fi++) {
                int row = wave * 32 + fi * 16 + lrow;
                int sw = (ks * 4 + lhk) ^ (row & 7);
                af[fi] = *reinterpret_cast<const bf16x8*>(&As[row * 64 + sw * 8]);
            }
#pragma unroll
            for (int fj = 0; fj < 8; fj++) {
                int col = fj * 16 + lrow;
                int sw = (ks * 4 + lhk) ^ (col & 7);
                bfr[fj] = *reinterpret_cast<const bf16x8*>(&Bs[col * 64 + sw * 8]);
            }
#pragma unroll
            for (int fi = 0; fi < 2; fi++)
#pragma unroll
                for (int fj = 0; fj < 8; fj++)
                    acc[fi][fj] = __builtin_amdgcn_mfma_f32_16x16x32_bf16(
                        af[fi], bfr[fj], acc[fi][fj], 0, 0, 0);
        }
        __syncthreads();
    }

    for (int hh = 0; hh < 2; hh++) {
        if ((wave >> 1) == hh) {
#pragma unroll
            for (int fi = 0; fi < 2; fi++) {
                int row = (wave & 1) * 32 + fi * 16 + (lane >> 4) * 4;
#pragma unroll
                for (int fj = 0; fj < 8; fj++) {
                    int col = fj * 16 + (lane & 15);
#pragma unroll
                    for (int r = 0; r < 4; r++)
                        Ep[(row + r) * 132 + col] = acc[fi][fj][r];
                }
            }
        }
        __syncthreads();
#pragma unroll
        for (int pass = 0; pass < 8; pass++) {
            int idx = pass * 256 + tid;     // 0..2047
            int r = idx >> 5;               // 0..63
            int c4 = (idx & 31) * 4;        // 0..124
            int rr = bm + hh * 64 + r;
            if (rr < NPTS) {
                float4 v = *reinterpret_cast<const float4*>(&Ep[r * 132 + c4]);
                float4 b = *reinterpret_cast<const float4*>(&biasf[bn + c4]);
                v.x += b.x; v.y += b.y; v.z += b.z; v.w += b.w;
                int col = bn + c4;
                if (col + 0 < reluLim) v.x = fmaxf(v.x, 0.f);
                if (col + 1 < reluLim) v.y = fmaxf(v.y, 0.f);
                if (col + 2 < reluLim) v.z = fmaxf(v.z, 0.f);
                if (col + 3 < reluLim) v.w = fmaxf(v.w, 0.f);
                float* o = &Out[(size_t)rr * ldo + bn + c4];
                if (addFlag) {
                    float4 ov = *reinterpret_cast<const float4*>(o);
                    v.x += ov.x; v.y += ov.y; v.z += ov.z; v.w += ov.w;
                }
                *reinterpret_cast<float4*>(o) = v;
            }
        }
        __syncthreads();
    }
}

// ---------------- window list build (block-local counting sort) ----------------
__global__ __launch_bounds__(256) void hist2_k(const int* __restrict__ wi,
                                               int* __restrict__ BH, int* __restrict__ HIST) {
    __shared__ int h[NWIN];
    int t = threadIdx.x;
    if (t < NWIN) h[t] = 0;
    __syncthreads();
    int n = blockIdx.x * 256 + t;
    if (n < NPTS) atomicAdd(&h[wi[n]], 1);
    __syncthreads();
    if (t < NWIN) {
        BH[blockIdx.x * 256 + t] = h[t];
        if (h[t]) atomicAdd(&HIST[t], h[t]);
    }
}

__global__ void scan_k(const int* __restrict__ hist, int* __restrict__ offs) {
    if (threadIdx.x == 0 && blockIdx.x == 0) {
        int a = 0;
        for (int w = 0; w < NWIN; w++) { offs[w] = a; a += hist[w]; }
        offs[NWIN] = a;
    }
}

__global__ void colscan_k(const int* __restrict__ BH, const int* __restrict__ OFFS,
                          int* __restrict__ OFFB) {
    int w = threadIdx.x;
    if (w >= NWIN) return;
    int a = OFFS[w];
    for (int b = 0; b < NBLK_SORT; b++) {
        OFFB[b * 256 + w] = a;
        a += BH[b * 256 + w];
    }
}

__global__ __launch_bounds__(256) void scatter2_k(const int* __restrict__ wi,
                                                  const int* __restrict__ OFFB,
                                                  int* __restrict__ list) {
    __shared__ int h[NWIN];
    int t = threadIdx.x;
    if (t < NWIN) h[t] = 0;
    __syncthreads();
    int n = blockIdx.x * 256 + t;
    if (n < NPTS) {
        int w = wi[n];
        int r = atomicAdd(&h[w], 1);
        list[OFFB[blockIdx.x * 256 + w] + r] = n;
    }
}

// ---------------- segment build: window-aligned segments of <= SEGSZ points ----------------
__global__ void segbuild_k(const int* __restrict__ OFFS,
                           int* __restrict__ SEGW, int* __restrict__ SEGP0,
                           int* __restrict__ SEGP1, int* __restrict__ SEGBASE) {
    __shared__ int base[NWIN];
    int w = threadIdx.x;
    if (w < NWIN) {
        int n = OFFS[w + 1] - OFFS[w];
        base[w] = (n + SEGSZ - 1) / SEGSZ;
    }
    __syncthreads();
    if (threadIdx.x == 0) {
        int a = 0;
        for (int i = 0; i < NWIN; i++) { int c = base[i]; base[i] = a; SEGBASE[i] = a; a += c; }
        SEGBASE[NWIN] = a;
    }
    __syncthreads();
    if (w < NWIN) {
        int b = base[w];
        int p0 = OFFS[w], p1 = OFFS[w + 1];
        for (int p = p0; p < p1; p += SEGSZ) {
            SEGW[b] = w; SEGP0[b] = p; SEGP1[b] = min(p + SEGSZ, p1); b++;
        }
    }
}

// ---------------- per-segment K^T V and sum(K): register acc, PLAIN stores ----------------
__global__ __launch_bounds__(256) void window_kv_seg(
    const float* __restrict__ R0,
    const int* __restrict__ list,
    const int* __restrict__ SEGP0, const int* __restrict__ SEGP1,
    const int* __restrict__ SEGBASE,
    float* __restrict__ PKV)
{
    int sid = blockIdx.x;
    if (sid >= SEGBASE[NWIN]) return;
    int t = threadIdx.x;
    int p0 = SEGP0[sid], p1 = SEGP1[sid];
    __shared__ float buf[8][256];
    float acc[8] = {0.f,0.f,0.f,0.f,0.f,0.f,0.f,0.f};
    float sa = 0.f;
    int f0 = t * 8;
    int h = f0 >> 8;
    int c = (f0 >> 4) & 15;
    int d0 = f0 & 15;
    const int sr = t >> 5;          // staging row 0..7
    const int sc4 = (t & 31) * 4;   // staging float4 col

    for (int g = p0; g < p1; g += 8) {
        int m = min(8, p1 - g);
        int nj[8];
#pragma unroll
        for (int j = 0; j < 8; j++)
            nj[j] = list[(g + j < p1) ? g + j : p1 - 1];
        __syncthreads();   // buf free (previous group consumed)
        {
            const float* row = &R0[(size_t)nj[sr] * 256];
            *reinterpret_cast<float4*>(&buf[sr][sc4]) =
                *reinterpret_cast<const float4*>(&row[sc4]);
            *reinterpret_cast<float4*>(&buf[sr][128 + sc4]) =
                *reinterpret_cast<const float4*>(&row[128 + sc4]);
        }
        __syncthreads();
#pragma unroll
        for (int j = 0; j < 8; j++) {
            if (j >= m) break;
            float kc = buf[j][h * 16 + c];
#pragma unroll
            for (int i = 0; i < 8; i++) acc[i] += kc * buf[j][128 + h * 16 + d0 + i];
            if (t < 128) sa += buf[j][t];
        }
    }
    float* out = &PKV[(size_t)sid * 2176];
#pragma unroll
    for (int i = 0; i < 8; i++) out[f0 + i] = acc[i];
    if (t < 128) out[2048 + t] = sa;
}

// ---------------- reduce segment partials per window ----------------
__global__ __launch_bounds__(256) void kv_reduce(
    const float* __restrict__ PKV, const int* __restrict__ SEGBASE,
    float* __restrict__ KV, float* __restrict__ SB)
{
    int w = blockIdx.x;
    int t = threadIdx.x;
    int s0 = SEGBASE[w], s1 = SEGBASE[w + 1];
    float a[8] = {0.f,0.f,0.f,0.f,0.f,0.f,0.f,0.f};
    float sb = 0.f;
    for (int s = s0; s < s1; s++) {
        const float* p = &PKV[(size_t)s * 2176];
#pragma unroll
        for (int i = 0; i < 8; i++) a[i] += p[t * 8 + i];
        if (t < 128) sb += p[2048 + t];
    }
#pragma unroll
    for (int i = 0; i < 8; i++) KV[w * 2048 + t * 8 + i] = a[i];
    if (t < 128) SB[w * 128 + t] = sb;
}

// ---------------- y = (q . kv[w]) / (q . s[w] + eps), segment-parallel, KV in registers ----------------
__global__ __launch_bounds__(256) void attn_y_seg(
    float* __restrict__ R0,
    const int* __restrict__ list,
    const int* __restrict__ SEGW, const int* __restrict__ SEGP0,
    const int* __restrict__ SEGP1, const int* __restrict__ SEGBASE,
    const float* __restrict__ KV, const float* __restrict__ SB)
{
    int sid = blockIdx.x;
    if (sid >= SEGBASE[NWIN]) return;
    int t = threadIdx.x;
    int w = SEGW[sid];
    int g  = t >> 5;            // point group 0..7
    int h  = (t >> 2) & 7;      // head
    int d4 = (t & 3) * 4;       // output d offset

    float4 kvr[16];
    const float* kvb = &KV[w * 2048 + h * 256 + d4];
#pragma unroll
    for (int cc = 0; cc < 16; cc++)
        kvr[cc] = *reinterpret_cast<const float4*>(&kvb[cc * 16]);
    float sreg[16];
    const float* sb = &SB[w * 128 + h * 16];
#pragma unroll
    for (int cc = 0; cc < 16; cc++) sreg[cc] = sb[cc];

    int p0 = SEGP0[sid], p1 = SEGP1[sid];
    for (int p = p0 + g; p < p1; p += 8) {
        int n = list[p];
        const float* q = &R0[(size_t)n * 256 + h * 16];
        float4 q0 = *reinterpret_cast<const float4*>(&q[0]);
        float4 q1 = *reinterpret_cast<const float4*>(&q[4]);
        float4 q2 = *reinterpret_cast<const float4*>(&q[8]);
        float4 q3 = *reinterpret_cast<const float4*>(&q[12]);
        float qq[16] = { q0.x,q0.y,q0.z,q0.w, q1.x,q1.y,q1.z,q1.w,
                         q2.x,q2.y,q2.z,q2.w, q3.x,q3.y,q3.z,q3.w };
        float z = 0.f;
        float4 y = make_float4(0.f, 0.f, 0.f, 0.f);
#pragma unroll
        for (int cc = 0; cc < 16; cc++) {
            z += qq[cc] * sreg[cc];
            y.x += qq[cc] * kvr[cc].x;
            y.y += qq[cc] * kvr[cc].y;
            y.z += qq[cc] * kvr[cc].z;
            y.w += qq[cc] * kvr[cc].w;
        }
        float inv = 1.f / (z + 1e-3f);
        float4 o = make_float4(y.x * inv, y.y * inv, y.z * inv, y.w * inv);
        *reinterpret_cast<float4*>(&R0[(size_t)n * 256 + 128 + h * 16 + d4]) = o;
    }
}

// ---------------- bn apply: FB = bn1(F); F[:,96:128] = 2*FB ----------------
__global__ void bn_apply(float* F, float* FB,
                         const float* __restrict__ scale, const float* __restrict__ shift)
{
    int i = blockIdx.x * 256 + threadIdx.x;
    int n = i >> 5;
    int c4 = (i & 31) * 4;
    float4 v = *reinterpret_cast<const float4*>(&F[n * CCH + c4]);
    float4 o;
    o.x = v.x * scale[c4 + 0] + shift[c4 + 0];
    o.y = v.y * scale[c4 + 1] + shift[c4 + 1];
    o.z = v.z * scale[c4 + 2] + shift[c4 + 2];
    o.w = v.w * scale[c4 + 3] + shift[c4 + 3];
    *reinterpret_cast<float4*>(&FB[n * 256 + c4]) = o;
    if (c4 >= 96) {
        float4 t = make_float4(2.f * o.x, 2.f * o.y, 2.f * o.z, 2.f * o.w);
        *reinterpret_cast<float4*>(&F[n * CCH + c4]) = t;
    }
}

// ---------------- submanifold conv ----------------
template<int KN>
__global__ __launch_bounds__(256) void conv_g(
    const int* __restrict__ nbr, const float* __restrict__ Wc,
    const float* __restrict__ FB, int goff,
    float* __restrict__ Fout, int outoff)
{
    int t = blockIdx.x * 256 + threadIdx.x;
    int pt = t >> 3;
    int so = (t & 7) * 4;
    if (pt >= NPTS) return;
    float acc0 = 0.f, acc1 = 0.f, acc2 = 0.f, acc3 = 0.f;
    const int* nb = &nbr[pt * KN];
#pragma unroll 1
    for (int k = 0; k < KN; k++) {
        int idx = nb[k];
        if (idx >= NPTS) continue;   // sentinel row = zeros
        const float* rr = &FB[idx * 256 + goff];
        const float* wk = &Wc[k * 1024 + so];
#pragma unroll
        for (int c = 0; c < 32; c += 4) {
            float4 rv = *reinterpret_cast<const float4*>(&rr[c]);
            float4 w0 = *reinterpret_cast<const float4*>(&wk[(c + 0) * 32]);
            float4 w1 = *reinterpret_cast<const float4*>(&wk[(c + 1) * 32]);
            float4 w2 = *reinterpret_cast<const float4*>(&wk[(c + 2) * 32]);
            float4 w3 = *reinterpret_cast<const float4*>(&wk[(c + 3) * 32]);
            acc0 += rv.x * w0.x + rv.y * w1.x + rv.z * w2.x + rv.w * w3.x;
            acc1 += rv.x * w0.y + rv.y * w1.y + rv.z * w2.y + rv.w * w3.y;
            acc2 += rv.x * w0.z + rv.y * w1.z + rv.z * w2.z + rv.w * w3.z;
            acc3 += rv.x * w0.w + rv.y * w1.w + rv.z * w2.w + rv.w * w3.w;
        }
    }
    float4 fb = *reinterpret_cast<const float4*>(&FB[pt * 256 + goff + so]);
    float4 o = make_float4(fb.x + acc0, fb.y + acc1, fb.z + acc2, fb.w + acc3);
    *reinterpret_cast<float4*>(&Fout[pt * CCH + outoff + so]) = o;
}

// ---------------- launch ----------------
extern "C" void kernel_launch(void* const* d_in, const int* in_sizes, int n_in,
                              void* d_out, int out_size, void* d_ws, size_t ws_size,
                              hipStream_t stream)
{
    const float* feats   = (const float*)d_in[0];
    const int*   win_inds= (const int*)d_in[1];
    const int*   nbr_k   = (const int*)d_in[2];
    const int*   nbr_h   = (const int*)d_in[3];
    const int*   nbr_w   = (const int*)d_in[4];
    const float* bn_g    = (const float*)d_in[5];
    const float* bn_b    = (const float*)d_in[6];
    const float* Wqkv    = (const float*)d_in[7];
    const float* Wproj   = (const float*)d_in[8];
    const float* bproj   = (const float*)d_in[9];
    const float* bn1_g   = (const float*)d_in[10];
    const float* bn1_b   = (const float*)d_in[11];
    const float* Wk      = (const float*)d_in[12];
    const float* Wh      = (const float*)d_in[13];
    const float* Ww      = (const float*)d_in[14];
    const float* bn2_g   = (const float*)d_in[15];
    const float* bn2_b   = (const float*)d_in[16];
    const float* fc1_W   = (const float*)d_in[17];
    const float* fc1_b   = (const float*)d_in[18];
    const float* fc2_W   = (const float*)d_in[19];
    const float* fc2_b   = (const float*)d_in[20];

    float* F  = (float*)d_out;
    float* R0 = (float*)d_ws;                       // NPTS*256
    float* KV = R0 + (size_t)NPTS * 256;            // NWIN*2048
    float* SB = KV + NWIN * 2048;                   // NWIN*128
    float* ST = SB + NWIN * 128;                    // 6*128
    float* PART = ST + 768;                         // NBLK_STATS*256
    float* PKV = PART + NBLK_STATS * 256;           // NSEG_MAX*2176
    int* HIST = (int*)(PKV + (size_t)NSEG_MAX * 2176);  // 256
    int* OFFS = HIST + 256;                         // 256 (201 used)
    int* LIST = OFFS + 256;                         // 100096 (NPTS rounded)
    int* BH   = LIST + 100096;                      // NBLK_SORT*256
    int* OFFB = BH + NBLK_SORT * 256;               // NBLK_SORT*256
    int* SEGW = OFFB + NBLK_SORT * 256;             // NSEG_MAX
    int* SEGP0= SEGW + NSEG_MAX;                    // NSEG_MAX
    int* SEGP1= SEGP0 + NSEG_MAX;                   // NSEG_MAX
    int* SEGBASE = SEGP1 + NSEG_MAX;                // 256
    unsigned short* WQKVT = (unsigned short*)(SEGBASE + 256);   // 384*128
    unsigned short* WPROJT = WQKVT + 384 * 128;                 // 128*128
    unsigned short* WFC1T  = WPROJT + 128 * 128;                // 256*128
    unsigned short* WFC2T  = WFC1T + 256 * 128;                 // 128*256
    float* BQKV  = (float*)(WFC2T + 128 * 256);     // 384
    float* BPROJ = BQKV + 384;                      // 128
    float* BFC1  = BPROJ + 128;                     // 256
    float* BFC2  = BFC1 + 256;                      // 128

    hipMemcpyAsync(F, feats, (size_t)NPTS * CCH * sizeof(float),
                   hipMemcpyDeviceToDevice, stream);

    dim3 g2(782, 2), g1(782, 1);    // 782 = ceil(100000/128)

    for (int d = 0; d < 2; d++) {
        const int* wi = win_inds + (size_t)d * NPTS;
        float* SC0 = ST, *SH0 = ST + 128, *SC1 = ST + 256, *SH1 = ST + 384,
             * SC2 = ST + 512, *SH2 = ST + 640;

        // ---- BN0 stats + folded W for qkv ----
        bn_partial<<<NBLK_STATS, 256, 0, stream>>>(F, PART);
        bn_finalize<<<1, 128, 0, stream>>>(PART, bn_g + d * CCH, bn_b + d * CCH, SC0, SH0);
        wprep<<<384, 128, 0, stream>>>(Wqkv + (size_t)d * CCH * 384, 128, 384,
                                       SC0, SH0, nullptr, WQKVT, BQKV);
        wprep<<<128, 128, 0, stream>>>(Wproj + (size_t)d * CCH * CCH, 128, 128,
                                       nullptr, nullptr, bproj + d * CCH, WPROJT, BPROJ);

        // ---- k,v = relu/id( bn0(F) @ Wqkv[:,128:384] ) -> R0 cols 0..255 ----
        gemm_bf16<<<g2, 256, 0, stream>>>(F, CCH, WQKVT + 128 * 128, BQKV + 128, 128,
                                          R0, 256, 128, 0);

        // ---- window lists (contention-free counting sort) ----
        hipMemsetAsync(HIST, 0, 256 * sizeof(int), stream);
        hist2_k<<<NBLK_SORT, 256, 0, stream>>>(wi, BH, HIST);
        scan_k<<<1, 64, 0, stream>>>(HIST, OFFS);
        colscan_k<<<1, 256, 0, stream>>>(BH, OFFS, OFFB);
        scatter2_k<<<NBLK_SORT, 256, 0, stream>>>(wi, OFFB, LIST);

        // ---- segments + per-segment KV partials (plain stores) + reduce ----
        segbuild_k<<<1, 256, 0, stream>>>(OFFS, SEGW, SEGP0, SEGP1, SEGBASE);
        window_kv_seg<<<NSEG_MAX, 256, 0, stream>>>(R0, LIST, SEGP0, SEGP1, SEGBASE, PKV);
        kv_reduce<<<NWIN, 256, 0, stream>>>(PKV, SEGBASE, KV, SB);

        // ---- q = relu( bn0(F) @ Wqkv[:,0:128] ) -> R0 cols 0..127 (over dead k) ----
        gemm_bf16<<<g1, 256, 0, stream>>>(F, CCH, WQKVT, BQKV, 128,
                                          R0, 256, 128, 0);

        // ---- y -> R0 cols 128..255 (over dead v); segment-parallel, KV in regs ----
        attn_y_seg<<<NSEG_MAX, 256, 0, stream>>>(R0, LIST, SEGW, SEGP0, SEGP1, SEGBASE, KV, SB);

        // ---- F += y @ Wproj + bproj ----
        gemm_bf16<<<g1, 256, 0, stream>>>(R0 + 128, 256, WPROJT, BPROJ, 128,
                                          F, CCH, 0, 1);

        // ---- BN1 -> FB (R0 cols 0..127 of ld 256), F[:,96:] = 2*FB ----
        bn_partial<<<NBLK_STATS, 256, 0, stream>>>(F, PART);
        bn_finalize<<<1, 128, 0, stream>>>(PART, bn1_g + d * CCH, bn1_b + d * CCH, SC1, SH1);
        bn_apply<<<12500, 256, 0, stream>>>(F, R0, SC1, SH1);

        // ---- submanifold convs (residual fused) ----
        conv_g<27><<<3125, 256, 0, stream>>>(nbr_k, Wk + (size_t)d * 27 * 1024, R0, 0,  F, 0);
        conv_g<13><<<3125, 256, 0, stream>>>(nbr_h, Wh + (size_t)d * 13 * 1024, R0, 32, F, 32);
        conv_g<13><<<3125, 256, 0, stream>>>(nbr_w, Ww + (size_t)d * 13 * 1024, R0, 64, F, 64);

        // ---- BN2 stats + folded W for fc1; fc2 prep ----
        bn_partial<<<NBLK_STATS, 256, 0, stream>>>(F, PART);
        bn_finalize<<<1, 128, 0, stream>>>(PART, bn2_g + d * CCH, bn2_b + d * CCH, SC2, SH2);
        wprep<<<256, 128, 0, stream>>>(fc1_W + (size_t)d * CCH * 256, 128, 256,
                                       SC2, SH2, fc1_b + d * 256, WFC1T, BFC1);
        wprep<<<128, 128, 0, stream>>>(fc2_W + (size_t)d * 256 * CCH, 256, 128,
                                       nullptr, nullptr, fc2_b + d * CCH, WFC2T, BFC2);

        // ---- MLP ----
        gemm_bf16<<<g2, 256, 0, stream>>>(F, CCH, WFC1T, BFC1, 128,
                                          R0, 256, 256, 0);
        gemm_bf16<<<g1, 256, 0, stream>>>(R0, 256, WFC2T, BFC2, 256,
                                          F, CCH, 0, 1);
    }
}

// Round 10
// 1019.912 us; speedup vs baseline: 3.6265x; 1.0718x over previous
//
#include <hip/hip_runtime.h>
#include <math.h>

#define NPTS 100000
#define CCH 128
#define NWIN 200
#define NBLK_STATS 512
#define NBLK_SORT 391   // ceil(NPTS/256)
#define SEGSZ 128
#define NSEG_MAX 1024   // >= 200 + ceil(100000/128) = 982

#define BM 128
#define BN 128
#define BK 64

typedef __attribute__((ext_vector_type(8))) short bf16x8;
typedef __attribute__((ext_vector_type(4))) float f32x4;
typedef __attribute__((ext_vector_type(4))) unsigned short u16x4;

__device__ __forceinline__ unsigned short f2bf(float f) {
    union { float f; unsigned u; } x; x.f = f;
    unsigned r = x.u + 0x7fff + ((x.u >> 16) & 1);   // RNE (no NaN inputs here)
    return (unsigned short)(r >> 16);
}
__device__ __forceinline__ float bf2f(unsigned short h) {
    union { unsigned u; float f; } x; x.u = ((unsigned)h) << 16;
    return x.f;
}

// ---------------- BN statistics: vectorized, 8 rows/block-pass ----------------
__global__ __launch_bounds__(256) void bn_partial(const float* __restrict__ F,
                                                  float* __restrict__ part) {
    int t = threadIdx.x;
    int b = blockIdx.x;
    int rg = t >> 5;            // row group 0..7
    int c4 = (t & 31) * 4;      // channel quad
    float s0=0.f,s1=0.f,s2=0.f,s3=0.f,q0=0.f,q1=0.f,q2=0.f,q3=0.f;
    for (int n = b * 8 + rg; n < NPTS; n += NBLK_STATS * 8) {
        float4 v = *reinterpret_cast<const float4*>(&F[(size_t)n * CCH + c4]);
        s0 += v.x; s1 += v.y; s2 += v.z; s3 += v.w;
        q0 += v.x*v.x; q1 += v.y*v.y; q2 += v.z*v.z; q3 += v.w*v.w;
    }
    __shared__ float red[8][256];
    red[rg][c4+0] = s0; red[rg][c4+1] = s1; red[rg][c4+2] = s2; red[rg][c4+3] = s3;
    red[rg][128+c4+0] = q0; red[rg][128+c4+1] = q1; red[rg][128+c4+2] = q2; red[rg][128+c4+3] = q3;
    __syncthreads();
    float a = 0.f;
#pragma unroll
    for (int g = 0; g < 8; g++) a += red[g][t];
    part[b * 256 + t] = a;
}

__global__ void bn_finalize(const float* __restrict__ part,
                            const float* __restrict__ g, const float* __restrict__ bb,
                            float* __restrict__ scale, float* __restrict__ shift) {
    int c = threadIdx.x;            // 128 threads
    double s = 0.0, q = 0.0;
    for (int b = 0; b < NBLK_STATS; b++) {
        s += (double)part[b * 256 + c];
        q += (double)part[b * 256 + 128 + c];
    }
    double m = s / (double)NPTS;
    double var = q / (double)NPTS - m * m;
    double rstd = 1.0 / sqrt(var + 1e-3);
    float sc = (float)rstd * g[c];
    scale[c] = sc;
    shift[c] = bb[c] - (float)m * sc;
}

// ---------------- W prep ----------------
__global__ __launch_bounds__(128) void wprep(
    const float* __restrict__ W, int K, int N,
    const float* __restrict__ sc, const float* __restrict__ sh,
    const float* __restrict__ bias,
    unsigned short* __restrict__ WT, float* __restrict__ biasf)
{
    int n = blockIdx.x;
    int t = threadIdx.x;
    float part = 0.f;
    for (int k = t; k < K; k += 128) {
        float w = W[(size_t)k * N + n];
        float s = sc ? sc[k] * w : w;
        WT[(size_t)n * K + k] = f2bf(s);
        if (sh) part += sh[k] * w;
    }
    __shared__ float red[128];
    red[t] = part;
    __syncthreads();
    for (int o = 64; o > 0; o >>= 1) {
        if (t < o) red[t] += red[t + o];
        __syncthreads();
    }
    if (t == 0) biasf[n] = red[0] + (bias ? bias[n] : 0.f);
}

// ---------------- bf16 MFMA GEMM, templated A/out dtype ----------------
// ABF: A is bf16 (straight copy staging); else f32 (cvt in staging).
// OBF: out bf16 (no addFlag support); else f32 (bias/relu/residual).
template<int ABF, int OBF>
__global__ __launch_bounds__(256) void gemm_t(
    const void* __restrict__ Ap, int lda,
    const unsigned short* __restrict__ WT, const float* __restrict__ biasf,
    int K,
    void* __restrict__ Outp, int ldo,
    int reluLim, int addFlag)
{
    __shared__ __align__(16) char smem[34048];
    unsigned short* As = (unsigned short*)smem;          // [128][64] bf16, swizzled
    unsigned short* Bs = As + BM * BK;                   // [128][64] bf16, swizzled
    float* Ep = (float*)smem;                            // [64][132] f32 epilogue

    const int tid  = threadIdx.x;
    const int wave = tid >> 6;
    const int lane = tid & 63;
    const int bm = blockIdx.x * BM;
    const int bn = blockIdx.y * BN;

    f32x4 acc[2][8];
#pragma unroll
    for (int i = 0; i < 2; i++)
#pragma unroll
        for (int j = 0; j < 8; j++)
            acc[i][j] = (f32x4){0.f, 0.f, 0.f, 0.f};

    const int lrow = lane & 15;
    const int lhk  = lane >> 4;           // 0..3

    for (int kk = 0; kk < K; kk += BK) {
        // ---- stage A ----
        if (ABF) {
            const unsigned short* Ab = (const unsigned short*)Ap;
#pragma unroll
            for (int pass = 0; pass < 4; pass++) {
                int row = pass * 32 + (tid >> 3);
                int grow = bm + row;
                bf16x8 w = (bf16x8){0,0,0,0,0,0,0,0};
                if (grow < NPTS)
                    w = *reinterpret_cast<const bf16x8*>(&Ab[(size_t)grow * lda + kk + (tid & 7) * 8]);
                int sw = (tid & 7) ^ (row & 7);
                *reinterpret_cast<bf16x8*>(&As[row * 64 + sw * 8]) = w;
            }
        } else {
            const float* Af = (const float*)Ap;
            const int arow_t = tid >> 4;
            const int acol   = (tid & 15) * 4;
#pragma unroll
            for (int pass = 0; pass < 8; pass++) {
                int row = pass * 16 + arow_t;
                int grow = bm + row;
                float4 v = make_float4(0.f, 0.f, 0.f, 0.f);
                if (grow < NPTS)
                    v = *reinterpret_cast<const float4*>(&Af[(size_t)grow * lda + kk + acol]);
                u16x4 h = { f2bf(v.x), f2bf(v.y), f2bf(v.z), f2bf(v.w) };
                int s = acol >> 3;
                int sw = s ^ (row & 7);
                *reinterpret_cast<u16x4*>(&As[row * 64 + sw * 8 + (acol & 7)]) = h;
            }
        }
        // ---- stage B ----
#pragma unroll
        for (int pass = 0; pass < 4; pass++) {
            int n = pass * 32 + (tid >> 3);
            bf16x8 w = *reinterpret_cast<const bf16x8*>(&WT[(size_t)(bn + n) * K + kk + (tid & 7) * 8]);
            int sw = (tid & 7) ^ (n & 7);
            *reinterpret_cast<bf16x8*>(&Bs[n * 64 + sw * 8]) = w;
        }
        __syncthreads();

#pragma unroll
        for (int ks = 0; ks < 2; ks++) {
            bf16x8 af[2], bfr[8];
#pragma unroll
            for (int fi = 0; fi < 2; fi++) {
                int row = wave * 32 + fi * 16 + lrow;
                int sw = (ks * 4 + lhk) ^ (row & 7);
                af[fi] = *reinterpret_cast<const bf16x8*>(&As[row * 64 + sw * 8]);
            }
#pragma unroll
            for (int fj = 0; fj < 8; fj++) {
                int col = fj * 16 + lrow;
                int sw = (ks * 4 + lhk) ^ (col & 7);
                bfr[fj] = *reinterpret_cast<const bf16x8*>(&Bs[col * 64 + sw * 8]);
            }
#pragma unroll
            for (int fi = 0; fi < 2; fi++)
#pragma unroll
                for (int fj = 0; fj < 8; fj++)
                    acc[fi][fj] = __builtin_amdgcn_mfma_f32_16x16x32_bf16(
                        af[fi], bfr[fj], acc[fi][fj], 0, 0, 0);
        }
        __syncthreads();
    }

    // ---- epilogue: LDS bounce -> coalesced stores ----
    for (int hh = 0; hh < 2; hh++) {
        if ((wave >> 1) == hh) {
#pragma unroll
            for (int fi = 0; fi < 2; fi++) {
                int row = (wave & 1) * 32 + fi * 16 + (lane >> 4) * 4;
#pragma unroll
                for (int fj = 0; fj < 8; fj++) {
                    int col = fj * 16 + (lane & 15);
#pragma unroll
                    for (int r = 0; r < 4; r++)
                        Ep[(row + r) * 132 + col] = acc[fi][fj][r];
                }
            }
        }
        __syncthreads();
#pragma unroll
        for (int pass = 0; pass < 8; pass++) {
            int idx = pass * 256 + tid;     // 0..2047
            int r = idx >> 5;               // 0..63
            int c4 = (idx & 31) * 4;        // 0..124
            int rr = bm + hh * 64 + r;
            if (rr < NPTS) {
                float4 v = *reinterpret_cast<const float4*>(&Ep[r * 132 + c4]);
                float4 b = *reinterpret_cast<const float4*>(&biasf[bn + c4]);
                v.x += b.x; v.y += b.y; v.z += b.z; v.w += b.w;
                int col = bn + c4;
                if (col + 0 < reluLim) v.x = fmaxf(v.x, 0.f);
                if (col + 1 < reluLim) v.y = fmaxf(v.y, 0.f);
                if (col + 2 < reluLim) v.z = fmaxf(v.z, 0.f);
                if (col + 3 < reluLim) v.w = fmaxf(v.w, 0.f);
                if (OBF) {
                    unsigned short* o = (unsigned short*)Outp + (size_t)rr * ldo + bn + c4;
                    u16x4 hv = { f2bf(v.x), f2bf(v.y), f2bf(v.z), f2bf(v.w) };
                    *reinterpret_cast<u16x4*>(o) = hv;
                } else {
                    float* o = (float*)Outp + (size_t)rr * ldo + bn + c4;
                    if (addFlag) {
                        float4 ov = *reinterpret_cast<const float4*>(o);
                        v.x += ov.x; v.y += ov.y; v.z += ov.z; v.w += ov.w;
                    }
                    *reinterpret_cast<float4*>(o) = v;
                }
            }
        }
        __syncthreads();
    }
}

// ---------------- window list build (block-local counting sort) ----------------
__global__ __launch_bounds__(256) void hist2_k(const int* __restrict__ wi,
                                               int* __restrict__ BH, int* __restrict__ HIST) {
    __shared__ int h[NWIN];
    int t = threadIdx.x;
    if (t < NWIN) h[t] = 0;
    __syncthreads();
    int n = blockIdx.x * 256 + t;
    if (n < NPTS) atomicAdd(&h[wi[n]], 1);
    __syncthreads();
    if (t < NWIN) {
        BH[blockIdx.x * 256 + t] = h[t];
        if (h[t]) atomicAdd(&HIST[t], h[t]);
    }
}

__global__ void scan_k(const int* __restrict__ hist, int* __restrict__ offs) {
    if (threadIdx.x == 0 && blockIdx.x == 0) {
        int a = 0;
        for (int w = 0; w < NWIN; w++) { offs[w] = a; a += hist[w]; }
        offs[NWIN] = a;
    }
}

__global__ void colscan_k(const int* __restrict__ BH, const int* __restrict__ OFFS,
                          int* __restrict__ OFFB) {
    int w = threadIdx.x;
    if (w >= NWIN) return;
    int a = OFFS[w];
    for (int b = 0; b < NBLK_SORT; b++) {
        OFFB[b * 256 + w] = a;
        a += BH[b * 256 + w];
    }
}

__global__ __launch_bounds__(256) void scatter2_k(const int* __restrict__ wi,
                                                  const int* __restrict__ OFFB,
                                                  int* __restrict__ list) {
    __shared__ int h[NWIN];
    int t = threadIdx.x;
    if (t < NWIN) h[t] = 0;
    __syncthreads();
    int n = blockIdx.x * 256 + t;
    if (n < NPTS) {
        int w = wi[n];
        int r = atomicAdd(&h[w], 1);
        list[OFFB[blockIdx.x * 256 + w] + r] = n;
    }
}

// ---------------- segment build ----------------
__global__ void segbuild_k(const int* __restrict__ OFFS,
                           int* __restrict__ SEGW, int* __restrict__ SEGP0,
                           int* __restrict__ SEGP1, int* __restrict__ SEGBASE) {
    __shared__ int base[NWIN];
    int w = threadIdx.x;
    if (w < NWIN) {
        int n = OFFS[w + 1] - OFFS[w];
        base[w] = (n + SEGSZ - 1) / SEGSZ;
    }
    __syncthreads();
    if (threadIdx.x == 0) {
        int a = 0;
        for (int i = 0; i < NWIN; i++) { int c = base[i]; base[i] = a; SEGBASE[i] = a; a += c; }
        SEGBASE[NWIN] = a;
    }
    __syncthreads();
    if (w < NWIN) {
        int b = base[w];
        int p0 = OFFS[w], p1 = OFFS[w + 1];
        for (int p = p0; p < p1; p += SEGSZ) {
            SEGW[b] = w; SEGP0[b] = p; SEGP1[b] = min(p + SEGSZ, p1); b++;
        }
    }
}

// ---------------- per-segment K^T V and sum(K): bf16 in, register acc, plain stores ----------------
// R0bf rows: [q(128) | k(128) | v(128)], ld 384 bf16.
__global__ __launch_bounds__(256) void window_kv_seg(
    const unsigned short* __restrict__ R0bf,
    const int* __restrict__ list,
    const int* __restrict__ SEGP0, const int* __restrict__ SEGP1,
    const int* __restrict__ SEGBASE,
    float* __restrict__ PKV)
{
    int sid = blockIdx.x;
    if (sid >= SEGBASE[NWIN]) return;
    int t = threadIdx.x;
    int p0 = SEGP0[sid], p1 = SEGP1[sid];
    __shared__ float buf[8][256];   // [k(0..127) | v(128..255)]
    float acc[8] = {0.f,0.f,0.f,0.f,0.f,0.f,0.f,0.f};
    float sa = 0.f;
    int f0 = t * 8;
    int h = f0 >> 8;
    int c = (f0 >> 4) & 15;
    int d0 = f0 & 15;
    const int sr = t >> 5;          // staging row 0..7
    const int c8 = (t & 31) * 8;    // staging 8-col group

    for (int g = p0; g < p1; g += 8) {
        int m = min(8, p1 - g);
        int nj[8];
#pragma unroll
        for (int j = 0; j < 8; j++)
            nj[j] = list[(g + j < p1) ? g + j : p1 - 1];
        __syncthreads();   // buf free (previous group consumed)
        {
            const unsigned short* row = &R0bf[(size_t)nj[sr] * 384 + 128];
            bf16x8 hv = *reinterpret_cast<const bf16x8*>(&row[c8]);
            float4 lo = make_float4(bf2f((unsigned short)hv[0]), bf2f((unsigned short)hv[1]),
                                    bf2f((unsigned short)hv[2]), bf2f((unsigned short)hv[3]));
            float4 hi = make_float4(bf2f((unsigned short)hv[4]), bf2f((unsigned short)hv[5]),
                                    bf2f((unsigned short)hv[6]), bf2f((unsigned short)hv[7]));
            *reinterpret_cast<float4*>(&buf[sr][c8]) = lo;
            *reinterpret_cast<float4*>(&buf[sr][c8 + 4]) = hi;
        }
        __syncthreads();
#pragma unroll
        for (int j = 0; j < 8; j++) {
            if (j >= m) break;
            float kc = buf[j][h * 16 + c];
#pragma unroll
            for (int i = 0; i < 8; i++) acc[i] += kc * buf[j][128 + h * 16 + d0 + i];
            if (t < 128) sa += buf[j][t];
        }
    }
    float* out = &PKV[(size_t)sid * 2176];
#pragma unroll
    for (int i = 0; i < 8; i++) out[f0 + i] = acc[i];
    if (t < 128) out[2048 + t] = sa;
}

// ---------------- reduce segment partials per window ----------------
__global__ __launch_bounds__(256) void kv_reduce(
    const float* __restrict__ PKV, const int* __restrict__ SEGBASE,
    float* __restrict__ KV, float* __restrict__ SB)
{
    int w = blockIdx.x;
    int t = threadIdx.x;
    int s0 = SEGBASE[w], s1 = SEGBASE[w + 1];
    float a[8] = {0.f,0.f,0.f,0.f,0.f,0.f,0.f,0.f};
    float sb = 0.f;
    for (int s = s0; s < s1; s++) {
        const float* p = &PKV[(size_t)s * 2176];
#pragma unroll
        for (int i = 0; i < 8; i++) a[i] += p[t * 8 + i];
        if (t < 128) sb += p[2048 + t];
    }
#pragma unroll
    for (int i = 0; i < 8; i++) KV[w * 2048 + t * 8 + i] = a[i];
    if (t < 128) SB[w * 128 + t] = sb;
}

// ---------------- y = (q . kv[w]) / (q . s[w] + eps): bf16 q in, bf16 y out ----------------
__global__ __launch_bounds__(256) void attn_y_seg(
    const unsigned short* __restrict__ R0bf,
    unsigned short* __restrict__ Ybf,
    const int* __restrict__ list,
    const int* __restrict__ SEGW, const int* __restrict__ SEGP0,
    const int* __restrict__ SEGP1, const int* __restrict__ SEGBASE,
    const float* __restrict__ KV, const float* __restrict__ SB)
{
    int sid = blockIdx.x;
    if (sid >= SEGBASE[NWIN]) return;
    int t = threadIdx.x;
    int w = SEGW[sid];
    int g  = t >> 5;            // point group 0..7
    int h  = (t >> 2) & 7;      // head
    int d4 = (t & 3) * 4;       // output d offset

    float4 kvr[16];
    const float* kvb = &KV[w * 2048 + h * 256 + d4];
#pragma unroll
    for (int cc = 0; cc < 16; cc++)
        kvr[cc] = *reinterpret_cast<const float4*>(&kvb[cc * 16]);
    float sreg[16];
    const float* sb = &SB[w * 128 + h * 16];
#pragma unroll
    for (int cc = 0; cc < 16; cc++) sreg[cc] = sb[cc];

    int p0 = SEGP0[sid], p1 = SEGP1[sid];
    for (int p = p0 + g; p < p1; p += 8) {
        int n = list[p];
        const unsigned short* q = &R0bf[(size_t)n * 384 + h * 16];
        bf16x8 qa = *reinterpret_cast<const bf16x8*>(&q[0]);
        bf16x8 qb = *reinterpret_cast<const bf16x8*>(&q[8]);
        float qq[16];
#pragma unroll
        for (int i = 0; i < 8; i++) {
            qq[i] = bf2f((unsigned short)qa[i]);
            qq[8 + i] = bf2f((unsigned short)qb[i]);
        }
        float z = 0.f;
        float4 y = make_float4(0.f, 0.f, 0.f, 0.f);
#pragma unroll
        for (int cc = 0; cc < 16; cc++) {
            z += qq[cc] * sreg[cc];
            y.x += qq[cc] * kvr[cc].x;
            y.y += qq[cc] * kvr[cc].y;
            y.z += qq[cc] * kvr[cc].z;
            y.w += qq[cc] * kvr[cc].w;
        }
        float inv = 1.f / (z + 1e-3f);
        u16x4 o = { f2bf(y.x * inv), f2bf(y.y * inv), f2bf(y.z * inv), f2bf(y.w * inv) };
        *reinterpret_cast<u16x4*>(&Ybf[(size_t)n * 128 + h * 16 + d4]) = o;
    }
}

// ---------------- bn apply: FBbf = bf16(bn1(F)) (ld 128); F[:,96:128] = 2*bn1(F) ----------------
__global__ void bn_apply(float* F, unsigned short* __restrict__ FBbf,
                         const float* __restrict__ scale, const float* __restrict__ shift)
{
    int i = blockIdx.x * 256 + threadIdx.x;
    int n = i >> 5;
    int c4 = (i & 31) * 4;
    float4 v = *reinterpret_cast<const float4*>(&F[n * CCH + c4]);
    float4 o;
    o.x = v.x * scale[c4 + 0] + shift[c4 + 0];
    o.y = v.y * scale[c4 + 1] + shift[c4 + 1];
    o.z = v.z * scale[c4 + 2] + shift[c4 + 2];
    o.w = v.w * scale[c4 + 3] + shift[c4 + 3];
    u16x4 hv = { f2bf(o.x), f2bf(o.y), f2bf(o.z), f2bf(o.w) };
    *reinterpret_cast<u16x4*>(&FBbf[(size_t)n * 128 + c4]) = hv;
    if (c4 >= 96) {
        float4 t = make_float4(2.f * o.x, 2.f * o.y, 2.f * o.z, 2.f * o.w);
        *reinterpret_cast<float4*>(&F[n * CCH + c4]) = t;
    }
}

// ---------------- submanifold conv: bf16 FB in ----------------
template<int KN>
__global__ __launch_bounds__(256) void conv_g(
    const int* __restrict__ nbr, const float* __restrict__ Wc,
    const unsigned short* __restrict__ FBbf, int goff,
    float* __restrict__ Fout, int outoff)
{
    int t = blockIdx.x * 256 + threadIdx.x;
    int pt = t >> 3;
    int so = (t & 7) * 4;
    if (pt >= NPTS) return;
    float acc0 = 0.f, acc1 = 0.f, acc2 = 0.f, acc3 = 0.f;
    const int* nb = &nbr[pt * KN];
#pragma unroll 1
    for (int k = 0; k < KN; k++) {
        int idx = nb[k];
        if (idx >= NPTS) continue;   // sentinel row = zeros
        const unsigned short* rr = &FBbf[(size_t)idx * 128 + goff];
        float r[32];
#pragma unroll
        for (int u = 0; u < 4; u++) {
            bf16x8 h8 = *reinterpret_cast<const bf16x8*>(&rr[u * 8]);
#pragma unroll
            for (int j = 0; j < 8; j++) r[u * 8 + j] = bf2f((unsigned short)h8[j]);
        }
        const float* wk = &Wc[k * 1024 + so];
#pragma unroll
        for (int c = 0; c < 32; c += 4) {
            float4 w0 = *reinterpret_cast<const float4*>(&wk[(c + 0) * 32]);
            float4 w1 = *reinterpret_cast<const float4*>(&wk[(c + 1) * 32]);
            float4 w2 = *reinterpret_cast<const float4*>(&wk[(c + 2) * 32]);
            float4 w3 = *reinterpret_cast<const float4*>(&wk[(c + 3) * 32]);
            acc0 += r[c] * w0.x + r[c+1] * w1.x + r[c+2] * w2.x + r[c+3] * w3.x;
            acc1 += r[c] * w0.y + r[c+1] * w1.y + r[c+2] * w2.y + r[c+3] * w3.y;
            acc2 += r[c] * w0.z + r[c+1] * w1.z + r[c+2] * w2.z + r[c+3] * w3.z;
            acc3 += r[c] * w0.w + r[c+1] * w1.w + r[c+2] * w2.w + r[c+3] * w3.w;
        }
    }
    u16x4 fbh = *reinterpret_cast<const u16x4*>(&FBbf[(size_t)pt * 128 + goff + so]);
    float4 o = make_float4(bf2f(fbh.x) + acc0, bf2f(fbh.y) + acc1,
                           bf2f(fbh.z) + acc2, bf2f(fbh.w) + acc3);
    *reinterpret_cast<float4*>(&Fout[(size_t)pt * CCH + outoff + so]) = o;
}

// ---------------- launch ----------------
extern "C" void kernel_launch(void* const* d_in, const int* in_sizes, int n_in,
                              void* d_out, int out_size, void* d_ws, size_t ws_size,
                              hipStream_t stream)
{
    const float* feats   = (const float*)d_in[0];
    const int*   win_inds= (const int*)d_in[1];
    const int*   nbr_k   = (const int*)d_in[2];
    const int*   nbr_h   = (const int*)d_in[3];
    const int*   nbr_w   = (const int*)d_in[4];
    const float* bn_g    = (const float*)d_in[5];
    const float* bn_b    = (const float*)d_in[6];
    const float* Wqkv    = (const float*)d_in[7];
    const float* Wproj   = (const float*)d_in[8];
    const float* bproj   = (const float*)d_in[9];
    const float* bn1_g   = (const float*)d_in[10];
    const float* bn1_b   = (const float*)d_in[11];
    const float* Wk      = (const float*)d_in[12];
    const float* Wh      = (const float*)d_in[13];
    const float* Ww      = (const float*)d_in[14];
    const float* bn2_g   = (const float*)d_in[15];
    const float* bn2_b   = (const float*)d_in[16];
    const float* fc1_W   = (const float*)d_in[17];
    const float* fc1_b   = (const float*)d_in[18];
    const float* fc2_W   = (const float*)d_in[19];
    const float* fc2_b   = (const float*)d_in[20];

    float* F  = (float*)d_out;
    float* KV = (float*)d_ws;                       // NWIN*2048
    float* SB = KV + NWIN * 2048;                   // NWIN*128
    float* ST = SB + NWIN * 128;                    // 6*128
    float* PART = ST + 768;                         // NBLK_STATS*256
    float* PKV = PART + NBLK_STATS * 256;           // NSEG_MAX*2176
    int* HIST = (int*)(PKV + (size_t)NSEG_MAX * 2176);  // 256
    int* OFFS = HIST + 256;                         // 256 (201 used)
    int* LIST = OFFS + 256;                         // 100096
    int* BH   = LIST + 100096;                      // NBLK_SORT*256
    int* OFFB = BH + NBLK_SORT * 256;               // NBLK_SORT*256
    int* SEGW = OFFB + NBLK_SORT * 256;             // NSEG_MAX
    int* SEGP0= SEGW + NSEG_MAX;                    // NSEG_MAX
    int* SEGP1= SEGP0 + NSEG_MAX;                   // NSEG_MAX
    int* SEGBASE = SEGP1 + NSEG_MAX;                // 256
    unsigned short* WQKVT = (unsigned short*)(SEGBASE + 256);   // 384*128
    unsigned short* WPROJT = WQKVT + 384 * 128;                 // 128*128
    unsigned short* WFC1T  = WPROJT + 128 * 128;                // 256*128
    unsigned short* WFC2T  = WFC1T + 256 * 128;                 // 128*256
    float* BQKV  = (float*)(WFC2T + 128 * 256);     // 384
    float* BPROJ = BQKV + 384;                      // 128
    float* BFC1  = BPROJ + 128;                     // 256
    float* BFC2  = BFC1 + 256;                      // 128
    unsigned short* R0bf = (unsigned short*)(BFC2 + 128);       // NPTS*384 bf16
    unsigned short* Hbf  = R0bf;                                // aliases (fc1 after R0bf dead)
    unsigned short* Ybf  = R0bf + (size_t)NPTS * 384;           // NPTS*128
    unsigned short* FBbf = Ybf + (size_t)NPTS * 128;            // NPTS*128

    hipMemcpyAsync(F, feats, (size_t)NPTS * CCH * sizeof(float),
                   hipMemcpyDeviceToDevice, stream);

    dim3 g3(782, 3), g2(782, 2), g1(782, 1);    // 782 = ceil(100000/128)

    for (int d = 0; d < 2; d++) {
        const int* wi = win_inds + (size_t)d * NPTS;
        float* SC0 = ST, *SH0 = ST + 128, *SC1 = ST + 256, *SH1 = ST + 384,
             * SC2 = ST + 512, *SH2 = ST + 640;

        // ---- BN0 stats + folded W ----
        bn_partial<<<NBLK_STATS, 256, 0, stream>>>(F, PART);
        bn_finalize<<<1, 128, 0, stream>>>(PART, bn_g + d * CCH, bn_b + d * CCH, SC0, SH0);
        wprep<<<384, 128, 0, stream>>>(Wqkv + (size_t)d * CCH * 384, 128, 384,
                                       SC0, SH0, nullptr, WQKVT, BQKV);
        wprep<<<128, 128, 0, stream>>>(Wproj + (size_t)d * CCH * CCH, 128, 128,
                                       nullptr, nullptr, bproj + d * CCH, WPROJT, BPROJ);

        // ---- [q|k|v] = bn0(F) @ Wqkv (relu on q,k) -> R0bf (bf16, ld 384) ----
        gemm_t<0,1><<<g3, 256, 0, stream>>>(F, CCH, WQKVT, BQKV, 128,
                                            R0bf, 384, 256, 0);

        // ---- window lists (contention-free counting sort) ----
        hipMemsetAsync(HIST, 0, 256 * sizeof(int), stream);
        hist2_k<<<NBLK_SORT, 256, 0, stream>>>(wi, BH, HIST);
        scan_k<<<1, 64, 0, stream>>>(HIST, OFFS);
        colscan_k<<<1, 256, 0, stream>>>(BH, OFFS, OFFB);
        scatter2_k<<<NBLK_SORT, 256, 0, stream>>>(wi, OFFB, LIST);

        // ---- segments + per-segment KV partials + reduce ----
        segbuild_k<<<1, 256, 0, stream>>>(OFFS, SEGW, SEGP0, SEGP1, SEGBASE);
        window_kv_seg<<<NSEG_MAX, 256, 0, stream>>>(R0bf, LIST, SEGP0, SEGP1, SEGBASE, PKV);
        kv_reduce<<<NWIN, 256, 0, stream>>>(PKV, SEGBASE, KV, SB);

        // ---- y (bf16) ----
        attn_y_seg<<<NSEG_MAX, 256, 0, stream>>>(R0bf, Ybf, LIST, SEGW, SEGP0, SEGP1,
                                                 SEGBASE, KV, SB);

        // ---- F += y @ Wproj + bproj ----
        gemm_t<1,0><<<g1, 256, 0, stream>>>(Ybf, 128, WPROJT, BPROJ, 128,
                                            F, CCH, 0, 1);

        // ---- BN1 -> FBbf (bf16, ld 128), F[:,96:] = 2*bn1(F) ----
        bn_partial<<<NBLK_STATS, 256, 0, stream>>>(F, PART);
        bn_finalize<<<1, 128, 0, stream>>>(PART, bn1_g + d * CCH, bn1_b + d * CCH, SC1, SH1);
        bn_apply<<<12500, 256, 0, stream>>>(F, FBbf, SC1, SH1);

        // ---- submanifold convs (residual fused) ----
        conv_g<27><<<3125, 256, 0, stream>>>(nbr_k, Wk + (size_t)d * 27 * 1024, FBbf, 0,  F, 0);
        conv_g<13><<<3125, 256, 0, stream>>>(nbr_h, Wh + (size_t)d * 13 * 1024, FBbf, 32, F, 32);
        conv_g<13><<<3125, 256, 0, stream>>>(nbr_w, Ww + (size_t)d * 13 * 1024, FBbf, 64, F, 64);

        // ---- BN2 stats + folded W for fc1; fc2 prep ----
        bn_partial<<<NBLK_STATS, 256, 0, stream>>>(F, PART);
        bn_finalize<<<1, 128, 0, stream>>>(PART, bn2_g + d * CCH, bn2_b + d * CCH, SC2, SH2);
        wprep<<<256, 128, 0, stream>>>(fc1_W + (size_t)d * CCH * 256, 128, 256,
                                       SC2, SH2, fc1_b + d * 256, WFC1T, BFC1);
        wprep<<<128, 128, 0, stream>>>(fc2_W + (size_t)d * 256 * CCH, 256, 128,
                                       nullptr, nullptr, fc2_b + d * CCH, WFC2T, BFC2);

        // ---- MLP: H = relu(bn2(F) @ fc1) (bf16); F += H @ fc2 ----
        gemm_t<0,1><<<g2, 256, 0, stream>>>(F, CCH, WFC1T, BFC1, 128,
                                            Hbf, 256, 256, 0);
        gemm_t<1,0><<<g1, 256, 0, stream>>>(Hbf, 256, WFC2T, BFC2, 256,
                                            F, CCH, 0, 1);
    }
}